// Round 10
// baseline (1452.848 us; speedup 1.0000x reference)
//
#include <hip/hip_runtime.h>
#include <hip/hip_bf16.h>
#include <math.h>

#define NB 4
#define CE 384
#define NH 12
#define DH 32
#define NPTS 9
#define NLAYERS 2
#define KFG 20
#define KBG 50
#define NITER 10
#define HDIM 64
#define WDIM 64
#define NPIX 4096
#define BNTOT (NB * NPIX)
#define NROW (NPIX + KFG + KBG)
#define NCH 16
#define TWO_PI 6.283185307179586f

#define AS1 __attribute__((address_space(1)))
#define AS3 __attribute__((address_space(3)))

typedef __attribute__((ext_vector_type(8))) short short8;
typedef __attribute__((ext_vector_type(4))) float float4v;

static __device__ __forceinline__ unsigned short f2bf(float f) {
  __hip_bfloat16 h = __float2bfloat16(f);
  return *reinterpret_cast<unsigned short*>(&h);
}
static __device__ __forceinline__ float bf2f(unsigned short u) {
  unsigned x = ((unsigned)u) << 16;
  return __uint_as_float(x);
}

__device__ __forceinline__ float4 sample4(const float* __restrict__ vb, int xi, int yi, int c) {
  bool valid = (xi >= 0) & (xi < WDIM) & (yi >= 0) & (yi < HDIM);
  int xc = min(max(xi, 0), WDIM - 1), yc = min(max(yi, 0), HDIM - 1);
  float4 g = *(const float4*)(vb + (long)(yc * WDIM + xc) * CE + c);
  if (!valid) { g.x = 0.f; g.y = 0.f; g.z = 0.f; g.w = 0.f; }
  return g;
}

// ---------------- masks ----------------
__global__ void k_masks(const float* __restrict__ pm, const float* __restrict__ sm,
                        float* padf, float* objf, float* notp, float* wfg, float* wbg) {
  int i = blockIdx.x * 256 + threadIdx.x;
  if (i >= NB * NPIX) return;
  float p  = (pm[i] == 255.0f) ? 1.f : 0.f;
  float o  = (sm[i] == 1.0f) ? 1.f : 0.f;
  float np_ = 1.f - p;
  padf[i] = p; objf[i] = o; notp[i] = np_;
  wfg[i] = o * np_;
  wbg[i] = (1.f - o) * np_;
}

// ---------------- LDS-tiled transpose s_x [B,C,N] -> X [B,N,C] ----------------
__global__ __launch_bounds__(256) void k_transpose(const float* __restrict__ sx,
                                                   float* __restrict__ X) {
  __shared__ float tile[64][65];
  int nb = blockIdx.x * 64, cb = blockIdx.y * 64, b = blockIdx.z;
  int t = threadIdx.x;
  for (int idx = t; idx < 64 * 64; idx += 256) {
    int cc = idx >> 6, nn = idx & 63;
    tile[cc][nn] = sx[((long)b * CE + cb + cc) * NPIX + nb + nn];
  }
  __syncthreads();
  for (int idx = t; idx < 64 * 64; idx += 256) {
    int nn = idx >> 6, cc = idx & 63;
    X[((long)b * NPIX + nb + nn) * CE + cb + cc] = tile[cc][nn];
  }
}

// ---------------- xsq (fp64) ----------------
__global__ void k_xsq(const float* __restrict__ X, double* __restrict__ xsq) {
  int row = blockIdx.x; int t = threadIdx.x;
  const float* xr = X + (long)row * CE;
  double s = 0.0;
  for (int i = t; i < CE; i += 64) { double v = (double)xr[i]; s += v * v; }
  #pragma unroll
  for (int o = 32; o > 0; o >>= 1) s += __shfl_down(s, o, 64);
  if (t == 0) xsq[row] = s;
}

// ---------------- pos cumsums + invdt table (LDS-staged; scans bit-identical) ----------------
__global__ __launch_bounds__(128) void k_cums(const float* __restrict__ padf,
                                              float* __restrict__ yvf,
                                              float* __restrict__ xvf,
                                              float* __restrict__ invdt) {
  __shared__ float pad_s[NPIX];
  int b = blockIdx.x; int t = threadIdx.x;
  for (int i = t; i < NPIX; i += 128) pad_s[i] = padf[b * NPIX + i];
  if (b == 0) {
    for (int c = t; c < CE; c += 128) {
      int tt = (c < 192) ? c : c - 192;
      invdt[c] = 1.0f / powf(10000.0f, (float)(2 * (tt / 2)) / 192.0f);
    }
  }
  __syncthreads();
  if (t < 64) {
    int w = t;
    float cum[64]; float tot = 0.f;
    for (int h = 0; h < 64; ++h) {
      float nm = 1.f - pad_s[h * WDIM + w];
      tot += nm; cum[h] = tot;
    }
    float sc = 1.f / (tot + 1e-6f);
    for (int h = 0; h < 64; ++h) yvf[b * NPIX + h * WDIM + w] = cum[h] * sc * TWO_PI;
  } else {
    int h = t - 64;
    float cum[64]; float tot = 0.f;
    for (int w = 0; w < 64; ++w) {
      float nm = 1.f - pad_s[h * WDIM + w];
      tot += nm; cum[w] = tot;
    }
    float sc = 1.f / (tot + 1e-6f);
    for (int w = 0; w < 64; ++w) xvf[b * NPIX + h * WDIM + w] = cum[w] * sc * TWO_PI;
  }
}

// ---------------- kmeans init (fp32 centers; X values are fp32 -> exact) ----------------
__global__ void k_kinit(const float* __restrict__ X, const float* __restrict__ wts,
                        float* __restrict__ cen, int K) {
  int b = blockIdx.x;
  __shared__ int idx[KBG];
  if (threadIdx.x == 0) {
    int cnt = 0;
    for (int n = 0; n < NPIX && cnt < K; ++n) if (wts[b * NPIX + n] > 0.f) idx[cnt++] = n;
    for (int n = 0; n < NPIX && cnt < K; ++n) if (!(wts[b * NPIX + n] > 0.f)) idx[cnt++] = n;
  }
  __syncthreads();
  for (int i = threadIdx.x; i < K * CE; i += blockDim.x) {
    int k = i / CE, c = i % CE;
    cen[((long)b * K + k) * CE + c] = X[((long)b * NPIX + idx[k]) * CE + c];
  }
}

// ---------------- kmeans distances: 4 px/thread, 8-way split, XCD-pinned ----------------
// grid (BN/128, 7), block 256. Thread map: h = t&7 (channel octant, 48 ch),
// px-group = t>>3 (32 groups x 4 px = 128 px/block). Same grid/occupancy as the
// R7 config (proven non-latency-bound: 896 blocks, 14 waves/CU), but:
// (1) R9 post-mortem budget: k_dots ~40-43 µs hiding under the top-5 cutoff
//     (~420 µs total = largest cost). Floors: LDS 860K wave-b128 x 12cyc = 16.8 µs,
//     X re-read 7z x 25 MB = 176 MB via L3 ~ 12-15 µs, VALU 5.6 µs.
// (2) 4px/thread halves wave count -> LDS floor 16.8 -> 8.4 µs. acc[10][4] fp32
//     = 40 VGPR (~95 total, NO bounds floor — R4 spill lesson; tripwire:
//     WRITE_SIZE >> 1.35 MB means spill).
// (3) XCD-pin swizzle: decode hw dispatch q so pxblk%8 == q%8 (bijective:
//     lo=q&7, hi=(q>>3)&15, z=q>>7, pxblk=lo+8*hi). All 7 z-visits of a pixel
//     block land on one XCD -> per-XCD X set 16x200KB = 3.2 MB < 4 MB L2 ->
//     X served from L2 (~35 TB/s) instead of L3-streamed.
// LDS pad HSTR8=52 floats (208 B): octant bases o*208 mod 128 B cycle through
// all 8 distinct 16B slots -> each wave b128 inst = 8 unique addrs (8-lane
// broadcast groups), conflict-free. KSTR8 = 8*52 = 416 (16.6 KB tile).
// Numerics: csq bit-identical (same 4-wave order). Dots: 8-way combine tree vs
// R7's 4-way (~1e-7 rel shift) — same tie-equivalence class as the fp64->fp32
// switch that passed with identical absmax.
#define HSTR8 52
#define KSTR8 416

__global__ __launch_bounds__(256) void k_dots(
    const float* __restrict__ X, const double* __restrict__ xsq,
    const float* __restrict__ cenF, const float* __restrict__ cenB,
    float* __restrict__ candD, int* __restrict__ candI, int* __restrict__ cntAll) {
  __shared__ float ct[10 * KSTR8];
  __shared__ float csq_s[10];
  int q = blockIdx.y * gridDim.x + blockIdx.x;   // hw dispatch order (x fastest)
  int z, pxblk;
  {
    int lo = q & 7, hi = (q >> 3) & 15;
    z = q >> 7;
    pxblk = lo + 8 * hi;                         // pxblk%8 == q%8 -> XCD-pinned
  }
  int isBg = (z >= 2) ? 1 : 0;
  int k0 = isBg ? (z - 2) * 10 : z * 10;
  int t = threadIdx.x;
  int h = t & 7;
  int n = pxblk * 128 + (t >> 3) * 4;            // first of this thread's 4 pixels
  int b = pxblk >> 5;                            // 32 blocks per batch
  if (blockIdx.x == 0 && blockIdx.y == 0) {
    for (int i = t; i < NB * (KFG + KBG); i += 256) cntAll[i] = 0;
  }
  const float* cb = (isBg ? cenB + (long)b * KBG * CE
                          : cenF + (long)b * KFG * CE) + (long)k0 * CE;
  for (int i = t; i < 10 * CE; i += 256) {
    int k = i / CE, c = i % CE;
    ct[k * KSTR8 + (c / 48) * HSTR8 + (c % 48)] = cb[i];
  }
  {
    int w = t >> 6, lane = t & 63;               // 4 waves cover centers 0..9
    for (int kk = w; kk < 10; kk += 4) {
      double s = 0.0;
      for (int c = lane; c < CE; c += 64) { double v = (double)cb[kk * CE + c]; s += v * v; }
      #pragma unroll
      for (int o = 32; o > 0; o >>= 1) s += __shfl_down(s, o, 64);
      if (lane == 0) csq_s[kk] = (float)s;
    }
  }
  __syncthreads();
  const float* xr = X + (long)n * CE + h * 48;
  const float* cth = ct + h * HSTR8;
  float acc[10][4];
  #pragma unroll
  for (int k = 0; k < 10; ++k)
    #pragma unroll
    for (int p = 0; p < 4; ++p) acc[k][p] = 0.f;
  for (int c0 = 0; c0 < 48; c0 += 8) {
    float4 xa[4], xb[4];
    #pragma unroll
    for (int p = 0; p < 4; ++p) {
      xa[p] = *(const float4*)(xr + p * CE + c0);
      xb[p] = *(const float4*)(xr + p * CE + c0 + 4);
    }
    #pragma unroll
    for (int k = 0; k < 10; ++k) {
      float4 c1 = *(const float4*)(&cth[k * KSTR8 + c0]);       // 8 unique addrs/wave
      float4 c2 = *(const float4*)(&cth[k * KSTR8 + c0 + 4]);
      #pragma unroll
      for (int p = 0; p < 4; ++p) {
        float a = acc[k][p];
        a += xa[p].x * c1.x; a += xa[p].y * c1.y;
        a += xa[p].z * c1.z; a += xa[p].w * c1.w;
        a += xb[p].x * c2.x; a += xb[p].y * c2.y;
        a += xb[p].z * c2.z; a += xb[p].w * c2.w;
        acc[k][p] = a;
      }
    }
  }
  // combine the 8 channel-octant partials (lanes t^1, t^2, t^4 are same-wave)
  #pragma unroll
  for (int k = 0; k < 10; ++k)
    #pragma unroll
    for (int p = 0; p < 4; ++p) {
      float a = acc[k][p];
      a += __shfl_xor(a, 1, 64);
      a += __shfl_xor(a, 2, 64);
      a += __shfl_xor(a, 4, 64);
      acc[k][p] = a;
    }
  if (h == 0) {
    #pragma unroll
    for (int p = 0; p < 4; ++p) {
      float qn = (float)xsq[n + p];
      float best = 3.0e38f; int bi = 0;
      #pragma unroll
      for (int k = 0; k < 10; ++k) {
        float d = qn - 2.0f * acc[k][p] + csq_s[k];
        if (d < best) { best = d; bi = k0 + k; }
      }
      long gi = (long)z * BNTOT + n + p;
      candD[gi] = best;
      candI[gi] = bi;
    }
  }
}

// ---------------- final argmin over 7 chunk candidates + bucket scatter ----------------
// One thread per pixel. FG candidates are chunks z=0..1, BG z=2..6. Strict < in ascending
// z preserves the reference's earliest-index argmin. Pixels are scattered into per-cluster
// index lists; within-cluster order is nondeterministic (atomic slots) which only perturbs
// the fp64 summation order in k_cacc (~1 ulp, far below tolerance).
__global__ void k_asn(const float* __restrict__ candD, const int* __restrict__ candI,
                      const float* __restrict__ wfg, const float* __restrict__ wbg,
                      int* __restrict__ listF, int* __restrict__ listB,
                      int* __restrict__ cntAll) {
  int n = blockIdx.x * 256 + threadIdx.x;
  if (n >= BNTOT) return;
  int b = n >> 12;
  int nn = n & (NPIX - 1);
  float wf = wfg[n], wb = wbg[n];
  if (wf > 0.f) {
    float d0 = candD[n]; int i0 = candI[n];
    float d1 = candD[(long)BNTOT + n];
    if (d1 < d0) { d0 = d1; i0 = candI[(long)BNTOT + n]; }
    int slot = atomicAdd(&cntAll[b * KFG + i0], 1);
    listF[((long)b * KFG + i0) * NPIX + slot] = nn;
  } else if (wb > 0.f) {
    float d0 = candD[2L * BNTOT + n]; int i0 = candI[2L * BNTOT + n];
    #pragma unroll
    for (int z = 3; z < 7; ++z) {
      float dz = candD[(long)z * BNTOT + n];
      if (dz < d0) { d0 = dz; i0 = candI[(long)z * BNTOT + n]; }
    }
    int slot = atomicAdd(&cntAll[NB * KFG + b * KBG + i0], 1);
    listB[((long)b * KBG + i0) * NPIX + slot] = nn;
  }
}

// ---------------- chunk-parallel gather-accumulate per cluster ----------------
// R7 post-mortem: single-block-per-cluster k_cacc was a STRAGGLER kernel — 45.4 µs
// at 1.7% occupancy. Fix (R9, verified): split each cluster's list into NCH=16
// contiguous chunks; grid (3, 70, NB*NCH) = 13,440 blocks; fp64 partial per chunk;
// k_cred sums in fixed chunk order. PC aliases V (dead during k-means) to stay
// inside the workspace budget (R8 post-mortem: appending 13.8 MB killed the
// container twice -> ws_size overflow -> OOB fault).
__global__ __launch_bounds__(128) void k_cacc(
    const float* __restrict__ X,
    const int* __restrict__ listF, const int* __restrict__ listB,
    const int* __restrict__ cntAll,
    double* __restrict__ PC) {
  __shared__ int ls[256];    // cs = ceil(4096/16) = 256 max
  int slice = blockIdx.x;    // 0..2
  int kq = blockIdx.y;       // 0..KFG+KBG-1
  int zz = blockIdx.z;       // b*NCH + ch
  int b = zz / NCH, ch = zz % NCH;
  int t = threadIdx.x;
  int c = slice * 128 + t;
  const int* list; int cnt;
  if (kq < KFG) {
    cnt = cntAll[b * KFG + kq];
    list = listF + ((long)b * KFG + kq) * NPIX;
  } else {
    int k = kq - KFG;
    cnt = cntAll[NB * KFG + b * KBG + k];
    list = listB + ((long)b * KBG + k) * NPIX;
  }
  int cs = (cnt + NCH - 1) / NCH;
  int i0 = ch * cs;
  int i1 = min(i0 + cs, cnt);
  int m = i1 - i0;                       // may be <= 0 -> partial stays 0
  for (int i = t; i < m; i += 128) ls[i] = list[i0 + i];
  __syncthreads();
  const float* Xb = X + (long)b * NPIX * CE;
  double acc = 0.0;
  int i = 0;
  for (; i + 4 <= m; i += 4) {
    int n0 = ls[i], n1 = ls[i + 1], n2 = ls[i + 2], n3 = ls[i + 3];
    float v0 = Xb[(long)n0 * CE + c];
    float v1 = Xb[(long)n1 * CE + c];
    float v2 = Xb[(long)n2 * CE + c];
    float v3 = Xb[(long)n3 * CE + c];
    acc += (double)v0; acc += (double)v1; acc += (double)v2; acc += (double)v3;
  }
  for (; i < m; ++i) acc += (double)Xb[(long)ls[i] * CE + c];
  // PC layout: [ch][b*(KFG+KBG)+kq][c]
  PC[((long)ch * (NB * (KFG + KBG)) + (long)b * (KFG + KBG) + kq) * CE + c] = acc;
}

// ---------------- reduce chunk partials -> center update (deterministic) ----------------
__global__ void k_cred(const double* __restrict__ PC, const int* __restrict__ cntAll,
                       const float* __restrict__ srcF, float* __restrict__ dstF,
                       const float* __restrict__ srcB, float* __restrict__ dstB) {
  int i = blockIdx.x * 256 + threadIdx.x;
  const int tot = NB * (KFG + KBG) * CE;
  if (i >= tot) return;
  int c = i % CE;
  int r = i / CE;                        // b*(KFG+KBG)+kq
  int kq = r % (KFG + KBG);
  int b = r / (KFG + KBG);
  const long stride = (long)NB * (KFG + KBG) * CE;
  double s = 0.0;
  #pragma unroll
  for (int ch = 0; ch < NCH; ++ch) s += PC[(long)ch * stride + (long)r * CE + c];
  if (kq < KFG) {
    int cnt = cntAll[b * KFG + kq];
    long o = ((long)b * KFG + kq) * CE + c;
    dstF[o] = (cnt > 0) ? (float)(s / (double)cnt) : srcF[o];
  } else {
    int k = kq - KFG;
    int cnt = cntAll[NB * KFG + b * KBG + k];
    long o = ((long)b * KBG + k) * CE + c;
    dstB[o] = (cnt > 0) ? (float)(s / (double)cnt) : srcB[o];
  }
}

// ---------------- fused pos + bf16 staging ----------------
__global__ void k_cvtQV(const float* __restrict__ X,
                        const float* __restrict__ yvf, const float* __restrict__ xvf,
                        const float* __restrict__ invdt, const float* __restrict__ notp,
                        float* __restrict__ POS,
                        unsigned short* __restrict__ QB, unsigned short* __restrict__ VBin) {
  long i = (long)blockIdx.x * 256 + threadIdx.x;
  if (i >= (long)NB * NPIX * CE) return;
  int c = (int)(i % CE);
  long row = i / CE;
  float p = (c < 192) ? yvf[row] : xvf[row];
  float v = p * invdt[c];
  int tt = (c < 192) ? c : c - 192;
  float r = (tt & 1) ? cosf(v) : sinf(v);
  POS[i] = r;
  float x = X[i];
  QB[i] = f2bf(x + r);
  VBin[i] = f2bf(x * notp[row]);
}

// ---------------- fused per-layer weight convert/transpose + concat bias ----------------
__global__ void k_cvtW_all(
    const float* __restrict__ Wv_l, const float* __restrict__ Woff_l,
    const float* __restrict__ Wa_l, const float* __restrict__ Wout_l,
    const float* __restrict__ Wf1_l, const float* __restrict__ Wf2_l,
    const float* __restrict__ boff_l, const float* __restrict__ ba_l,
    unsigned short* __restrict__ W0, unsigned short* __restrict__ W1,
    unsigned short* __restrict__ W3, unsigned short* __restrict__ W4,
    unsigned short* __restrict__ W5, float* __restrict__ biasCat) {
  int i = blockIdx.x * 256 + threadIdx.x;
  const int S = 147456, SF = 442368;
  if (i < S) {
    int n = i / 384, k = i % 384;
    W0[i] = f2bf(Wv_l[(long)k * 384 + n]);
  } else if (i < 2 * S) {
    int j = i - S; int n = j / 384, k = j % 384;
    float v = 0.f;
    if (n < 216) v = Woff_l[(long)k * 216 + n];
    else if (n < 324) v = Wa_l[(long)k * 108 + (n - 216)];
    W1[j] = f2bf(v);
  } else if (i < 3 * S) {
    int j = i - 2 * S; int n = j / 384, k = j % 384;
    W3[j] = f2bf(Wout_l[(long)k * 384 + n]);
  } else if (i < 3 * S + SF) {
    int j = i - 3 * S; int n = j / 384, k = j % 384;
    W4[j] = f2bf(Wf1_l[(long)k * 1152 + n]);
  } else if (i < 3 * S + 2 * SF) {
    int j = i - 3 * S - SF; int n = j / 1152, k = j % 1152;
    W5[j] = f2bf(Wf2_l[(long)k * 384 + n]);
  } else if (i < 3 * S + 2 * SF + 324) {
    int j = i - 3 * S - 2 * SF;
    biasCat[j] = (j < 216) ? boff_l[j] : ba_l[j - 216];
  }
}

// ---------------- bf16 MFMA GEMM: C = A @ Bt^T (+bias)(+relu) ----------------
// Staging via global_load_lds width=16 (DMA direct to LDS, contiguous 64B rows).
// XCD-bijective block remap (T1): pins by%8 == xcd so blocks sharing an A-row-panel
// land on one XCD's L2 (verified R9: FFN2 FETCH 56.7 -> 22.2 MB, FFN1 -> 12.3 MB).
__global__ __launch_bounds__(256) void k_gemm_bf(
    const unsigned short* __restrict__ A, const unsigned short* __restrict__ Bt,
    const float* __restrict__ bias, float* __restrict__ Cf, unsigned short* __restrict__ Cb,
    int M, int K, int N, int relu) {
  __shared__ unsigned short As[128 * 32];
  __shared__ unsigned short Bs[128 * 32];
  int bx, by;
  {
    int gx = gridDim.x;
    int q = blockIdx.y * gx + blockIdx.x;
    if ((gridDim.y & 7) == 0) {
      int xcd = q & 7;
      int r = q >> 3;
      bx = r % gx;
      by = xcd + 8 * (r / gx);
    } else { bx = blockIdx.x; by = blockIdx.y; }
  }
  int m0 = by * 128, n0 = bx * 128;
  int t = threadIdx.x;
  int w = t >> 6, l = t & 63;
  int wm = w >> 1, wn = w & 1;
  int half = l >> 4, lr = l & 15;
  float4v acc[4][4] = {};
  for (int k0 = 0; k0 < K; k0 += 32) {
    #pragma unroll
    for (int i = 0; i < 2; ++i) {
      int c = w * 64 + i * 256 + l;           // 0..511
      int r = c >> 2, part = c & 3;
      int ldsOff = (w * 64 + i * 256) * 8;    // shorts; lane adds l*16 bytes
      __builtin_amdgcn_global_load_lds(
          (const AS1 unsigned int*)(A + (size_t)(m0 + r) * K + k0 + part * 8),
          (AS3 unsigned int*)(As + ldsOff), 16, 0, 0);
      __builtin_amdgcn_global_load_lds(
          (const AS1 unsigned int*)(Bt + (size_t)(n0 + r) * K + k0 + part * 8),
          (AS3 unsigned int*)(Bs + ldsOff), 16, 0, 0);
    }
    __syncthreads();
    short8 af[4], bfr[4];
    #pragma unroll
    for (int am = 0; am < 4; ++am)
      af[am] = *(const short8*)(&As[(wm * 64 + am * 16 + lr) * 32 + half * 8]);
    #pragma unroll
    for (int bn = 0; bn < 4; ++bn)
      bfr[bn] = *(const short8*)(&Bs[(wn * 64 + bn * 16 + lr) * 32 + half * 8]);
    #pragma unroll
    for (int am = 0; am < 4; ++am)
      #pragma unroll
      for (int bn = 0; bn < 4; ++bn)
        acc[am][bn] = __builtin_amdgcn_mfma_f32_16x16x32_bf16(af[am], bfr[bn], acc[am][bn], 0, 0, 0);
    __syncthreads();
  }
  #pragma unroll
  for (int am = 0; am < 4; ++am) {
    #pragma unroll
    for (int bn = 0; bn < 4; ++bn) {
      int gc = n0 + wn * 64 + bn * 16 + lr;
      if (gc < N) {
        float bv = bias ? bias[gc] : 0.f;
        int gr0 = m0 + wm * 64 + am * 16 + half * 4;
        #pragma unroll
        for (int r = 0; r < 4; ++r) {
          float v = acc[am][bn][r] + bv;
          if (relu) v = fmaxf(v, 0.f);
          size_t oi = (size_t)(gr0 + r) * N + gc;
          if (Cf) Cf[oi] = v;
          else Cb[oi] = f2bf(v);
        }
      }
    }
  }
}

// ---------------- coords+softmax: one thread per (row, head) ----------------
__global__ void k_coords(const unsigned short* __restrict__ OAB, float4* __restrict__ CRD) {
  int idx = blockIdx.x * 256 + threadIdx.x;
  if (idx >= NB * NPIX * NH) return;
  int row = idx / NH, h = idx % NH;
  int n = row & (NPIX - 1);
  int hh = n >> 6, ww = n & 63;
  float refx = ((float)ww + 0.5f) / (float)WDIM;
  float refy = ((float)hh + 0.5f) / (float)HDIM;
  const unsigned short* oab = OAB + (size_t)row * 324;
  float f[NPTS];
  #pragma unroll
  for (int j = 0; j < NPTS; ++j) f[j] = bf2f(oab[216 + h * 9 + j]);
  float m = f[0];
  #pragma unroll
  for (int j = 1; j < NPTS; ++j) m = fmaxf(m, f[j]);
  float s = 0.f;
  #pragma unroll
  for (int j = 0; j < NPTS; ++j) { f[j] = expf(f[j] - m); s += f[j]; }
  float inv = 1.f / s;
  float4* crd = CRD + (size_t)row * 108 + h * 9;
  #pragma unroll
  for (int p = 0; p < NPTS; ++p) {
    float ox = bf2f(oab[h * 18 + p * 2 + 0]);
    float oy = bf2f(oab[h * 18 + p * 2 + 1]);
    float lx = refx + ox / (float)WDIM;
    float ly = refy + oy / (float)HDIM;
    float xs = lx * (float)WDIM - 0.5f;
    float ys = ly * (float)HDIM - 0.5f;
    float x0f = floorf(xs), y0f = floorf(ys);
    int x0 = (int)x0f, y0 = (int)y0f;
    float4 o;
    o.x = xs - x0f;
    o.y = ys - y0f;
    o.z = f[p] * inv;
    o.w = __int_as_float((y0 << 16) | (x0 & 0xFFFF));
    crd[p] = o;
  }
}

// ---------------- gather: 4 channels per thread, float4 gathers ----------------
__global__ __launch_bounds__(256) void k_gather(
    const float* __restrict__ V, const float4* __restrict__ CRD,
    uint2* __restrict__ ATTu) {
  int idx = blockIdx.x * 256 + threadIdx.x;
  if (idx >= NB * NPIX * (CE / 4)) return;
  int row = idx / (CE / 4), cq = idx % (CE / 4);
  int c = cq * 4;
  int h = c >> 5;
  int b = row >> 12;
  const float* vb = V + (size_t)b * NPIX * CE;
  const float4* crd = CRD + (size_t)row * 108 + h * 9;
  float a0 = 0.f, a1 = 0.f, a2 = 0.f, a3 = 0.f;
  #pragma unroll
  for (int p = 0; p < NPTS; ++p) {
    float4 o = crd[p];
    int pk = __float_as_int(o.w);
    int x0 = (int)(short)(pk & 0xFFFF);
    int y0 = pk >> 16;
    float wx = o.x, wy = o.y, aw = o.z;
    float4 g00 = sample4(vb, x0,     y0,     c);
    float4 g01 = sample4(vb, x0 + 1, y0,     c);
    float4 g10 = sample4(vb, x0,     y0 + 1, c);
    float4 g11 = sample4(vb, x0 + 1, y0 + 1, c);
    float w00 = (1.f - wx) * (1.f - wy), w01 = wx * (1.f - wy);
    float w10 = (1.f - wx) * wy,         w11 = wx * wy;
    a0 += aw * (g00.x * w00 + g01.x * w01 + g10.x * w10 + g11.x * w11);
    a1 += aw * (g00.y * w00 + g01.y * w01 + g10.y * w10 + g11.y * w11);
    a2 += aw * (g00.z * w00 + g01.z * w01 + g10.z * w10 + g11.z * w11);
    a3 += aw * (g00.w * w00 + g01.w * w01 + g10.w * w10 + g11.w * w11);
  }
  uint2 pk2;
  pk2.x = (unsigned)f2bf(a0) | ((unsigned)f2bf(a1) << 16);
  pk2.y = (unsigned)f2bf(a2) | ((unsigned)f2bf(a3) << 16);
  ATTu[(size_t)row * (CE / 4) + cq] = pk2;
}

// ---------------- LayerNorm(X + T), 4 rows/block, fused epilogues ----------------
__global__ __launch_bounds__(256) void k_ln(
    float* __restrict__ X, const float* __restrict__ T,
    const float* __restrict__ g, const float* __restrict__ bb,
    unsigned short* __restrict__ xbOut,
    const float* __restrict__ posp, const float* __restrict__ notp,
    unsigned short* __restrict__ qb, unsigned short* __restrict__ vbin,
    float* __restrict__ outp) {
  int t = threadIdx.x;
  int row = blockIdx.x * 4 + (t >> 6);
  int lane = t & 63;
  float* xr = X + (long)row * CE;
  const float* tr = T + (long)row * CE;
  float v[6]; float s = 0.f;
  #pragma unroll
  for (int i = 0; i < 6; ++i) { v[i] = xr[lane + 64 * i] + tr[lane + 64 * i]; s += v[i]; }
  #pragma unroll
  for (int o = 32; o > 0; o >>= 1) s += __shfl_down(s, o, 64);
  s = __shfl(s, 0, 64);
  float m = s / (float)CE;
  float var = 0.f;
  #pragma unroll
  for (int i = 0; i < 6; ++i) { float d = v[i] - m; var += d * d; }
  #pragma unroll
  for (int o = 32; o > 0; o >>= 1) var += __shfl_down(var, o, 64);
  var = __shfl(var, 0, 64);
  float rst = rsqrtf(var / (float)CE + 1e-5f);
  float nprow = notp ? notp[row] : 0.f;
  int b = row >> 12, n = row & (NPIX - 1);
  #pragma unroll
  for (int i = 0; i < 6; ++i) {
    int c = lane + 64 * i;
    float xn = (v[i] - m) * rst * g[c] + bb[c];
    if (outp) outp[((long)b * NROW + n) * CE + c] = xn;
    else xr[c] = xn;
    if (xbOut) xbOut[(long)row * CE + c] = f2bf(xn);
    if (qb) {
      qb[(long)row * CE + c] = f2bf(xn + posp[(long)row * CE + c]);
      vbin[(long)row * CE + c] = f2bf(xn * nprow);
    }
  }
}

// ---------------- centers -> output ----------------
__global__ void k_out_cen(const float* __restrict__ fg, const float* __restrict__ bg,
                          float* __restrict__ out) {
  int i = blockIdx.x * 256 + threadIdx.x;
  const int tot = NB * (KFG + KBG) * CE;
  if (i >= tot) return;
  int c = i % CE;
  int r = i / CE;
  int rr = r % (KFG + KBG);
  int b = r / (KFG + KBG);
  float v;
  if (rr < KFG) v = fg[((long)b * KFG + rr) * CE + c];
  else v = bg[((long)b * KBG + (rr - KFG)) * CE + c];
  out[((long)b * NROW + NPIX + rr) * CE + c] = v;
}

extern "C" void kernel_launch(void* const* d_in, const int* in_sizes, int n_in,
                              void* d_out, int out_size, void* d_ws, size_t ws_size,
                              hipStream_t stream) {
  (void)in_sizes; (void)n_in; (void)out_size; (void)ws_size;
  const float* s_x  = (const float*)d_in[0];
  const float* s_pm = (const float*)d_in[1];
  const float* s_sm = (const float*)d_in[2];
  const float* Wv   = (const float*)d_in[3];
  const float* bv   = (const float*)d_in[4];
  const float* Woff = (const float*)d_in[5];
  const float* boff = (const float*)d_in[6];
  const float* Wa   = (const float*)d_in[7];
  const float* ba   = (const float*)d_in[8];
  const float* Wout = (const float*)d_in[9];
  const float* bout = (const float*)d_in[10];
  const float* ln1g = (const float*)d_in[11];
  const float* ln1b = (const float*)d_in[12];
  const float* Wf1  = (const float*)d_in[13];
  const float* Wf2  = (const float*)d_in[14];
  const float* ln2g = (const float*)d_in[15];
  const float* ln2b = (const float*)d_in[16];
  float* out = (float*)d_out;
  char* pb = (char*)d_ws;

  const long BN  = (long)NB * NPIX;      // 16384
  const long BNC = BN * CE;              // 6291456

  float* X    = (float*)pb; pb += BNC * 4;
  float* POS  = (float*)pb; pb += BNC * 4;
  float* V    = (float*)pb; pb += BNC * 4;
  float* T2   = (float*)pb; pb += BNC * 4;
  double* PC  = (double*)V;   // 13.8 MB chunk partials alias V (dead during k-means;
                              // first written by layer-0 GEMM). R0 precedent: PF/PB
                              // aliased V/T2 under a "< 24 MB" budget note.
  unsigned short* QB   = (unsigned short*)pb; pb += BNC * 2;
  unsigned short* VBin = (unsigned short*)pb; pb += BNC * 2;
  unsigned short* T1b  = (unsigned short*)pb; pb += BNC * 2;
  unsigned short* Zbf  = QB;   // FFN hidden aliases QB+VBin+T1b
  unsigned short* XB   = (unsigned short*)pb; pb += BNC * 2;
  unsigned short* OAB  = (unsigned short*)pb; pb += BN * 324 * 2;
  float4* CRD = (float4*)pb; pb += BN * 108 * 16;
  const int S_W = 147456, S_F = 442368;
  unsigned short* WT[NLAYERS][5];
  float* biasCat[NLAYERS];
  for (int l = 0; l < NLAYERS; ++l) {
    WT[l][0] = (unsigned short*)pb; pb += S_W * 2;
    WT[l][1] = (unsigned short*)pb; pb += S_W * 2;
    WT[l][2] = (unsigned short*)pb; pb += S_W * 2;
    WT[l][3] = (unsigned short*)pb; pb += S_F * 2;
    WT[l][4] = (unsigned short*)pb; pb += S_F * 2;
    biasCat[l] = (float*)pb; pb += 324 * 4;
  }
  float* padf = (float*)pb; pb += BN * 4;
  float* objf = (float*)pb; pb += BN * 4;
  float* notp = (float*)pb; pb += BN * 4;
  float* wfg  = (float*)pb; pb += BN * 4;
  float* wbg  = (float*)pb; pb += BN * 4;
  float* yvf  = (float*)pb; pb += BN * 4;
  float* xvf  = (float*)pb; pb += BN * 4;
  float* invdt = (float*)pb; pb += CE * 4;
  pb = (char*)(((size_t)pb + 7) & ~(size_t)7);
  double* xsq   = (double*)pb; pb += BN * 8;
  float* candD = (float*)pb; pb += BN * 7 * 4;            // per-chunk best distance (fp32)
  float* cFgA = (float*)pb; pb += (long)NB * KFG * CE * 4;  // fp32 centers
  float* cFgB = (float*)pb; pb += (long)NB * KFG * CE * 4;
  float* cBgA = (float*)pb; pb += (long)NB * KBG * CE * 4;
  float* cBgB = (float*)pb; pb += (long)NB * KBG * CE * 4;
  int* candI  = (int*)pb; pb += BN * 7 * 4;               // per-chunk best global-k
  int* cntAll = (int*)pb; pb += NB * (KFG + KBG) * 4;     // cluster counts (FG then BG)
  int* listF  = (int*)pb; pb += (long)NB * KFG * NPIX * 4;
  int* listB  = (int*)pb; pb += (long)NB * KBG * NPIX * 4;

  int bn = (int)BN;
  int cvtBlocks = (int)((BNC + 255) / 256);

  k_masks<<<(bn + 255) / 256, 256, 0, stream>>>(s_pm, s_sm, padf, objf, notp, wfg, wbg);
  k_transpose<<<dim3(NPIX / 64, CE / 64, NB), 256, 0, stream>>>(s_x, X);
  k_xsq<<<bn, 64, 0, stream>>>(X, xsq);
  k_cums<<<NB, 128, 0, stream>>>(padf, yvf, xvf, invdt);
  k_cvtQV<<<cvtBlocks, 256, 0, stream>>>(X, yvf, xvf, invdt, notp, POS, QB, VBin);

  const int CVTW_TOT = 3 * S_W + 2 * S_F + 324;
  for (int l = 0; l < NLAYERS; ++l) {
    k_cvtW_all<<<(CVTW_TOT + 255) / 256, 256, 0, stream>>>(
        Wv + (long)l * CE * CE, Woff + (long)l * CE * 216, Wa + (long)l * CE * 108,
        Wout + (long)l * CE * CE, Wf1 + (long)l * CE * 1152, Wf2 + (long)l * 1152 * CE,
        boff + l * 216, ba + l * 108,
        WT[l][0], WT[l][1], WT[l][2], WT[l][3], WT[l][4], biasCat[l]);
  }

  // ---- kmeans: dots(+chunk argmin) -> asn(bucket lists) -> cacc(chunk partials) -> cred ----
  float *srcF = cFgA, *dstF = cFgB, *srcB = cBgA, *dstB = cBgB;
  k_kinit<<<NB, 256, 0, stream>>>(X, wfg, srcF, KFG);
  k_kinit<<<NB, 256, 0, stream>>>(X, wbg, srcB, KBG);
  const int credBlocks = (NB * (KFG + KBG) * CE + 255) / 256;
  for (int it = 0; it < NITER; ++it) {
    k_dots<<<dim3(bn / 128, 7), 256, 0, stream>>>(X, xsq, srcF, srcB, candD, candI, cntAll);
    k_asn<<<(bn + 255) / 256, 256, 0, stream>>>(candD, candI, wfg, wbg, listF, listB, cntAll);
    k_cacc<<<dim3(3, KFG + KBG, NB * NCH), 128, 0, stream>>>(
        X, listF, listB, cntAll, PC);
    k_cred<<<credBlocks, 256, 0, stream>>>(PC, cntAll, srcF, dstF, srcB, dstB);
    float* tmp;
    tmp = srcF; srcF = dstF; dstF = tmp;
    tmp = srcB; srcB = dstB; dstB = tmp;
  }
  float* fgC = srcF; float* bgC = srcB;

  // ---- layers ----
  for (int l = 0; l < NLAYERS; ++l) {
    const float* bv_l   = bv   + l * CE;
    const float* bout_l = bout + l * CE;
    int last = (l == NLAYERS - 1);

    k_gemm_bf<<<dim3(3, 128), 256, 0, stream>>>(VBin, WT[l][0], bv_l, V, (unsigned short*)nullptr,
                                                bn, CE, 384, 0);
    k_gemm_bf<<<dim3(3, 128), 256, 0, stream>>>(QB, WT[l][1], biasCat[l], (float*)nullptr, OAB,
                                                bn, CE, 324, 0);
    k_coords<<<(bn * NH + 255) / 256, 256, 0, stream>>>(OAB, CRD);
    k_gather<<<(bn * (CE / 4) + 255) / 256, 256, 0, stream>>>(V, CRD, (uint2*)T1b);
    k_gemm_bf<<<dim3(3, 128), 256, 0, stream>>>(T1b, WT[l][2], bout_l, T2, (unsigned short*)nullptr,
                                                bn, CE, 384, 0);
    k_ln<<<bn / 4, 256, 0, stream>>>(X, T2, ln1g + l * CE, ln1b + l * CE,
                                     XB, (const float*)nullptr, (const float*)nullptr,
                                     (unsigned short*)nullptr, (unsigned short*)nullptr,
                                     (float*)nullptr);
    k_gemm_bf<<<dim3(9, 128), 256, 0, stream>>>(XB, WT[l][3], (const float*)nullptr,
                                                (float*)nullptr, Zbf, bn, CE, 1152, 1);
    k_gemm_bf<<<dim3(3, 128), 256, 0, stream>>>(Zbf, WT[l][4], (const float*)nullptr,
                                                T2, (unsigned short*)nullptr, bn, 1152, 384, 0);
    if (!last) {
      k_ln<<<bn / 4, 256, 0, stream>>>(X, T2, ln2g + l * CE, ln2b + l * CE,
                                       (unsigned short*)nullptr, POS, notp, QB, VBin,
                                       (float*)nullptr);
    } else {
      k_ln<<<bn / 4, 256, 0, stream>>>(X, T2, ln2g + l * CE, ln2b + l * CE,
                                       (unsigned short*)nullptr, (const float*)nullptr,
                                       (const float*)nullptr, (unsigned short*)nullptr,
                                       (unsigned short*)nullptr, out);
    }
  }

  k_out_cen<<<(NB * (KFG + KBG) * CE + 255) / 256, 256, 0, stream>>>(fgC, bgC, out);
}

// Round 11
// 1288.936 us; speedup vs baseline: 1.1272x; 1.1272x over previous
//
#include <hip/hip_runtime.h>
#include <hip/hip_bf16.h>
#include <math.h>

#define NB 4
#define CE 384
#define NH 12
#define DH 32
#define NPTS 9
#define NLAYERS 2
#define KFG 20
#define KBG 50
#define NITER 10
#define HDIM 64
#define WDIM 64
#define NPIX 4096
#define BNTOT (NB * NPIX)
#define NROW (NPIX + KFG + KBG)
#define NCH 16
#define TWO_PI 6.283185307179586f

#define AS1 __attribute__((address_space(1)))
#define AS3 __attribute__((address_space(3)))

typedef __attribute__((ext_vector_type(8))) short short8;
typedef __attribute__((ext_vector_type(4))) float float4v;

static __device__ __forceinline__ unsigned short f2bf(float f) {
  __hip_bfloat16 h = __float2bfloat16(f);
  return *reinterpret_cast<unsigned short*>(&h);
}
static __device__ __forceinline__ float bf2f(unsigned short u) {
  unsigned x = ((unsigned)u) << 16;
  return __uint_as_float(x);
}

__device__ __forceinline__ float4 sample4(const float* __restrict__ vb, int xi, int yi, int c) {
  bool valid = (xi >= 0) & (xi < WDIM) & (yi >= 0) & (yi < HDIM);
  int xc = min(max(xi, 0), WDIM - 1), yc = min(max(yi, 0), HDIM - 1);
  float4 g = *(const float4*)(vb + (long)(yc * WDIM + xc) * CE + c);
  if (!valid) { g.x = 0.f; g.y = 0.f; g.z = 0.f; g.w = 0.f; }
  return g;
}

// ---------------- masks ----------------
__global__ void k_masks(const float* __restrict__ pm, const float* __restrict__ sm,
                        float* padf, float* objf, float* notp, float* wfg, float* wbg) {
  int i = blockIdx.x * 256 + threadIdx.x;
  if (i >= NB * NPIX) return;
  float p  = (pm[i] == 255.0f) ? 1.f : 0.f;
  float o  = (sm[i] == 1.0f) ? 1.f : 0.f;
  float np_ = 1.f - p;
  padf[i] = p; objf[i] = o; notp[i] = np_;
  wfg[i] = o * np_;
  wbg[i] = (1.f - o) * np_;
}

// ---------------- LDS-tiled transpose s_x [B,C,N] -> X [B,N,C] ----------------
__global__ __launch_bounds__(256) void k_transpose(const float* __restrict__ sx,
                                                   float* __restrict__ X) {
  __shared__ float tile[64][65];
  int nb = blockIdx.x * 64, cb = blockIdx.y * 64, b = blockIdx.z;
  int t = threadIdx.x;
  for (int idx = t; idx < 64 * 64; idx += 256) {
    int cc = idx >> 6, nn = idx & 63;
    tile[cc][nn] = sx[((long)b * CE + cb + cc) * NPIX + nb + nn];
  }
  __syncthreads();
  for (int idx = t; idx < 64 * 64; idx += 256) {
    int nn = idx >> 6, cc = idx & 63;
    X[((long)b * NPIX + nb + nn) * CE + cb + cc] = tile[cc][nn];
  }
}

// ---------------- xsq (fp64) ----------------
__global__ void k_xsq(const float* __restrict__ X, double* __restrict__ xsq) {
  int row = blockIdx.x; int t = threadIdx.x;
  const float* xr = X + (long)row * CE;
  double s = 0.0;
  for (int i = t; i < CE; i += 64) { double v = (double)xr[i]; s += v * v; }
  #pragma unroll
  for (int o = 32; o > 0; o >>= 1) s += __shfl_down(s, o, 64);
  if (t == 0) xsq[row] = s;
}

// ---------------- pos cumsums + invdt table (LDS-staged; scans bit-identical) ----------------
__global__ __launch_bounds__(128) void k_cums(const float* __restrict__ padf,
                                              float* __restrict__ yvf,
                                              float* __restrict__ xvf,
                                              float* __restrict__ invdt) {
  __shared__ float pad_s[NPIX];
  int b = blockIdx.x; int t = threadIdx.x;
  for (int i = t; i < NPIX; i += 128) pad_s[i] = padf[b * NPIX + i];
  if (b == 0) {
    for (int c = t; c < CE; c += 128) {
      int tt = (c < 192) ? c : c - 192;
      invdt[c] = 1.0f / powf(10000.0f, (float)(2 * (tt / 2)) / 192.0f);
    }
  }
  __syncthreads();
  if (t < 64) {
    int w = t;
    float cum[64]; float tot = 0.f;
    for (int h = 0; h < 64; ++h) {
      float nm = 1.f - pad_s[h * WDIM + w];
      tot += nm; cum[h] = tot;
    }
    float sc = 1.f / (tot + 1e-6f);
    for (int h = 0; h < 64; ++h) yvf[b * NPIX + h * WDIM + w] = cum[h] * sc * TWO_PI;
  } else {
    int h = t - 64;
    float cum[64]; float tot = 0.f;
    for (int w = 0; w < 64; ++w) {
      float nm = 1.f - pad_s[h * WDIM + w];
      tot += nm; cum[w] = tot;
    }
    float sc = 1.f / (tot + 1e-6f);
    for (int w = 0; w < 64; ++w) xvf[b * NPIX + h * WDIM + w] = cum[w] * sc * TWO_PI;
  }
}

// ---------------- kmeans init (fp32 centers; X values are fp32 -> exact) ----------------
__global__ void k_kinit(const float* __restrict__ X, const float* __restrict__ wts,
                        float* __restrict__ cen, int K) {
  int b = blockIdx.x;
  __shared__ int idx[KBG];
  if (threadIdx.x == 0) {
    int cnt = 0;
    for (int n = 0; n < NPIX && cnt < K; ++n) if (wts[b * NPIX + n] > 0.f) idx[cnt++] = n;
    for (int n = 0; n < NPIX && cnt < K; ++n) if (!(wts[b * NPIX + n] > 0.f)) idx[cnt++] = n;
  }
  __syncthreads();
  for (int i = threadIdx.x; i < K * CE; i += blockDim.x) {
    int k = i / CE, c = i % CE;
    cen[((long)b * K + k) * CE + c] = X[((long)b * NPIX + idx[k]) * CE + c];
  }
}

// ---------------- kmeans distances: fp32 centers, 128 px/block, 2 px/thread ----------------
// FROZEN at the R7 config (best measured ~40-43 µs). R10 post-mortem: the 8-way
// split + 4px/thread + XCD-pin variant REGRESSED to 62 µs — occupancy measured
// 20% (not the predicted 43%), bank conflicts appeared (35840), and the 192-B
// lane stride scattered each wave's X loads across 64 cache lines. Reverted
// verbatim; do not touch k_dots again without new counter evidence.
// grid (BN/128, 7), block 256 = 64 px-pairs x 4-way channel split (h = t&3, 96 ch).
// LDS padding: HSTR4=104 floats -> h-group bases at banks {0,8,16,24}; each wave
// b128 read touches 4 unique addrs (16-lane broadcast), conflict-free.
#define HSTR4 104
#define KSTR4 416

__global__ __launch_bounds__(256) void k_dots(
    const float* __restrict__ X, const double* __restrict__ xsq,
    const float* __restrict__ cenF, const float* __restrict__ cenB,
    float* __restrict__ candD, int* __restrict__ candI, int* __restrict__ cntAll) {
  __shared__ float ct[10 * KSTR4];
  __shared__ float csq_s[10];
  int z = blockIdx.y;
  int isBg = (z >= 2) ? 1 : 0;
  int k0 = isBg ? (z - 2) * 10 : z * 10;
  int t = threadIdx.x;
  int h = t & 3;
  int n = blockIdx.x * 128 + (t >> 2) * 2;   // first of this thread's 2 pixels
  int b = blockIdx.x >> 5;                   // 32 blocks per batch
  if (blockIdx.x == 0 && z == 0) {
    for (int i = t; i < NB * (KFG + KBG); i += 256) cntAll[i] = 0;
  }
  const float* cb = (isBg ? cenB + (long)b * KBG * CE
                          : cenF + (long)b * KFG * CE) + (long)k0 * CE;
  for (int i = t; i < 10 * CE; i += 256) {
    int k = i / CE, c = i % CE;
    ct[k * KSTR4 + (c / 96) * HSTR4 + (c % 96)] = cb[i];
  }
  {
    int w = t >> 6, lane = t & 63;           // 4 waves cover centers 0..9
    for (int kk = w; kk < 10; kk += 4) {
      double s = 0.0;
      for (int c = lane; c < CE; c += 64) { double v = (double)cb[kk * CE + c]; s += v * v; }
      #pragma unroll
      for (int o = 32; o > 0; o >>= 1) s += __shfl_down(s, o, 64);
      if (lane == 0) csq_s[kk] = (float)s;
    }
  }
  __syncthreads();
  const float* xr = X + (long)n * CE + h * 96;
  const float* cth = ct + h * HSTR4;
  float acc[10][2];
  #pragma unroll
  for (int k = 0; k < 10; ++k) { acc[k][0] = 0.f; acc[k][1] = 0.f; }
  for (int c0 = 0; c0 < 96; c0 += 8) {
    float4 xa[2], xb[2];
    #pragma unroll
    for (int p = 0; p < 2; ++p) {
      xa[p] = *(const float4*)(xr + p * CE + c0);
      xb[p] = *(const float4*)(xr + p * CE + c0 + 4);
    }
    #pragma unroll
    for (int k = 0; k < 10; ++k) {
      float4 c1 = *(const float4*)(&cth[k * KSTR4 + c0]);       // 4 unique addrs/wave
      float4 c2 = *(const float4*)(&cth[k * KSTR4 + c0 + 4]);
      #pragma unroll
      for (int p = 0; p < 2; ++p) {
        float a = acc[k][p];
        a += xa[p].x * c1.x; a += xa[p].y * c1.y;
        a += xa[p].z * c1.z; a += xa[p].w * c1.w;
        a += xb[p].x * c2.x; a += xb[p].y * c2.y;
        a += xb[p].z * c2.z; a += xb[p].w * c2.w;
        acc[k][p] = a;
      }
    }
  }
  // combine the 4 channel-quarter partials (lanes t, t^1, t^2 are same-wave)
  #pragma unroll
  for (int k = 0; k < 10; ++k)
    #pragma unroll
    for (int p = 0; p < 2; ++p) {
      float a = acc[k][p];
      a += __shfl_xor(a, 1, 64);
      a += __shfl_xor(a, 2, 64);
      acc[k][p] = a;
    }
  if (h == 0) {
    #pragma unroll
    for (int p = 0; p < 2; ++p) {
      float qn = (float)xsq[n + p];
      float best = 3.0e38f; int bi = 0;
      #pragma unroll
      for (int k = 0; k < 10; ++k) {
        float d = qn - 2.0f * acc[k][p] + csq_s[k];
        if (d < best) { best = d; bi = k0 + k; }
      }
      long gi = (long)z * BNTOT + n + p;
      candD[gi] = best;
      candI[gi] = bi;
    }
  }
}

// ---------------- final argmin over 7 chunk candidates + bucket scatter ----------------
// One thread per pixel. FG candidates are chunks z=0..1, BG z=2..6. Strict < in ascending
// z preserves the reference's earliest-index argmin. Pixels are scattered into per-cluster
// index lists; within-cluster order is nondeterministic (atomic slots) which only perturbs
// the fp64 summation order in k_cacc (~1 ulp, far below tolerance).
__global__ void k_asn(const float* __restrict__ candD, const int* __restrict__ candI,
                      const float* __restrict__ wfg, const float* __restrict__ wbg,
                      int* __restrict__ listF, int* __restrict__ listB,
                      int* __restrict__ cntAll) {
  int n = blockIdx.x * 256 + threadIdx.x;
  if (n >= BNTOT) return;
  int b = n >> 12;
  int nn = n & (NPIX - 1);
  float wf = wfg[n], wb = wbg[n];
  if (wf > 0.f) {
    float d0 = candD[n]; int i0 = candI[n];
    float d1 = candD[(long)BNTOT + n];
    if (d1 < d0) { d0 = d1; i0 = candI[(long)BNTOT + n]; }
    int slot = atomicAdd(&cntAll[b * KFG + i0], 1);
    listF[((long)b * KFG + i0) * NPIX + slot] = nn;
  } else if (wb > 0.f) {
    float d0 = candD[2L * BNTOT + n]; int i0 = candI[2L * BNTOT + n];
    #pragma unroll
    for (int z = 3; z < 7; ++z) {
      float dz = candD[(long)z * BNTOT + n];
      if (dz < d0) { d0 = dz; i0 = candI[(long)z * BNTOT + n]; }
    }
    int slot = atomicAdd(&cntAll[NB * KFG + b * KBG + i0], 1);
    listB[((long)b * KBG + i0) * NPIX + slot] = nn;
  }
}

// ---------------- chunk-parallel gather-accumulate per cluster ----------------
// R7 post-mortem: single-block-per-cluster k_cacc was a STRAGGLER kernel — 45.4 µs
// at 1.7% occupancy. Fix (R9, verified): split each cluster's list into NCH=16
// contiguous chunks; grid (3, 70, NB*NCH) = 13,440 blocks; fp64 partial per chunk;
// k_cred sums in fixed chunk order. PC aliases V (dead during k-means) to stay
// inside the workspace budget (R8 post-mortem: appending 13.8 MB killed the
// container twice -> ws_size overflow -> OOB fault).
__global__ __launch_bounds__(128) void k_cacc(
    const float* __restrict__ X,
    const int* __restrict__ listF, const int* __restrict__ listB,
    const int* __restrict__ cntAll,
    double* __restrict__ PC) {
  __shared__ int ls[256];    // cs = ceil(4096/16) = 256 max
  int slice = blockIdx.x;    // 0..2
  int kq = blockIdx.y;       // 0..KFG+KBG-1
  int zz = blockIdx.z;       // b*NCH + ch
  int b = zz / NCH, ch = zz % NCH;
  int t = threadIdx.x;
  int c = slice * 128 + t;
  const int* list; int cnt;
  if (kq < KFG) {
    cnt = cntAll[b * KFG + kq];
    list = listF + ((long)b * KFG + kq) * NPIX;
  } else {
    int k = kq - KFG;
    cnt = cntAll[NB * KFG + b * KBG + k];
    list = listB + ((long)b * KBG + k) * NPIX;
  }
  int cs = (cnt + NCH - 1) / NCH;
  int i0 = ch * cs;
  int i1 = min(i0 + cs, cnt);
  int m = i1 - i0;                       // may be <= 0 -> partial stays 0
  for (int i = t; i < m; i += 128) ls[i] = list[i0 + i];
  __syncthreads();
  const float* Xb = X + (long)b * NPIX * CE;
  double acc = 0.0;
  int i = 0;
  for (; i + 4 <= m; i += 4) {
    int n0 = ls[i], n1 = ls[i + 1], n2 = ls[i + 2], n3 = ls[i + 3];
    float v0 = Xb[(long)n0 * CE + c];
    float v1 = Xb[(long)n1 * CE + c];
    float v2 = Xb[(long)n2 * CE + c];
    float v3 = Xb[(long)n3 * CE + c];
    acc += (double)v0; acc += (double)v1; acc += (double)v2; acc += (double)v3;
  }
  for (; i < m; ++i) acc += (double)Xb[(long)ls[i] * CE + c];
  // PC layout: [ch][b*(KFG+KBG)+kq][c]
  PC[((long)ch * (NB * (KFG + KBG)) + (long)b * (KFG + KBG) + kq) * CE + c] = acc;
}

// ---------------- reduce chunk partials -> center update (deterministic) ----------------
__global__ void k_cred(const double* __restrict__ PC, const int* __restrict__ cntAll,
                       const float* __restrict__ srcF, float* __restrict__ dstF,
                       const float* __restrict__ srcB, float* __restrict__ dstB) {
  int i = blockIdx.x * 256 + threadIdx.x;
  const int tot = NB * (KFG + KBG) * CE;
  if (i >= tot) return;
  int c = i % CE;
  int r = i / CE;                        // b*(KFG+KBG)+kq
  int kq = r % (KFG + KBG);
  int b = r / (KFG + KBG);
  const long stride = (long)NB * (KFG + KBG) * CE;
  double s = 0.0;
  #pragma unroll
  for (int ch = 0; ch < NCH; ++ch) s += PC[(long)ch * stride + (long)r * CE + c];
  if (kq < KFG) {
    int cnt = cntAll[b * KFG + kq];
    long o = ((long)b * KFG + kq) * CE + c;
    dstF[o] = (cnt > 0) ? (float)(s / (double)cnt) : srcF[o];
  } else {
    int k = kq - KFG;
    int cnt = cntAll[NB * KFG + b * KBG + k];
    long o = ((long)b * KBG + k) * CE + c;
    dstB[o] = (cnt > 0) ? (float)(s / (double)cnt) : srcB[o];
  }
}

// ---------------- fused pos + bf16 staging ----------------
__global__ void k_cvtQV(const float* __restrict__ X,
                        const float* __restrict__ yvf, const float* __restrict__ xvf,
                        const float* __restrict__ invdt, const float* __restrict__ notp,
                        float* __restrict__ POS,
                        unsigned short* __restrict__ QB, unsigned short* __restrict__ VBin) {
  long i = (long)blockIdx.x * 256 + threadIdx.x;
  if (i >= (long)NB * NPIX * CE) return;
  int c = (int)(i % CE);
  long row = i / CE;
  float p = (c < 192) ? yvf[row] : xvf[row];
  float v = p * invdt[c];
  int tt = (c < 192) ? c : c - 192;
  float r = (tt & 1) ? cosf(v) : sinf(v);
  POS[i] = r;
  float x = X[i];
  QB[i] = f2bf(x + r);
  VBin[i] = f2bf(x * notp[row]);
}

// ---------------- fused per-layer weight convert/transpose + concat bias ----------------
__global__ void k_cvtW_all(
    const float* __restrict__ Wv_l, const float* __restrict__ Woff_l,
    const float* __restrict__ Wa_l, const float* __restrict__ Wout_l,
    const float* __restrict__ Wf1_l, const float* __restrict__ Wf2_l,
    const float* __restrict__ boff_l, const float* __restrict__ ba_l,
    unsigned short* __restrict__ W0, unsigned short* __restrict__ W1,
    unsigned short* __restrict__ W3, unsigned short* __restrict__ W4,
    unsigned short* __restrict__ W5, float* __restrict__ biasCat) {
  int i = blockIdx.x * 256 + threadIdx.x;
  const int S = 147456, SF = 442368;
  if (i < S) {
    int n = i / 384, k = i % 384;
    W0[i] = f2bf(Wv_l[(long)k * 384 + n]);
  } else if (i < 2 * S) {
    int j = i - S; int n = j / 384, k = j % 384;
    float v = 0.f;
    if (n < 216) v = Woff_l[(long)k * 216 + n];
    else if (n < 324) v = Wa_l[(long)k * 108 + (n - 216)];
    W1[j] = f2bf(v);
  } else if (i < 3 * S) {
    int j = i - 2 * S; int n = j / 384, k = j % 384;
    W3[j] = f2bf(Wout_l[(long)k * 384 + n]);
  } else if (i < 3 * S + SF) {
    int j = i - 3 * S; int n = j / 384, k = j % 384;
    W4[j] = f2bf(Wf1_l[(long)k * 1152 + n]);
  } else if (i < 3 * S + 2 * SF) {
    int j = i - 3 * S - SF; int n = j / 1152, k = j % 1152;
    W5[j] = f2bf(Wf2_l[(long)k * 384 + n]);
  } else if (i < 3 * S + 2 * SF + 324) {
    int j = i - 3 * S - 2 * SF;
    biasCat[j] = (j < 216) ? boff_l[j] : ba_l[j - 216];
  }
}

// ---------------- bf16 MFMA GEMM: C = A @ Bt^T (+bias)(+relu) ----------------
// Staging via global_load_lds width=16 (DMA direct to LDS, contiguous 64B rows).
// XCD-bijective block remap (T1): pins by%8 == xcd so blocks sharing an A-row-panel
// land on one XCD's L2 (verified R9: FFN2 FETCH 56.7 -> 22.2 MB, FFN1 -> 12.3 MB).
// NEW (R11): LDS XOR-swizzle to kill the measured 1.77M bank-conflict cycles per
// FFN dispatch (R9 counters). Old read As[row*32 + half*8]: 64-B row stride puts
// the 16 lr-lanes on only 2 four-bank groups -> 8-way conflict (G4/m136 ~2.94x).
// Swizzle (rule #21, both-sides): global_load_lds writes LINEARLY, so permute the
// GLOBAL source chunk: LDS slot c (row r=c>>2) receives part' = (c&3) ^ ((r>>1)&3);
// reads apply the same involution: half -> half ^ ((row>>1)&3). Bank check: even
// rows start at {0,4,8,12}, odd at {16,20,24,28} -> 16 lanes cover all 32 banks
// exactly 2x = free. Coalescing unchanged (permutation within each 64-B row).
// Numerics bit-identical (layout-only).
__global__ __launch_bounds__(256) void k_gemm_bf(
    const unsigned short* __restrict__ A, const unsigned short* __restrict__ Bt,
    const float* __restrict__ bias, float* __restrict__ Cf, unsigned short* __restrict__ Cb,
    int M, int K, int N, int relu) {
  __shared__ unsigned short As[128 * 32];
  __shared__ unsigned short Bs[128 * 32];
  int bx, by;
  {
    int gx = gridDim.x;
    int q = blockIdx.y * gx + blockIdx.x;
    if ((gridDim.y & 7) == 0) {
      int xcd = q & 7;
      int r = q >> 3;
      bx = r % gx;
      by = xcd + 8 * (r / gx);
    } else { bx = blockIdx.x; by = blockIdx.y; }
  }
  int m0 = by * 128, n0 = bx * 128;
  int t = threadIdx.x;
  int w = t >> 6, l = t & 63;
  int wm = w >> 1, wn = w & 1;
  int half = l >> 4, lr = l & 15;
  float4v acc[4][4] = {};
  for (int k0 = 0; k0 < K; k0 += 32) {
    #pragma unroll
    for (int i = 0; i < 2; ++i) {
      int c = w * 64 + i * 256 + l;           // 0..511 = LDS slot index
      int r = c >> 2;
      int part = (c & 3) ^ ((r >> 1) & 3);    // swizzled global source chunk
      int ldsOff = (w * 64 + i * 256) * 8;    // shorts; lane adds l*16 bytes
      __builtin_amdgcn_global_load_lds(
          (const AS1 unsigned int*)(A + (size_t)(m0 + r) * K + k0 + part * 8),
          (AS3 unsigned int*)(As + ldsOff), 16, 0, 0);
      __builtin_amdgcn_global_load_lds(
          (const AS1 unsigned int*)(Bt + (size_t)(n0 + r) * K + k0 + part * 8),
          (AS3 unsigned int*)(Bs + ldsOff), 16, 0, 0);
    }
    __syncthreads();
    short8 af[4], bfr[4];
    #pragma unroll
    for (int am = 0; am < 4; ++am) {
      int arow = wm * 64 + am * 16 + lr;
      af[am] = *(const short8*)(&As[arow * 32 + (half ^ ((arow >> 1) & 3)) * 8]);
    }
    #pragma unroll
    for (int bn = 0; bn < 4; ++bn) {
      int brow = wn * 64 + bn * 16 + lr;
      bfr[bn] = *(const short8*)(&Bs[brow * 32 + (half ^ ((brow >> 1) & 3)) * 8]);
    }
    #pragma unroll
    for (int am = 0; am < 4; ++am)
      #pragma unroll
      for (int bn = 0; bn < 4; ++bn)
        acc[am][bn] = __builtin_amdgcn_mfma_f32_16x16x32_bf16(af[am], bfr[bn], acc[am][bn], 0, 0, 0);
    __syncthreads();
  }
  #pragma unroll
  for (int am = 0; am < 4; ++am) {
    #pragma unroll
    for (int bn = 0; bn < 4; ++bn) {
      int gc = n0 + wn * 64 + bn * 16 + lr;
      if (gc < N) {
        float bv = bias ? bias[gc] : 0.f;
        int gr0 = m0 + wm * 64 + am * 16 + half * 4;
        #pragma unroll
        for (int r = 0; r < 4; ++r) {
          float v = acc[am][bn][r] + bv;
          if (relu) v = fmaxf(v, 0.f);
          size_t oi = (size_t)(gr0 + r) * N + gc;
          if (Cf) Cf[oi] = v;
          else Cb[oi] = f2bf(v);
        }
      }
    }
  }
}

// ---------------- coords+softmax: one thread per (row, head) ----------------
__global__ void k_coords(const unsigned short* __restrict__ OAB, float4* __restrict__ CRD) {
  int idx = blockIdx.x * 256 + threadIdx.x;
  if (idx >= NB * NPIX * NH) return;
  int row = idx / NH, h = idx % NH;
  int n = row & (NPIX - 1);
  int hh = n >> 6, ww = n & 63;
  float refx = ((float)ww + 0.5f) / (float)WDIM;
  float refy = ((float)hh + 0.5f) / (float)HDIM;
  const unsigned short* oab = OAB + (size_t)row * 324;
  float f[NPTS];
  #pragma unroll
  for (int j = 0; j < NPTS; ++j) f[j] = bf2f(oab[216 + h * 9 + j]);
  float m = f[0];
  #pragma unroll
  for (int j = 1; j < NPTS; ++j) m = fmaxf(m, f[j]);
  float s = 0.f;
  #pragma unroll
  for (int j = 0; j < NPTS; ++j) { f[j] = expf(f[j] - m); s += f[j]; }
  float inv = 1.f / s;
  float4* crd = CRD + (size_t)row * 108 + h * 9;
  #pragma unroll
  for (int p = 0; p < NPTS; ++p) {
    float ox = bf2f(oab[h * 18 + p * 2 + 0]);
    float oy = bf2f(oab[h * 18 + p * 2 + 1]);
    float lx = refx + ox / (float)WDIM;
    float ly = refy + oy / (float)HDIM;
    float xs = lx * (float)WDIM - 0.5f;
    float ys = ly * (float)HDIM - 0.5f;
    float x0f = floorf(xs), y0f = floorf(ys);
    int x0 = (int)x0f, y0 = (int)y0f;
    float4 o;
    o.x = xs - x0f;
    o.y = ys - y0f;
    o.z = f[p] * inv;
    o.w = __int_as_float((y0 << 16) | (x0 & 0xFFFF));
    crd[p] = o;
  }
}

// ---------------- gather: 4 channels per thread, float4 gathers ----------------
__global__ __launch_bounds__(256) void k_gather(
    const float* __restrict__ V, const float4* __restrict__ CRD,
    uint2* __restrict__ ATTu) {
  int idx = blockIdx.x * 256 + threadIdx.x;
  if (idx >= NB * NPIX * (CE / 4)) return;
  int row = idx / (CE / 4), cq = idx % (CE / 4);
  int c = cq * 4;
  int h = c >> 5;
  int b = row >> 12;
  const float* vb = V + (size_t)b * NPIX * CE;
  const float4* crd = CRD + (size_t)row * 108 + h * 9;
  float a0 = 0.f, a1 = 0.f, a2 = 0.f, a3 = 0.f;
  #pragma unroll
  for (int p = 0; p < NPTS; ++p) {
    float4 o = crd[p];
    int pk = __float_as_int(o.w);
    int x0 = (int)(short)(pk & 0xFFFF);
    int y0 = pk >> 16;
    float wx = o.x, wy = o.y, aw = o.z;
    float4 g00 = sample4(vb, x0,     y0,     c);
    float4 g01 = sample4(vb, x0 + 1, y0,     c);
    float4 g10 = sample4(vb, x0,     y0 + 1, c);
    float4 g11 = sample4(vb, x0 + 1, y0 + 1, c);
    float w00 = (1.f - wx) * (1.f - wy), w01 = wx * (1.f - wy);
    float w10 = (1.f - wx) * wy,         w11 = wx * wy;
    a0 += aw * (g00.x * w00 + g01.x * w01 + g10.x * w10 + g11.x * w11);
    a1 += aw * (g00.y * w00 + g01.y * w01 + g10.y * w10 + g11.y * w11);
    a2 += aw * (g00.z * w00 + g01.z * w01 + g10.z * w10 + g11.z * w11);
    a3 += aw * (g00.w * w00 + g01.w * w01 + g10.w * w10 + g11.w * w11);
  }
  uint2 pk2;
  pk2.x = (unsigned)f2bf(a0) | ((unsigned)f2bf(a1) << 16);
  pk2.y = (unsigned)f2bf(a2) | ((unsigned)f2bf(a3) << 16);
  ATTu[(size_t)row * (CE / 4) + cq] = pk2;
}

// ---------------- LayerNorm(X + T), 4 rows/block, fused epilogues ----------------
__global__ __launch_bounds__(256) void k_ln(
    float* __restrict__ X, const float* __restrict__ T,
    const float* __restrict__ g, const float* __restrict__ bb,
    unsigned short* __restrict__ xbOut,
    const float* __restrict__ posp, const float* __restrict__ notp,
    unsigned short* __restrict__ qb, unsigned short* __restrict__ vbin,
    float* __restrict__ outp) {
  int t = threadIdx.x;
  int row = blockIdx.x * 4 + (t >> 6);
  int lane = t & 63;
  float* xr = X + (long)row * CE;
  const float* tr = T + (long)row * CE;
  float v[6]; float s = 0.f;
  #pragma unroll
  for (int i = 0; i < 6; ++i) { v[i] = xr[lane + 64 * i] + tr[lane + 64 * i]; s += v[i]; }
  #pragma unroll
  for (int o = 32; o > 0; o >>= 1) s += __shfl_down(s, o, 64);
  s = __shfl(s, 0, 64);
  float m = s / (float)CE;
  float var = 0.f;
  #pragma unroll
  for (int i = 0; i < 6; ++i) { float d = v[i] - m; var += d * d; }
  #pragma unroll
  for (int o = 32; o > 0; o >>= 1) var += __shfl_down(var, o, 64);
  var = __shfl(var, 0, 64);
  float rst = rsqrtf(var / (float)CE + 1e-5f);
  float nprow = notp ? notp[row] : 0.f;
  int b = row >> 12, n = row & (NPIX - 1);
  #pragma unroll
  for (int i = 0; i < 6; ++i) {
    int c = lane + 64 * i;
    float xn = (v[i] - m) * rst * g[c] + bb[c];
    if (outp) outp[((long)b * NROW + n) * CE + c] = xn;
    else xr[c] = xn;
    if (xbOut) xbOut[(long)row * CE + c] = f2bf(xn);
    if (qb) {
      qb[(long)row * CE + c] = f2bf(xn + posp[(long)row * CE + c]);
      vbin[(long)row * CE + c] = f2bf(xn * nprow);
    }
  }
}

// ---------------- centers -> output ----------------
__global__ void k_out_cen(const float* __restrict__ fg, const float* __restrict__ bg,
                          float* __restrict__ out) {
  int i = blockIdx.x * 256 + threadIdx.x;
  const int tot = NB * (KFG + KBG) * CE;
  if (i >= tot) return;
  int c = i % CE;
  int r = i / CE;
  int rr = r % (KFG + KBG);
  int b = r / (KFG + KBG);
  float v;
  if (rr < KFG) v = fg[((long)b * KFG + rr) * CE + c];
  else v = bg[((long)b * KBG + (rr - KFG)) * CE + c];
  out[((long)b * NROW + NPIX + rr) * CE + c] = v;
}

extern "C" void kernel_launch(void* const* d_in, const int* in_sizes, int n_in,
                              void* d_out, int out_size, void* d_ws, size_t ws_size,
                              hipStream_t stream) {
  (void)in_sizes; (void)n_in; (void)out_size; (void)ws_size;
  const float* s_x  = (const float*)d_in[0];
  const float* s_pm = (const float*)d_in[1];
  const float* s_sm = (const float*)d_in[2];
  const float* Wv   = (const float*)d_in[3];
  const float* bv   = (const float*)d_in[4];
  const float* Woff = (const float*)d_in[5];
  const float* boff = (const float*)d_in[6];
  const float* Wa   = (const float*)d_in[7];
  const float* ba   = (const float*)d_in[8];
  const float* Wout = (const float*)d_in[9];
  const float* bout = (const float*)d_in[10];
  const float* ln1g = (const float*)d_in[11];
  const float* ln1b = (const float*)d_in[12];
  const float* Wf1  = (const float*)d_in[13];
  const float* Wf2  = (const float*)d_in[14];
  const float* ln2g = (const float*)d_in[15];
  const float* ln2b = (const float*)d_in[16];
  float* out = (float*)d_out;
  char* pb = (char*)d_ws;

  const long BN  = (long)NB * NPIX;      // 16384
  const long BNC = BN * CE;              // 6291456

  float* X    = (float*)pb; pb += BNC * 4;
  float* POS  = (float*)pb; pb += BNC * 4;
  float* V    = (float*)pb; pb += BNC * 4;
  float* T2   = (float*)pb; pb += BNC * 4;
  double* PC  = (double*)V;   // 13.8 MB chunk partials alias V (dead during k-means;
                              // first written by layer-0 GEMM). R0 precedent: PF/PB
                              // aliased V/T2 under a "< 24 MB" budget note.
  unsigned short* QB   = (unsigned short*)pb; pb += BNC * 2;
  unsigned short* VBin = (unsigned short*)pb; pb += BNC * 2;
  unsigned short* T1b  = (unsigned short*)pb; pb += BNC * 2;
  unsigned short* Zbf  = QB;   // FFN hidden aliases QB+VBin+T1b
  unsigned short* XB   = (unsigned short*)pb; pb += BNC * 2;
  unsigned short* OAB  = (unsigned short*)pb; pb += BN * 324 * 2;
  float4* CRD = (float4*)pb; pb += BN * 108 * 16;
  const int S_W = 147456, S_F = 442368;
  unsigned short* WT[NLAYERS][5];
  float* biasCat[NLAYERS];
  for (int l = 0; l < NLAYERS; ++l) {
    WT[l][0] = (unsigned short*)pb; pb += S_W * 2;
    WT[l][1] = (unsigned short*)pb; pb += S_W * 2;
    WT[l][2] = (unsigned short*)pb; pb += S_W * 2;
    WT[l][3] = (unsigned short*)pb; pb += S_F * 2;
    WT[l][4] = (unsigned short*)pb; pb += S_F * 2;
    biasCat[l] = (float*)pb; pb += 324 * 4;
  }
  float* padf = (float*)pb; pb += BN * 4;
  float* objf = (float*)pb; pb += BN * 4;
  float* notp = (float*)pb; pb += BN * 4;
  float* wfg  = (float*)pb; pb += BN * 4;
  float* wbg  = (float*)pb; pb += BN * 4;
  float* yvf  = (float*)pb; pb += BN * 4;
  float* xvf  = (float*)pb; pb += BN * 4;
  float* invdt = (float*)pb; pb += CE * 4;
  pb = (char*)(((size_t)pb + 7) & ~(size_t)7);
  double* xsq   = (double*)pb; pb += BN * 8;
  float* candD = (float*)pb; pb += BN * 7 * 4;            // per-chunk best distance (fp32)
  float* cFgA = (float*)pb; pb += (long)NB * KFG * CE * 4;  // fp32 centers
  float* cFgB = (float*)pb; pb += (long)NB * KFG * CE * 4;
  float* cBgA = (float*)pb; pb += (long)NB * KBG * CE * 4;
  float* cBgB = (float*)pb; pb += (long)NB * KBG * CE * 4;
  int* candI  = (int*)pb; pb += BN * 7 * 4;               // per-chunk best global-k
  int* cntAll = (int*)pb; pb += NB * (KFG + KBG) * 4;     // cluster counts (FG then BG)
  int* listF  = (int*)pb; pb += (long)NB * KFG * NPIX * 4;
  int* listB  = (int*)pb; pb += (long)NB * KBG * NPIX * 4;

  int bn = (int)BN;
  int cvtBlocks = (int)((BNC + 255) / 256);

  k_masks<<<(bn + 255) / 256, 256, 0, stream>>>(s_pm, s_sm, padf, objf, notp, wfg, wbg);
  k_transpose<<<dim3(NPIX / 64, CE / 64, NB), 256, 0, stream>>>(s_x, X);
  k_xsq<<<bn, 64, 0, stream>>>(X, xsq);
  k_cums<<<NB, 128, 0, stream>>>(padf, yvf, xvf, invdt);
  k_cvtQV<<<cvtBlocks, 256, 0, stream>>>(X, yvf, xvf, invdt, notp, POS, QB, VBin);

  const int CVTW_TOT = 3 * S_W + 2 * S_F + 324;
  for (int l = 0; l < NLAYERS; ++l) {
    k_cvtW_all<<<(CVTW_TOT + 255) / 256, 256, 0, stream>>>(
        Wv + (long)l * CE * CE, Woff + (long)l * CE * 216, Wa + (long)l * CE * 108,
        Wout + (long)l * CE * CE, Wf1 + (long)l * CE * 1152, Wf2 + (long)l * 1152 * CE,
        boff + l * 216, ba + l * 108,
        WT[l][0], WT[l][1], WT[l][2], WT[l][3], WT[l][4], biasCat[l]);
  }

  // ---- kmeans: dots(+chunk argmin) -> asn(bucket lists) -> cacc(chunk partials) -> cred ----
  float *srcF = cFgA, *dstF = cFgB, *srcB = cBgA, *dstB = cBgB;
  k_kinit<<<NB, 256, 0, stream>>>(X, wfg, srcF, KFG);
  k_kinit<<<NB, 256, 0, stream>>>(X, wbg, srcB, KBG);
  const int credBlocks = (NB * (KFG + KBG) * CE + 255) / 256;
  for (int it = 0; it < NITER; ++it) {
    k_dots<<<dim3(bn / 128, 7), 256, 0, stream>>>(X, xsq, srcF, srcB, candD, candI, cntAll);
    k_asn<<<(bn + 255) / 256, 256, 0, stream>>>(candD, candI, wfg, wbg, listF, listB, cntAll);
    k_cacc<<<dim3(3, KFG + KBG, NB * NCH), 128, 0, stream>>>(
        X, listF, listB, cntAll, PC);
    k_cred<<<credBlocks, 256, 0, stream>>>(PC, cntAll, srcF, dstF, srcB, dstB);
    float* tmp;
    tmp = srcF; srcF = dstF; dstF = tmp;
    tmp = srcB; srcB = dstB; dstB = tmp;
  }
  float* fgC = srcF; float* bgC = srcB;

  // ---- layers ----
  for (int l = 0; l < NLAYERS; ++l) {
    const float* bv_l   = bv   + l * CE;
    const float* bout_l = bout + l * CE;
    int last = (l == NLAYERS - 1);

    k_gemm_bf<<<dim3(3, 128), 256, 0, stream>>>(VBin, WT[l][0], bv_l, V, (unsigned short*)nullptr,
                                                bn, CE, 384, 0);
    k_gemm_bf<<<dim3(3, 128), 256, 0, stream>>>(QB, WT[l][1], biasCat[l], (float*)nullptr, OAB,
                                                bn, CE, 324, 0);
    k_coords<<<(bn * NH + 255) / 256, 256, 0, stream>>>(OAB, CRD);
    k_gather<<<(bn * (CE / 4) + 255) / 256, 256, 0, stream>>>(V, CRD, (uint2*)T1b);
    k_gemm_bf<<<dim3(3, 128), 256, 0, stream>>>(T1b, WT[l][2], bout_l, T2, (unsigned short*)nullptr,
                                                bn, CE, 384, 0);
    k_ln<<<bn / 4, 256, 0, stream>>>(X, T2, ln1g + l * CE, ln1b + l * CE,
                                     XB, (const float*)nullptr, (const float*)nullptr,
                                     (unsigned short*)nullptr, (unsigned short*)nullptr,
                                     (float*)nullptr);
    k_gemm_bf<<<dim3(9, 128), 256, 0, stream>>>(XB, WT[l][3], (const float*)nullptr,
                                                (float*)nullptr, Zbf, bn, CE, 1152, 1);
    k_gemm_bf<<<dim3(3, 128), 256, 0, stream>>>(Zbf, WT[l][4], (const float*)nullptr,
                                                T2, (unsigned short*)nullptr, bn, 1152, 384, 0);
    if (!last) {
      k_ln<<<bn / 4, 256, 0, stream>>>(X, T2, ln2g + l * CE, ln2b + l * CE,
                                       (unsigned short*)nullptr, POS, notp, QB, VBin,
                                       (float*)nullptr);
    } else {
      k_ln<<<bn / 4, 256, 0, stream>>>(X, T2, ln2g + l * CE, ln2b + l * CE,
                                       (unsigned short*)nullptr, (const float*)nullptr,
                                       (const float*)nullptr, (unsigned short*)nullptr,
                                       (unsigned short*)nullptr, out);
    }
  }

  k_out_cen<<<(NB * (KFG + KBG) * CE + 255) / 256, 256, 0, stream>>>(fgC, bgC, out);
}

// Round 12
// 1263.709 us; speedup vs baseline: 1.1497x; 1.0200x over previous
//
#include <hip/hip_runtime.h>
#include <hip/hip_bf16.h>
#include <math.h>

#define NB 4
#define CE 384
#define NH 12
#define DH 32
#define NPTS 9
#define NLAYERS 2
#define KFG 20
#define KBG 50
#define NITER 10
#define HDIM 64
#define WDIM 64
#define NPIX 4096
#define BNTOT (NB * NPIX)
#define NROW (NPIX + KFG + KBG)
#define NCH 16
#define TWO_PI 6.283185307179586f

#define AS1 __attribute__((address_space(1)))
#define AS3 __attribute__((address_space(3)))

typedef __attribute__((ext_vector_type(8))) short short8;
typedef __attribute__((ext_vector_type(4))) float float4v;

static __device__ __forceinline__ unsigned short f2bf(float f) {
  __hip_bfloat16 h = __float2bfloat16(f);
  return *reinterpret_cast<unsigned short*>(&h);
}
static __device__ __forceinline__ float bf2f(unsigned short u) {
  unsigned x = ((unsigned)u) << 16;
  return __uint_as_float(x);
}

__device__ __forceinline__ float4 sample4(const float* __restrict__ vb, int xi, int yi, int c) {
  bool valid = (xi >= 0) & (xi < WDIM) & (yi >= 0) & (yi < HDIM);
  int xc = min(max(xi, 0), WDIM - 1), yc = min(max(yi, 0), HDIM - 1);
  float4 g = *(const float4*)(vb + (long)(yc * WDIM + xc) * CE + c);
  if (!valid) { g.x = 0.f; g.y = 0.f; g.z = 0.f; g.w = 0.f; }
  return g;
}

// ---------------- masks ----------------
__global__ void k_masks(const float* __restrict__ pm, const float* __restrict__ sm,
                        float* padf, float* objf, float* notp, float* wfg, float* wbg) {
  int i = blockIdx.x * 256 + threadIdx.x;
  if (i >= NB * NPIX) return;
  float p  = (pm[i] == 255.0f) ? 1.f : 0.f;
  float o  = (sm[i] == 1.0f) ? 1.f : 0.f;
  float np_ = 1.f - p;
  padf[i] = p; objf[i] = o; notp[i] = np_;
  wfg[i] = o * np_;
  wbg[i] = (1.f - o) * np_;
}

// ---------------- LDS-tiled transpose s_x [B,C,N] -> X [B,N,C] ----------------
__global__ __launch_bounds__(256) void k_transpose(const float* __restrict__ sx,
                                                   float* __restrict__ X) {
  __shared__ float tile[64][65];
  int nb = blockIdx.x * 64, cb = blockIdx.y * 64, b = blockIdx.z;
  int t = threadIdx.x;
  for (int idx = t; idx < 64 * 64; idx += 256) {
    int cc = idx >> 6, nn = idx & 63;
    tile[cc][nn] = sx[((long)b * CE + cb + cc) * NPIX + nb + nn];
  }
  __syncthreads();
  for (int idx = t; idx < 64 * 64; idx += 256) {
    int nn = idx >> 6, cc = idx & 63;
    X[((long)b * NPIX + nb + nn) * CE + cb + cc] = tile[cc][nn];
  }
}

// ---------------- xsq (fp64) ----------------
__global__ void k_xsq(const float* __restrict__ X, double* __restrict__ xsq) {
  int row = blockIdx.x; int t = threadIdx.x;
  const float* xr = X + (long)row * CE;
  double s = 0.0;
  for (int i = t; i < CE; i += 64) { double v = (double)xr[i]; s += v * v; }
  #pragma unroll
  for (int o = 32; o > 0; o >>= 1) s += __shfl_down(s, o, 64);
  if (t == 0) xsq[row] = s;
}

// ---------------- pos cumsums + invdt table (LDS-staged; scans bit-identical) ----------------
__global__ __launch_bounds__(128) void k_cums(const float* __restrict__ padf,
                                              float* __restrict__ yvf,
                                              float* __restrict__ xvf,
                                              float* __restrict__ invdt) {
  __shared__ float pad_s[NPIX];
  int b = blockIdx.x; int t = threadIdx.x;
  for (int i = t; i < NPIX; i += 128) pad_s[i] = padf[b * NPIX + i];
  if (b == 0) {
    for (int c = t; c < CE; c += 128) {
      int tt = (c < 192) ? c : c - 192;
      invdt[c] = 1.0f / powf(10000.0f, (float)(2 * (tt / 2)) / 192.0f);
    }
  }
  __syncthreads();
  if (t < 64) {
    int w = t;
    float cum[64]; float tot = 0.f;
    for (int h = 0; h < 64; ++h) {
      float nm = 1.f - pad_s[h * WDIM + w];
      tot += nm; cum[h] = tot;
    }
    float sc = 1.f / (tot + 1e-6f);
    for (int h = 0; h < 64; ++h) yvf[b * NPIX + h * WDIM + w] = cum[h] * sc * TWO_PI;
  } else {
    int h = t - 64;
    float cum[64]; float tot = 0.f;
    for (int w = 0; w < 64; ++w) {
      float nm = 1.f - pad_s[h * WDIM + w];
      tot += nm; cum[w] = tot;
    }
    float sc = 1.f / (tot + 1e-6f);
    for (int w = 0; w < 64; ++w) xvf[b * NPIX + h * WDIM + w] = cum[w] * sc * TWO_PI;
  }
}

// ---------------- kmeans init (fp32 centers; X values are fp32 -> exact) ----------------
__global__ void k_kinit(const float* __restrict__ X, const float* __restrict__ wts,
                        float* __restrict__ cen, int K) {
  int b = blockIdx.x;
  __shared__ int idx[KBG];
  if (threadIdx.x == 0) {
    int cnt = 0;
    for (int n = 0; n < NPIX && cnt < K; ++n) if (wts[b * NPIX + n] > 0.f) idx[cnt++] = n;
    for (int n = 0; n < NPIX && cnt < K; ++n) if (!(wts[b * NPIX + n] > 0.f)) idx[cnt++] = n;
  }
  __syncthreads();
  for (int i = threadIdx.x; i < K * CE; i += blockDim.x) {
    int k = i / CE, c = i % CE;
    cen[((long)b * K + k) * CE + c] = X[((long)b * NPIX + idx[k]) * CE + c];
  }
}

// ---------------- kmeans distances: fp32 centers, 128 px/block, 2 px/thread ----------------
// FROZEN at the R7 config (best measured ~40-43 µs). R10 post-mortem: the 8-way
// split + 4px/thread + XCD-pin variant REGRESSED to 62 µs — occupancy measured
// 20% (not the predicted 43%), bank conflicts appeared (35840), and the 192-B
// lane stride scattered each wave's X loads across 64 cache lines. Reverted
// verbatim; do not touch k_dots again without new counter evidence.
// grid (BN/128, 7), block 256 = 64 px-pairs x 4-way channel split (h = t&3, 96 ch).
// LDS padding: HSTR4=104 floats -> h-group bases at banks {0,8,16,24}; each wave
// b128 read touches 4 unique addrs (16-lane broadcast), conflict-free.
#define HSTR4 104
#define KSTR4 416

__global__ __launch_bounds__(256) void k_dots(
    const float* __restrict__ X, const double* __restrict__ xsq,
    const float* __restrict__ cenF, const float* __restrict__ cenB,
    float* __restrict__ candD, int* __restrict__ candI, int* __restrict__ cntAll) {
  __shared__ float ct[10 * KSTR4];
  __shared__ float csq_s[10];
  int z = blockIdx.y;
  int isBg = (z >= 2) ? 1 : 0;
  int k0 = isBg ? (z - 2) * 10 : z * 10;
  int t = threadIdx.x;
  int h = t & 3;
  int n = blockIdx.x * 128 + (t >> 2) * 2;   // first of this thread's 2 pixels
  int b = blockIdx.x >> 5;                   // 32 blocks per batch
  if (blockIdx.x == 0 && z == 0) {
    for (int i = t; i < NB * (KFG + KBG); i += 256) cntAll[i] = 0;
  }
  const float* cb = (isBg ? cenB + (long)b * KBG * CE
                          : cenF + (long)b * KFG * CE) + (long)k0 * CE;
  for (int i = t; i < 10 * CE; i += 256) {
    int k = i / CE, c = i % CE;
    ct[k * KSTR4 + (c / 96) * HSTR4 + (c % 96)] = cb[i];
  }
  {
    int w = t >> 6, lane = t & 63;           // 4 waves cover centers 0..9
    for (int kk = w; kk < 10; kk += 4) {
      double s = 0.0;
      for (int c = lane; c < CE; c += 64) { double v = (double)cb[kk * CE + c]; s += v * v; }
      #pragma unroll
      for (int o = 32; o > 0; o >>= 1) s += __shfl_down(s, o, 64);
      if (lane == 0) csq_s[kk] = (float)s;
    }
  }
  __syncthreads();
  const float* xr = X + (long)n * CE + h * 96;
  const float* cth = ct + h * HSTR4;
  float acc[10][2];
  #pragma unroll
  for (int k = 0; k < 10; ++k) { acc[k][0] = 0.f; acc[k][1] = 0.f; }
  for (int c0 = 0; c0 < 96; c0 += 8) {
    float4 xa[2], xb[2];
    #pragma unroll
    for (int p = 0; p < 2; ++p) {
      xa[p] = *(const float4*)(xr + p * CE + c0);
      xb[p] = *(const float4*)(xr + p * CE + c0 + 4);
    }
    #pragma unroll
    for (int k = 0; k < 10; ++k) {
      float4 c1 = *(const float4*)(&cth[k * KSTR4 + c0]);       // 4 unique addrs/wave
      float4 c2 = *(const float4*)(&cth[k * KSTR4 + c0 + 4]);
      #pragma unroll
      for (int p = 0; p < 2; ++p) {
        float a = acc[k][p];
        a += xa[p].x * c1.x; a += xa[p].y * c1.y;
        a += xa[p].z * c1.z; a += xa[p].w * c1.w;
        a += xb[p].x * c2.x; a += xb[p].y * c2.y;
        a += xb[p].z * c2.z; a += xb[p].w * c2.w;
        acc[k][p] = a;
      }
    }
  }
  // combine the 4 channel-quarter partials (lanes t, t^1, t^2 are same-wave)
  #pragma unroll
  for (int k = 0; k < 10; ++k)
    #pragma unroll
    for (int p = 0; p < 2; ++p) {
      float a = acc[k][p];
      a += __shfl_xor(a, 1, 64);
      a += __shfl_xor(a, 2, 64);
      acc[k][p] = a;
    }
  if (h == 0) {
    #pragma unroll
    for (int p = 0; p < 2; ++p) {
      float qn = (float)xsq[n + p];
      float best = 3.0e38f; int bi = 0;
      #pragma unroll
      for (int k = 0; k < 10; ++k) {
        float d = qn - 2.0f * acc[k][p] + csq_s[k];
        if (d < best) { best = d; bi = k0 + k; }
      }
      long gi = (long)z * BNTOT + n + p;
      candD[gi] = best;
      candI[gi] = bi;
    }
  }
}

// ---------------- final argmin over 7 chunk candidates + bucket scatter ----------------
// One thread per pixel. FG candidates are chunks z=0..1, BG z=2..6. Strict < in ascending
// z preserves the reference's earliest-index argmin. Pixels are scattered into per-cluster
// index lists; within-cluster order is nondeterministic (atomic slots) which only perturbs
// the fp64 summation order in k_cacc (~1 ulp, far below tolerance).
__global__ void k_asn(const float* __restrict__ candD, const int* __restrict__ candI,
                      const float* __restrict__ wfg, const float* __restrict__ wbg,
                      int* __restrict__ listF, int* __restrict__ listB,
                      int* __restrict__ cntAll) {
  int n = blockIdx.x * 256 + threadIdx.x;
  if (n >= BNTOT) return;
  int b = n >> 12;
  int nn = n & (NPIX - 1);
  float wf = wfg[n], wb = wbg[n];
  if (wf > 0.f) {
    float d0 = candD[n]; int i0 = candI[n];
    float d1 = candD[(long)BNTOT + n];
    if (d1 < d0) { d0 = d1; i0 = candI[(long)BNTOT + n]; }
    int slot = atomicAdd(&cntAll[b * KFG + i0], 1);
    listF[((long)b * KFG + i0) * NPIX + slot] = nn;
  } else if (wb > 0.f) {
    float d0 = candD[2L * BNTOT + n]; int i0 = candI[2L * BNTOT + n];
    #pragma unroll
    for (int z = 3; z < 7; ++z) {
      float dz = candD[(long)z * BNTOT + n];
      if (dz < d0) { d0 = dz; i0 = candI[(long)z * BNTOT + n]; }
    }
    int slot = atomicAdd(&cntAll[NB * KFG + b * KBG + i0], 1);
    listB[((long)b * KBG + i0) * NPIX + slot] = nn;
  }
}

// ---------------- chunk-parallel gather-accumulate per cluster ----------------
// R7 post-mortem: single-block-per-cluster k_cacc was a STRAGGLER kernel — 45.4 µs
// at 1.7% occupancy. Fix (R9, verified): split each cluster's list into NCH=16
// contiguous chunks; grid (3, 70, NB*NCH) = 13,440 blocks; fp64 partial per chunk;
// k_cred sums in fixed chunk order. PC aliases V (dead during k-means) to stay
// inside the workspace budget (R8 post-mortem: appending 13.8 MB killed the
// container twice -> ws_size overflow -> OOB fault).
__global__ __launch_bounds__(128) void k_cacc(
    const float* __restrict__ X,
    const int* __restrict__ listF, const int* __restrict__ listB,
    const int* __restrict__ cntAll,
    double* __restrict__ PC) {
  __shared__ int ls[256];    // cs = ceil(4096/16) = 256 max
  int slice = blockIdx.x;    // 0..2
  int kq = blockIdx.y;       // 0..KFG+KBG-1
  int zz = blockIdx.z;       // b*NCH + ch
  int b = zz / NCH, ch = zz % NCH;
  int t = threadIdx.x;
  int c = slice * 128 + t;
  const int* list; int cnt;
  if (kq < KFG) {
    cnt = cntAll[b * KFG + kq];
    list = listF + ((long)b * KFG + kq) * NPIX;
  } else {
    int k = kq - KFG;
    cnt = cntAll[NB * KFG + b * KBG + k];
    list = listB + ((long)b * KBG + k) * NPIX;
  }
  int cs = (cnt + NCH - 1) / NCH;
  int i0 = ch * cs;
  int i1 = min(i0 + cs, cnt);
  int m = i1 - i0;                       // may be <= 0 -> partial stays 0
  for (int i = t; i < m; i += 128) ls[i] = list[i0 + i];
  __syncthreads();
  const float* Xb = X + (long)b * NPIX * CE;
  double acc = 0.0;
  int i = 0;
  for (; i + 4 <= m; i += 4) {
    int n0 = ls[i], n1 = ls[i + 1], n2 = ls[i + 2], n3 = ls[i + 3];
    float v0 = Xb[(long)n0 * CE + c];
    float v1 = Xb[(long)n1 * CE + c];
    float v2 = Xb[(long)n2 * CE + c];
    float v3 = Xb[(long)n3 * CE + c];
    acc += (double)v0; acc += (double)v1; acc += (double)v2; acc += (double)v3;
  }
  for (; i < m; ++i) acc += (double)Xb[(long)ls[i] * CE + c];
  // PC layout: [ch][b*(KFG+KBG)+kq][c]
  PC[((long)ch * (NB * (KFG + KBG)) + (long)b * (KFG + KBG) + kq) * CE + c] = acc;
}

// ---------------- reduce chunk partials -> center update (deterministic) ----------------
__global__ void k_cred(const double* __restrict__ PC, const int* __restrict__ cntAll,
                       const float* __restrict__ srcF, float* __restrict__ dstF,
                       const float* __restrict__ srcB, float* __restrict__ dstB) {
  int i = blockIdx.x * 256 + threadIdx.x;
  const int tot = NB * (KFG + KBG) * CE;
  if (i >= tot) return;
  int c = i % CE;
  int r = i / CE;                        // b*(KFG+KBG)+kq
  int kq = r % (KFG + KBG);
  int b = r / (KFG + KBG);
  const long stride = (long)NB * (KFG + KBG) * CE;
  double s = 0.0;
  #pragma unroll
  for (int ch = 0; ch < NCH; ++ch) s += PC[(long)ch * stride + (long)r * CE + c];
  if (kq < KFG) {
    int cnt = cntAll[b * KFG + kq];
    long o = ((long)b * KFG + kq) * CE + c;
    dstF[o] = (cnt > 0) ? (float)(s / (double)cnt) : srcF[o];
  } else {
    int k = kq - KFG;
    int cnt = cntAll[NB * KFG + b * KBG + k];
    long o = ((long)b * KBG + k) * CE + c;
    dstB[o] = (cnt > 0) ? (float)(s / (double)cnt) : srcB[o];
  }
}

// ---------------- fused pos + bf16 staging ----------------
__global__ void k_cvtQV(const float* __restrict__ X,
                        const float* __restrict__ yvf, const float* __restrict__ xvf,
                        const float* __restrict__ invdt, const float* __restrict__ notp,
                        float* __restrict__ POS,
                        unsigned short* __restrict__ QB, unsigned short* __restrict__ VBin) {
  long i = (long)blockIdx.x * 256 + threadIdx.x;
  if (i >= (long)NB * NPIX * CE) return;
  int c = (int)(i % CE);
  long row = i / CE;
  float p = (c < 192) ? yvf[row] : xvf[row];
  float v = p * invdt[c];
  int tt = (c < 192) ? c : c - 192;
  float r = (tt & 1) ? cosf(v) : sinf(v);
  POS[i] = r;
  float x = X[i];
  QB[i] = f2bf(x + r);
  VBin[i] = f2bf(x * notp[row]);
}

// ---------------- fused per-layer weight convert/transpose + concat bias ----------------
__global__ void k_cvtW_all(
    const float* __restrict__ Wv_l, const float* __restrict__ Woff_l,
    const float* __restrict__ Wa_l, const float* __restrict__ Wout_l,
    const float* __restrict__ Wf1_l, const float* __restrict__ Wf2_l,
    const float* __restrict__ boff_l, const float* __restrict__ ba_l,
    unsigned short* __restrict__ W0, unsigned short* __restrict__ W1,
    unsigned short* __restrict__ W3, unsigned short* __restrict__ W4,
    unsigned short* __restrict__ W5, float* __restrict__ biasCat) {
  int i = blockIdx.x * 256 + threadIdx.x;
  const int S = 147456, SF = 442368;
  if (i < S) {
    int n = i / 384, k = i % 384;
    W0[i] = f2bf(Wv_l[(long)k * 384 + n]);
  } else if (i < 2 * S) {
    int j = i - S; int n = j / 384, k = j % 384;
    float v = 0.f;
    if (n < 216) v = Woff_l[(long)k * 216 + n];
    else if (n < 324) v = Wa_l[(long)k * 108 + (n - 216)];
    W1[j] = f2bf(v);
  } else if (i < 3 * S) {
    int j = i - 2 * S; int n = j / 384, k = j % 384;
    W3[j] = f2bf(Wout_l[(long)k * 384 + n]);
  } else if (i < 3 * S + SF) {
    int j = i - 3 * S; int n = j / 384, k = j % 384;
    W4[j] = f2bf(Wf1_l[(long)k * 1152 + n]);
  } else if (i < 3 * S + 2 * SF) {
    int j = i - 3 * S - SF; int n = j / 1152, k = j % 1152;
    W5[j] = f2bf(Wf2_l[(long)k * 384 + n]);
  } else if (i < 3 * S + 2 * SF + 324) {
    int j = i - 3 * S - 2 * SF;
    biasCat[j] = (j < 216) ? boff_l[j] : ba_l[j - 216];
  }
}

// ---------------- bf16 MFMA GEMM: C = A @ Bt^T (+bias)(+relu) ----------------
// Staging via global_load_lds width=16. XCD-bijective remap (verified R9: FFN FETCH
// 56.7 -> 22.2/12.3 MB). LDS XOR-swizzle (verified R11: conflicts 1.77M -> 0).
// NEW (R12): 2-phase double-buffered K-loop. R11 post-mortem: with conflicts at 0,
// FFN GEMMs sit at 55 µs with MfmaUtil 9.6%, VALU 23%, HBM 11% -> latency/barrier
// bound: 12 K-steps each exposing a full load-latency drain (two __syncthreads,
// zero load/compute overlap). Fix = guide T3 "minimum 2-phase": issue next tile's
// global_load_lds BEFORE computing current tile; ONE barrier per K-step. The
// syncthreads drain then only waits residual latency not hidden by the 16-MFMA
// compute phase. Four statically distinct __shared__ arrays (As0/As1/Bs0/Bs1) with
// compile-time buffer selection so the compiler can PROVE prefetch writes don't
// alias current-tile ds_reads (else it inserts vmcnt(0) before the reads and the
// overlap dies — likely why m99/m100-style dbuf measured neutral). K%64==0 for all
// shapes (384, 1152). LDS 32 KB -> >=5 blocks/CU, above the 4.5 grid limit.
// MFMA order unchanged -> numerics bit-identical.
__global__ __launch_bounds__(256) void k_gemm_bf(
    const unsigned short* __restrict__ A, const unsigned short* __restrict__ Bt,
    const float* __restrict__ bias, float* __restrict__ Cf, unsigned short* __restrict__ Cb,
    int M, int K, int N, int relu) {
  __shared__ unsigned short As0[128 * 32];
  __shared__ unsigned short Bs0[128 * 32];
  __shared__ unsigned short As1[128 * 32];
  __shared__ unsigned short Bs1[128 * 32];
  int bx, by;
  {
    int gx = gridDim.x;
    int q = blockIdx.y * gx + blockIdx.x;
    if ((gridDim.y & 7) == 0) {
      int xcd = q & 7;
      int r = q >> 3;
      bx = r % gx;
      by = xcd + 8 * (r / gx);
    } else { bx = blockIdx.x; by = blockIdx.y; }
  }
  int m0 = by * 128, n0 = bx * 128;
  int t = threadIdx.x;
  int w = t >> 6, l = t & 63;
  int wm = w >> 1, wn = w & 1;
  int half = l >> 4, lr = l & 15;
  float4v acc[4][4] = {};

  auto STAGE = [&](unsigned short* AD, unsigned short* BD, int kk) {
    #pragma unroll
    for (int i = 0; i < 2; ++i) {
      int c = w * 64 + i * 256 + l;           // 0..511 = LDS slot index
      int r = c >> 2;
      int part = (c & 3) ^ ((r >> 1) & 3);    // swizzled global source chunk
      int ldsOff = (w * 64 + i * 256) * 8;    // shorts; lane adds l*16 bytes
      __builtin_amdgcn_global_load_lds(
          (const AS1 unsigned int*)(A + (size_t)(m0 + r) * K + kk + part * 8),
          (AS3 unsigned int*)(AD + ldsOff), 16, 0, 0);
      __builtin_amdgcn_global_load_lds(
          (const AS1 unsigned int*)(Bt + (size_t)(n0 + r) * K + kk + part * 8),
          (AS3 unsigned int*)(BD + ldsOff), 16, 0, 0);
    }
  };
  auto COMPUTE = [&](const unsigned short* AD, const unsigned short* BD) {
    short8 af[4], bfr[4];
    #pragma unroll
    for (int am = 0; am < 4; ++am) {
      int arow = wm * 64 + am * 16 + lr;
      af[am] = *(const short8*)(&AD[arow * 32 + (half ^ ((arow >> 1) & 3)) * 8]);
    }
    #pragma unroll
    for (int bn = 0; bn < 4; ++bn) {
      int brow = wn * 64 + bn * 16 + lr;
      bfr[bn] = *(const short8*)(&BD[brow * 32 + (half ^ ((brow >> 1) & 3)) * 8]);
    }
    #pragma unroll
    for (int am = 0; am < 4; ++am)
      #pragma unroll
      for (int bn = 0; bn < 4; ++bn)
        acc[am][bn] = __builtin_amdgcn_mfma_f32_16x16x32_bf16(af[am], bfr[bn], acc[am][bn], 0, 0, 0);
  };

  STAGE(As0, Bs0, 0);
  __syncthreads();
  for (int k0 = 0; k0 < K; k0 += 64) {
    // phase 0: prefetch k0+32 into buf1 while computing buf0
    STAGE(As1, Bs1, k0 + 32);               // k0+32 < K always (K % 64 == 0)
    COMPUTE(As0, Bs0);
    __syncthreads();
    // phase 1: prefetch k0+64 into buf0 (unless last) while computing buf1
    if (k0 + 64 < K) STAGE(As0, Bs0, k0 + 64);
    COMPUTE(As1, Bs1);
    __syncthreads();
  }
  #pragma unroll
  for (int am = 0; am < 4; ++am) {
    #pragma unroll
    for (int bn = 0; bn < 4; ++bn) {
      int gc = n0 + wn * 64 + bn * 16 + lr;
      if (gc < N) {
        float bv = bias ? bias[gc] : 0.f;
        int gr0 = m0 + wm * 64 + am * 16 + half * 4;
        #pragma unroll
        for (int r = 0; r < 4; ++r) {
          float v = acc[am][bn][r] + bv;
          if (relu) v = fmaxf(v, 0.f);
          size_t oi = (size_t)(gr0 + r) * N + gc;
          if (Cf) Cf[oi] = v;
          else Cb[oi] = f2bf(v);
        }
      }
    }
  }
}

// ---------------- coords+softmax: one thread per (row, head) ----------------
__global__ void k_coords(const unsigned short* __restrict__ OAB, float4* __restrict__ CRD) {
  int idx = blockIdx.x * 256 + threadIdx.x;
  if (idx >= NB * NPIX * NH) return;
  int row = idx / NH, h = idx % NH;
  int n = row & (NPIX - 1);
  int hh = n >> 6, ww = n & 63;
  float refx = ((float)ww + 0.5f) / (float)WDIM;
  float refy = ((float)hh + 0.5f) / (float)HDIM;
  const unsigned short* oab = OAB + (size_t)row * 324;
  float f[NPTS];
  #pragma unroll
  for (int j = 0; j < NPTS; ++j) f[j] = bf2f(oab[216 + h * 9 + j]);
  float m = f[0];
  #pragma unroll
  for (int j = 1; j < NPTS; ++j) m = fmaxf(m, f[j]);
  float s = 0.f;
  #pragma unroll
  for (int j = 0; j < NPTS; ++j) { f[j] = expf(f[j] - m); s += f[j]; }
  float inv = 1.f / s;
  float4* crd = CRD + (size_t)row * 108 + h * 9;
  #pragma unroll
  for (int p = 0; p < NPTS; ++p) {
    float ox = bf2f(oab[h * 18 + p * 2 + 0]);
    float oy = bf2f(oab[h * 18 + p * 2 + 1]);
    float lx = refx + ox / (float)WDIM;
    float ly = refy + oy / (float)HDIM;
    float xs = lx * (float)WDIM - 0.5f;
    float ys = ly * (float)HDIM - 0.5f;
    float x0f = floorf(xs), y0f = floorf(ys);
    int x0 = (int)x0f, y0 = (int)y0f;
    float4 o;
    o.x = xs - x0f;
    o.y = ys - y0f;
    o.z = f[p] * inv;
    o.w = __int_as_float((y0 << 16) | (x0 & 0xFFFF));
    crd[p] = o;
  }
}

// ---------------- gather: 4 channels per thread, float4 gathers ----------------
__global__ __launch_bounds__(256) void k_gather(
    const float* __restrict__ V, const float4* __restrict__ CRD,
    uint2* __restrict__ ATTu) {
  int idx = blockIdx.x * 256 + threadIdx.x;
  if (idx >= NB * NPIX * (CE / 4)) return;
  int row = idx / (CE / 4), cq = idx % (CE / 4);
  int c = cq * 4;
  int h = c >> 5;
  int b = row >> 12;
  const float* vb = V + (size_t)b * NPIX * CE;
  const float4* crd = CRD + (size_t)row * 108 + h * 9;
  float a0 = 0.f, a1 = 0.f, a2 = 0.f, a3 = 0.f;
  #pragma unroll
  for (int p = 0; p < NPTS; ++p) {
    float4 o = crd[p];
    int pk = __float_as_int(o.w);
    int x0 = (int)(short)(pk & 0xFFFF);
    int y0 = pk >> 16;
    float wx = o.x, wy = o.y, aw = o.z;
    float4 g00 = sample4(vb, x0,     y0,     c);
    float4 g01 = sample4(vb, x0 + 1, y0,     c);
    float4 g10 = sample4(vb, x0,     y0 + 1, c);
    float4 g11 = sample4(vb, x0 + 1, y0 + 1, c);
    float w00 = (1.f - wx) * (1.f - wy), w01 = wx * (1.f - wy);
    float w10 = (1.f - wx) * wy,         w11 = wx * wy;
    a0 += aw * (g00.x * w00 + g01.x * w01 + g10.x * w10 + g11.x * w11);
    a1 += aw * (g00.y * w00 + g01.y * w01 + g10.y * w10 + g11.y * w11);
    a2 += aw * (g00.z * w00 + g01.z * w01 + g10.z * w10 + g11.z * w11);
    a3 += aw * (g00.w * w00 + g01.w * w01 + g10.w * w10 + g11.w * w11);
  }
  uint2 pk2;
  pk2.x = (unsigned)f2bf(a0) | ((unsigned)f2bf(a1) << 16);
  pk2.y = (unsigned)f2bf(a2) | ((unsigned)f2bf(a3) << 16);
  ATTu[(size_t)row * (CE / 4) + cq] = pk2;
}

// ---------------- LayerNorm(X + T), 4 rows/block, fused epilogues ----------------
__global__ __launch_bounds__(256) void k_ln(
    float* __restrict__ X, const float* __restrict__ T,
    const float* __restrict__ g, const float* __restrict__ bb,
    unsigned short* __restrict__ xbOut,
    const float* __restrict__ posp, const float* __restrict__ notp,
    unsigned short* __restrict__ qb, unsigned short* __restrict__ vbin,
    float* __restrict__ outp) {
  int t = threadIdx.x;
  int row = blockIdx.x * 4 + (t >> 6);
  int lane = t & 63;
  float* xr = X + (long)row * CE;
  const float* tr = T + (long)row * CE;
  float v[6]; float s = 0.f;
  #pragma unroll
  for (int i = 0; i < 6; ++i) { v[i] = xr[lane + 64 * i] + tr[lane + 64 * i]; s += v[i]; }
  #pragma unroll
  for (int o = 32; o > 0; o >>= 1) s += __shfl_down(s, o, 64);
  s = __shfl(s, 0, 64);
  float m = s / (float)CE;
  float var = 0.f;
  #pragma unroll
  for (int i = 0; i < 6; ++i) { float d = v[i] - m; var += d * d; }
  #pragma unroll
  for (int o = 32; o > 0; o >>= 1) var += __shfl_down(var, o, 64);
  var = __shfl(var, 0, 64);
  float rst = rsqrtf(var / (float)CE + 1e-5f);
  float nprow = notp ? notp[row] : 0.f;
  int b = row >> 12, n = row & (NPIX - 1);
  #pragma unroll
  for (int i = 0; i < 6; ++i) {
    int c = lane + 64 * i;
    float xn = (v[i] - m) * rst * g[c] + bb[c];
    if (outp) outp[((long)b * NROW + n) * CE + c] = xn;
    else xr[c] = xn;
    if (xbOut) xbOut[(long)row * CE + c] = f2bf(xn);
    if (qb) {
      qb[(long)row * CE + c] = f2bf(xn + posp[(long)row * CE + c]);
      vbin[(long)row * CE + c] = f2bf(xn * nprow);
    }
  }
}

// ---------------- centers -> output ----------------
__global__ void k_out_cen(const float* __restrict__ fg, const float* __restrict__ bg,
                          float* __restrict__ out) {
  int i = blockIdx.x * 256 + threadIdx.x;
  const int tot = NB * (KFG + KBG) * CE;
  if (i >= tot) return;
  int c = i % CE;
  int r = i / CE;
  int rr = r % (KFG + KBG);
  int b = r / (KFG + KBG);
  float v;
  if (rr < KFG) v = fg[((long)b * KFG + rr) * CE + c];
  else v = bg[((long)b * KBG + (rr - KFG)) * CE + c];
  out[((long)b * NROW + NPIX + rr) * CE + c] = v;
}

extern "C" void kernel_launch(void* const* d_in, const int* in_sizes, int n_in,
                              void* d_out, int out_size, void* d_ws, size_t ws_size,
                              hipStream_t stream) {
  (void)in_sizes; (void)n_in; (void)out_size; (void)ws_size;
  const float* s_x  = (const float*)d_in[0];
  const float* s_pm = (const float*)d_in[1];
  const float* s_sm = (const float*)d_in[2];
  const float* Wv   = (const float*)d_in[3];
  const float* bv   = (const float*)d_in[4];
  const float* Woff = (const float*)d_in[5];
  const float* boff = (const float*)d_in[6];
  const float* Wa   = (const float*)d_in[7];
  const float* ba   = (const float*)d_in[8];
  const float* Wout = (const float*)d_in[9];
  const float* bout = (const float*)d_in[10];
  const float* ln1g = (const float*)d_in[11];
  const float* ln1b = (const float*)d_in[12];
  const float* Wf1  = (const float*)d_in[13];
  const float* Wf2  = (const float*)d_in[14];
  const float* ln2g = (const float*)d_in[15];
  const float* ln2b = (const float*)d_in[16];
  float* out = (float*)d_out;
  char* pb = (char*)d_ws;

  const long BN  = (long)NB * NPIX;      // 16384
  const long BNC = BN * CE;              // 6291456

  float* X    = (float*)pb; pb += BNC * 4;
  float* POS  = (float*)pb; pb += BNC * 4;
  float* V    = (float*)pb; pb += BNC * 4;
  float* T2   = (float*)pb; pb += BNC * 4;
  double* PC  = (double*)V;   // 13.8 MB chunk partials alias V (dead during k-means;
                              // first written by layer-0 GEMM). R0 precedent: PF/PB
                              // aliased V/T2 under a "< 24 MB" budget note.
  unsigned short* QB   = (unsigned short*)pb; pb += BNC * 2;
  unsigned short* VBin = (unsigned short*)pb; pb += BNC * 2;
  unsigned short* T1b  = (unsigned short*)pb; pb += BNC * 2;
  unsigned short* Zbf  = QB;   // FFN hidden aliases QB+VBin+T1b
  unsigned short* XB   = (unsigned short*)pb; pb += BNC * 2;
  unsigned short* OAB  = (unsigned short*)pb; pb += BN * 324 * 2;
  float4* CRD = (float4*)pb; pb += BN * 108 * 16;
  const int S_W = 147456, S_F = 442368;
  unsigned short* WT[NLAYERS][5];
  float* biasCat[NLAYERS];
  for (int l = 0; l < NLAYERS; ++l) {
    WT[l][0] = (unsigned short*)pb; pb += S_W * 2;
    WT[l][1] = (unsigned short*)pb; pb += S_W * 2;
    WT[l][2] = (unsigned short*)pb; pb += S_W * 2;
    WT[l][3] = (unsigned short*)pb; pb += S_F * 2;
    WT[l][4] = (unsigned short*)pb; pb += S_F * 2;
    biasCat[l] = (float*)pb; pb += 324 * 4;
  }
  float* padf = (float*)pb; pb += BN * 4;
  float* objf = (float*)pb; pb += BN * 4;
  float* notp = (float*)pb; pb += BN * 4;
  float* wfg  = (float*)pb; pb += BN * 4;
  float* wbg  = (float*)pb; pb += BN * 4;
  float* yvf  = (float*)pb; pb += BN * 4;
  float* xvf  = (float*)pb; pb += BN * 4;
  float* invdt = (float*)pb; pb += CE * 4;
  pb = (char*)(((size_t)pb + 7) & ~(size_t)7);
  double* xsq   = (double*)pb; pb += BN * 8;
  float* candD = (float*)pb; pb += BN * 7 * 4;            // per-chunk best distance (fp32)
  float* cFgA = (float*)pb; pb += (long)NB * KFG * CE * 4;  // fp32 centers
  float* cFgB = (float*)pb; pb += (long)NB * KFG * CE * 4;
  float* cBgA = (float*)pb; pb += (long)NB * KBG * CE * 4;
  float* cBgB = (float*)pb; pb += (long)NB * KBG * CE * 4;
  int* candI  = (int*)pb; pb += BN * 7 * 4;               // per-chunk best global-k
  int* cntAll = (int*)pb; pb += NB * (KFG + KBG) * 4;     // cluster counts (FG then BG)
  int* listF  = (int*)pb; pb += (long)NB * KFG * NPIX * 4;
  int* listB  = (int*)pb; pb += (long)NB * KBG * NPIX * 4;

  int bn = (int)BN;
  int cvtBlocks = (int)((BNC + 255) / 256);

  k_masks<<<(bn + 255) / 256, 256, 0, stream>>>(s_pm, s_sm, padf, objf, notp, wfg, wbg);
  k_transpose<<<dim3(NPIX / 64, CE / 64, NB), 256, 0, stream>>>(s_x, X);
  k_xsq<<<bn, 64, 0, stream>>>(X, xsq);
  k_cums<<<NB, 128, 0, stream>>>(padf, yvf, xvf, invdt);
  k_cvtQV<<<cvtBlocks, 256, 0, stream>>>(X, yvf, xvf, invdt, notp, POS, QB, VBin);

  const int CVTW_TOT = 3 * S_W + 2 * S_F + 324;
  for (int l = 0; l < NLAYERS; ++l) {
    k_cvtW_all<<<(CVTW_TOT + 255) / 256, 256, 0, stream>>>(
        Wv + (long)l * CE * CE, Woff + (long)l * CE * 216, Wa + (long)l * CE * 108,
        Wout + (long)l * CE * CE, Wf1 + (long)l * CE * 1152, Wf2 + (long)l * 1152 * CE,
        boff + l * 216, ba + l * 108,
        WT[l][0], WT[l][1], WT[l][2], WT[l][3], WT[l][4], biasCat[l]);
  }

  // ---- kmeans: dots(+chunk argmin) -> asn(bucket lists) -> cacc(chunk partials) -> cred ----
  float *srcF = cFgA, *dstF = cFgB, *srcB = cBgA, *dstB = cBgB;
  k_kinit<<<NB, 256, 0, stream>>>(X, wfg, srcF, KFG);
  k_kinit<<<NB, 256, 0, stream>>>(X, wbg, srcB, KBG);
  const int credBlocks = (NB * (KFG + KBG) * CE + 255) / 256;
  for (int it = 0; it < NITER; ++it) {
    k_dots<<<dim3(bn / 128, 7), 256, 0, stream>>>(X, xsq, srcF, srcB, candD, candI, cntAll);
    k_asn<<<(bn + 255) / 256, 256, 0, stream>>>(candD, candI, wfg, wbg, listF, listB, cntAll);
    k_cacc<<<dim3(3, KFG + KBG, NB * NCH), 128, 0, stream>>>(
        X, listF, listB, cntAll, PC);
    k_cred<<<credBlocks, 256, 0, stream>>>(PC, cntAll, srcF, dstF, srcB, dstB);
    float* tmp;
    tmp = srcF; srcF = dstF; dstF = tmp;
    tmp = srcB; srcB = dstB; dstB = tmp;
  }
  float* fgC = srcF; float* bgC = srcB;

  // ---- layers ----
  for (int l = 0; l < NLAYERS; ++l) {
    const float* bv_l   = bv   + l * CE;
    const float* bout_l = bout + l * CE;
    int last = (l == NLAYERS - 1);

    k_gemm_bf<<<dim3(3, 128), 256, 0, stream>>>(VBin, WT[l][0], bv_l, V, (unsigned short*)nullptr,
                                                bn, CE, 384, 0);
    k_gemm_bf<<<dim3(3, 128), 256, 0, stream>>>(QB, WT[l][1], biasCat[l], (float*)nullptr, OAB,
                                                bn, CE, 324, 0);
    k_coords<<<(bn * NH + 255) / 256, 256, 0, stream>>>(OAB, CRD);
    k_gather<<<(bn * (CE / 4) + 255) / 256, 256, 0, stream>>>(V, CRD, (uint2*)T1b);
    k_gemm_bf<<<dim3(3, 128), 256, 0, stream>>>(T1b, WT[l][2], bout_l, T2, (unsigned short*)nullptr,
                                                bn, CE, 384, 0);
    k_ln<<<bn / 4, 256, 0, stream>>>(X, T2, ln1g + l * CE, ln1b + l * CE,
                                     XB, (const float*)nullptr, (const float*)nullptr,
                                     (unsigned short*)nullptr, (unsigned short*)nullptr,
                                     (float*)nullptr);
    k_gemm_bf<<<dim3(9, 128), 256, 0, stream>>>(XB, WT[l][3], (const float*)nullptr,
                                                (float*)nullptr, Zbf, bn, CE, 1152, 1);
    k_gemm_bf<<<dim3(3, 128), 256, 0, stream>>>(Zbf, WT[l][4], (const float*)nullptr,
                                                T2, (unsigned short*)nullptr, bn, 1152, 384, 0);
    if (!last) {
      k_ln<<<bn / 4, 256, 0, stream>>>(X, T2, ln2g + l * CE, ln2b + l * CE,
                                       (unsigned short*)nullptr, POS, notp, QB, VBin,
                                       (float*)nullptr);
    } else {
      k_ln<<<bn / 4, 256, 0, stream>>>(X, T2, ln2g + l * CE, ln2b + l * CE,
                                       (unsigned short*)nullptr, (const float*)nullptr,
                                       (const float*)nullptr, (unsigned short*)nullptr,
                                       (unsigned short*)nullptr, out);
    }
  }

  k_out_cen<<<(NB * (KFG + KBG) * CE + 255) / 256, 256, 0, stream>>>(fgC, bgC, out);
}

// Round 13
// 1236.422 us; speedup vs baseline: 1.1750x; 1.0221x over previous
//
#include <hip/hip_runtime.h>
#include <hip/hip_bf16.h>
#include <math.h>

#define NB 4
#define CE 384
#define NH 12
#define DH 32
#define NPTS 9
#define NLAYERS 2
#define KFG 20
#define KBG 50
#define NITER 10
#define HDIM 64
#define WDIM 64
#define NPIX 4096
#define BNTOT (NB * NPIX)
#define NROW (NPIX + KFG + KBG)
#define NCH 16
#define TWO_PI 6.283185307179586f

#define AS1 __attribute__((address_space(1)))
#define AS3 __attribute__((address_space(3)))

typedef __attribute__((ext_vector_type(8))) short short8;
typedef __attribute__((ext_vector_type(4))) float float4v;

static __device__ __forceinline__ unsigned short f2bf(float f) {
  __hip_bfloat16 h = __float2bfloat16(f);
  return *reinterpret_cast<unsigned short*>(&h);
}
static __device__ __forceinline__ float bf2f(unsigned short u) {
  unsigned x = ((unsigned)u) << 16;
  return __uint_as_float(x);
}

// ---------------- masks ----------------
__global__ void k_masks(const float* __restrict__ pm, const float* __restrict__ sm,
                        float* padf, float* objf, float* notp, float* wfg, float* wbg) {
  int i = blockIdx.x * 256 + threadIdx.x;
  if (i >= NB * NPIX) return;
  float p  = (pm[i] == 255.0f) ? 1.f : 0.f;
  float o  = (sm[i] == 1.0f) ? 1.f : 0.f;
  float np_ = 1.f - p;
  padf[i] = p; objf[i] = o; notp[i] = np_;
  wfg[i] = o * np_;
  wbg[i] = (1.f - o) * np_;
}

// ---------------- LDS-tiled transpose s_x [B,C,N] -> X [B,N,C] ----------------
__global__ __launch_bounds__(256) void k_transpose(const float* __restrict__ sx,
                                                   float* __restrict__ X) {
  __shared__ float tile[64][65];
  int nb = blockIdx.x * 64, cb = blockIdx.y * 64, b = blockIdx.z;
  int t = threadIdx.x;
  for (int idx = t; idx < 64 * 64; idx += 256) {
    int cc = idx >> 6, nn = idx & 63;
    tile[cc][nn] = sx[((long)b * CE + cb + cc) * NPIX + nb + nn];
  }
  __syncthreads();
  for (int idx = t; idx < 64 * 64; idx += 256) {
    int nn = idx >> 6, cc = idx & 63;
    X[((long)b * NPIX + nb + nn) * CE + cb + cc] = tile[cc][nn];
  }
}

// ---------------- xsq (fp64) ----------------
__global__ void k_xsq(const float* __restrict__ X, double* __restrict__ xsq) {
  int row = blockIdx.x; int t = threadIdx.x;
  const float* xr = X + (long)row * CE;
  double s = 0.0;
  for (int i = t; i < CE; i += 64) { double v = (double)xr[i]; s += v * v; }
  #pragma unroll
  for (int o = 32; o > 0; o >>= 1) s += __shfl_down(s, o, 64);
  if (t == 0) xsq[row] = s;
}

// ---------------- pos cumsums + invdt table (LDS-staged; scans bit-identical) ----------------
__global__ __launch_bounds__(128) void k_cums(const float* __restrict__ padf,
                                              float* __restrict__ yvf,
                                              float* __restrict__ xvf,
                                              float* __restrict__ invdt) {
  __shared__ float pad_s[NPIX];
  int b = blockIdx.x; int t = threadIdx.x;
  for (int i = t; i < NPIX; i += 128) pad_s[i] = padf[b * NPIX + i];
  if (b == 0) {
    for (int c = t; c < CE; c += 128) {
      int tt = (c < 192) ? c : c - 192;
      invdt[c] = 1.0f / powf(10000.0f, (float)(2 * (tt / 2)) / 192.0f);
    }
  }
  __syncthreads();
  if (t < 64) {
    int w = t;
    float cum[64]; float tot = 0.f;
    for (int h = 0; h < 64; ++h) {
      float nm = 1.f - pad_s[h * WDIM + w];
      tot += nm; cum[h] = tot;
    }
    float sc = 1.f / (tot + 1e-6f);
    for (int h = 0; h < 64; ++h) yvf[b * NPIX + h * WDIM + w] = cum[h] * sc * TWO_PI;
  } else {
    int h = t - 64;
    float cum[64]; float tot = 0.f;
    for (int w = 0; w < 64; ++w) {
      float nm = 1.f - pad_s[h * WDIM + w];
      tot += nm; cum[w] = tot;
    }
    float sc = 1.f / (tot + 1e-6f);
    for (int w = 0; w < 64; ++w) xvf[b * NPIX + h * WDIM + w] = cum[w] * sc * TWO_PI;
  }
}

// ---------------- kmeans init (fp32 centers; X values are fp32 -> exact) ----------------
__global__ void k_kinit(const float* __restrict__ X, const float* __restrict__ wts,
                        float* __restrict__ cen, int K) {
  int b = blockIdx.x;
  __shared__ int idx[KBG];
  if (threadIdx.x == 0) {
    int cnt = 0;
    for (int n = 0; n < NPIX && cnt < K; ++n) if (wts[b * NPIX + n] > 0.f) idx[cnt++] = n;
    for (int n = 0; n < NPIX && cnt < K; ++n) if (!(wts[b * NPIX + n] > 0.f)) idx[cnt++] = n;
  }
  __syncthreads();
  for (int i = threadIdx.x; i < K * CE; i += blockDim.x) {
    int k = i / CE, c = i % CE;
    cen[((long)b * K + k) * CE + c] = X[((long)b * NPIX + idx[k]) * CE + c];
  }
}

// ---------------- kmeans distances: fp32 centers, 128 px/block, 2 px/thread ----------------
// FROZEN at the R7 config (best measured ~40-43 µs). R10 post-mortem: the 8-way
// split + 4px/thread + XCD-pin variant REGRESSED to 62 µs. Reverted verbatim;
// do not touch k_dots again without new counter evidence.
// grid (BN/128, 7), block 256 = 64 px-pairs x 4-way channel split (h = t&3, 96 ch).
// LDS padding: HSTR4=104 floats -> h-group bases at banks {0,8,16,24}; each wave
// b128 read touches 4 unique addrs (16-lane broadcast), conflict-free.
#define HSTR4 104
#define KSTR4 416

__global__ __launch_bounds__(256) void k_dots(
    const float* __restrict__ X, const double* __restrict__ xsq,
    const float* __restrict__ cenF, const float* __restrict__ cenB,
    float* __restrict__ candD, int* __restrict__ candI, int* __restrict__ cntAll) {
  __shared__ float ct[10 * KSTR4];
  __shared__ float csq_s[10];
  int z = blockIdx.y;
  int isBg = (z >= 2) ? 1 : 0;
  int k0 = isBg ? (z - 2) * 10 : z * 10;
  int t = threadIdx.x;
  int h = t & 3;
  int n = blockIdx.x * 128 + (t >> 2) * 2;   // first of this thread's 2 pixels
  int b = blockIdx.x >> 5;                   // 32 blocks per batch
  if (blockIdx.x == 0 && z == 0) {
    for (int i = t; i < NB * (KFG + KBG); i += 256) cntAll[i] = 0;
  }
  const float* cb = (isBg ? cenB + (long)b * KBG * CE
                          : cenF + (long)b * KFG * CE) + (long)k0 * CE;
  for (int i = t; i < 10 * CE; i += 256) {
    int k = i / CE, c = i % CE;
    ct[k * KSTR4 + (c / 96) * HSTR4 + (c % 96)] = cb[i];
  }
  {
    int w = t >> 6, lane = t & 63;           // 4 waves cover centers 0..9
    for (int kk = w; kk < 10; kk += 4) {
      double s = 0.0;
      for (int c = lane; c < CE; c += 64) { double v = (double)cb[kk * CE + c]; s += v * v; }
      #pragma unroll
      for (int o = 32; o > 0; o >>= 1) s += __shfl_down(s, o, 64);
      if (lane == 0) csq_s[kk] = (float)s;
    }
  }
  __syncthreads();
  const float* xr = X + (long)n * CE + h * 96;
  const float* cth = ct + h * HSTR4;
  float acc[10][2];
  #pragma unroll
  for (int k = 0; k < 10; ++k) { acc[k][0] = 0.f; acc[k][1] = 0.f; }
  for (int c0 = 0; c0 < 96; c0 += 8) {
    float4 xa[2], xb[2];
    #pragma unroll
    for (int p = 0; p < 2; ++p) {
      xa[p] = *(const float4*)(xr + p * CE + c0);
      xb[p] = *(const float4*)(xr + p * CE + c0 + 4);
    }
    #pragma unroll
    for (int k = 0; k < 10; ++k) {
      float4 c1 = *(const float4*)(&cth[k * KSTR4 + c0]);       // 4 unique addrs/wave
      float4 c2 = *(const float4*)(&cth[k * KSTR4 + c0 + 4]);
      #pragma unroll
      for (int p = 0; p < 2; ++p) {
        float a = acc[k][p];
        a += xa[p].x * c1.x; a += xa[p].y * c1.y;
        a += xa[p].z * c1.z; a += xa[p].w * c1.w;
        a += xb[p].x * c2.x; a += xb[p].y * c2.y;
        a += xb[p].z * c2.z; a += xb[p].w * c2.w;
        acc[k][p] = a;
      }
    }
  }
  // combine the 4 channel-quarter partials (lanes t, t^1, t^2 are same-wave)
  #pragma unroll
  for (int k = 0; k < 10; ++k)
    #pragma unroll
    for (int p = 0; p < 2; ++p) {
      float a = acc[k][p];
      a += __shfl_xor(a, 1, 64);
      a += __shfl_xor(a, 2, 64);
      acc[k][p] = a;
    }
  if (h == 0) {
    #pragma unroll
    for (int p = 0; p < 2; ++p) {
      float qn = (float)xsq[n + p];
      float best = 3.0e38f; int bi = 0;
      #pragma unroll
      for (int k = 0; k < 10; ++k) {
        float d = qn - 2.0f * acc[k][p] + csq_s[k];
        if (d < best) { best = d; bi = k0 + k; }
      }
      long gi = (long)z * BNTOT + n + p;
      candD[gi] = best;
      candI[gi] = bi;
    }
  }
}

// ---------------- final argmin over 7 chunk candidates + bucket scatter ----------------
// One thread per pixel. FG candidates are chunks z=0..1, BG z=2..6. Strict < in ascending
// z preserves the reference's earliest-index argmin. Pixels are scattered into per-cluster
// index lists; within-cluster order is nondeterministic (atomic slots) which only perturbs
// the fp64 summation order in k_cacc (~1 ulp, far below tolerance).
__global__ void k_asn(const float* __restrict__ candD, const int* __restrict__ candI,
                      const float* __restrict__ wfg, const float* __restrict__ wbg,
                      int* __restrict__ listF, int* __restrict__ listB,
                      int* __restrict__ cntAll) {
  int n = blockIdx.x * 256 + threadIdx.x;
  if (n >= BNTOT) return;
  int b = n >> 12;
  int nn = n & (NPIX - 1);
  float wf = wfg[n], wb = wbg[n];
  if (wf > 0.f) {
    float d0 = candD[n]; int i0 = candI[n];
    float d1 = candD[(long)BNTOT + n];
    if (d1 < d0) { d0 = d1; i0 = candI[(long)BNTOT + n]; }
    int slot = atomicAdd(&cntAll[b * KFG + i0], 1);
    listF[((long)b * KFG + i0) * NPIX + slot] = nn;
  } else if (wb > 0.f) {
    float d0 = candD[2L * BNTOT + n]; int i0 = candI[2L * BNTOT + n];
    #pragma unroll
    for (int z = 3; z < 7; ++z) {
      float dz = candD[(long)z * BNTOT + n];
      if (dz < d0) { d0 = dz; i0 = candI[(long)z * BNTOT + n]; }
    }
    int slot = atomicAdd(&cntAll[NB * KFG + b * KBG + i0], 1);
    listB[((long)b * KBG + i0) * NPIX + slot] = nn;
  }
}

// ---------------- chunk-parallel gather-accumulate per cluster ----------------
// R7 post-mortem: single-block-per-cluster k_cacc was a STRAGGLER kernel — 45.4 µs
// at 1.7% occupancy. Fix (R9, verified): split each cluster's list into NCH=16
// contiguous chunks; grid (3, 70, NB*NCH) = 13,440 blocks; fp64 partial per chunk;
// k_cred sums in fixed chunk order. PC aliases T2 (dead during k-means; first
// written by the layer-0 attention-out GEMM). R13: moved from V because V now
// holds bf16 data (12.6 MB < PC's 13.8 MB). R8 lesson: never grow the workspace.
__global__ __launch_bounds__(128) void k_cacc(
    const float* __restrict__ X,
    const int* __restrict__ listF, const int* __restrict__ listB,
    const int* __restrict__ cntAll,
    double* __restrict__ PC) {
  __shared__ int ls[256];    // cs = ceil(4096/16) = 256 max
  int slice = blockIdx.x;    // 0..2
  int kq = blockIdx.y;       // 0..KFG+KBG-1
  int zz = blockIdx.z;       // b*NCH + ch
  int b = zz / NCH, ch = zz % NCH;
  int t = threadIdx.x;
  int c = slice * 128 + t;
  const int* list; int cnt;
  if (kq < KFG) {
    cnt = cntAll[b * KFG + kq];
    list = listF + ((long)b * KFG + kq) * NPIX;
  } else {
    int k = kq - KFG;
    cnt = cntAll[NB * KFG + b * KBG + k];
    list = listB + ((long)b * KBG + k) * NPIX;
  }
  int cs = (cnt + NCH - 1) / NCH;
  int i0 = ch * cs;
  int i1 = min(i0 + cs, cnt);
  int m = i1 - i0;                       // may be <= 0 -> partial stays 0
  for (int i = t; i < m; i += 128) ls[i] = list[i0 + i];
  __syncthreads();
  const float* Xb = X + (long)b * NPIX * CE;
  double acc = 0.0;
  int i = 0;
  for (; i + 4 <= m; i += 4) {
    int n0 = ls[i], n1 = ls[i + 1], n2 = ls[i + 2], n3 = ls[i + 3];
    float v0 = Xb[(long)n0 * CE + c];
    float v1 = Xb[(long)n1 * CE + c];
    float v2 = Xb[(long)n2 * CE + c];
    float v3 = Xb[(long)n3 * CE + c];
    acc += (double)v0; acc += (double)v1; acc += (double)v2; acc += (double)v3;
  }
  for (; i < m; ++i) acc += (double)Xb[(long)ls[i] * CE + c];
  // PC layout: [ch][b*(KFG+KBG)+kq][c]
  PC[((long)ch * (NB * (KFG + KBG)) + (long)b * (KFG + KBG) + kq) * CE + c] = acc;
}

// ---------------- reduce chunk partials -> center update (deterministic) ----------------
__global__ void k_cred(const double* __restrict__ PC, const int* __restrict__ cntAll,
                       const float* __restrict__ srcF, float* __restrict__ dstF,
                       const float* __restrict__ srcB, float* __restrict__ dstB) {
  int i = blockIdx.x * 256 + threadIdx.x;
  const int tot = NB * (KFG + KBG) * CE;
  if (i >= tot) return;
  int c = i % CE;
  int r = i / CE;                        // b*(KFG+KBG)+kq
  int kq = r % (KFG + KBG);
  int b = r / (KFG + KBG);
  const long stride = (long)NB * (KFG + KBG) * CE;
  double s = 0.0;
  #pragma unroll
  for (int ch = 0; ch < NCH; ++ch) s += PC[(long)ch * stride + (long)r * CE + c];
  if (kq < KFG) {
    int cnt = cntAll[b * KFG + kq];
    long o = ((long)b * KFG + kq) * CE + c;
    dstF[o] = (cnt > 0) ? (float)(s / (double)cnt) : srcF[o];
  } else {
    int k = kq - KFG;
    int cnt = cntAll[NB * KFG + b * KBG + k];
    long o = ((long)b * KBG + k) * CE + c;
    dstB[o] = (cnt > 0) ? (float)(s / (double)cnt) : srcB[o];
  }
}

// ---------------- fused pos + bf16 staging ----------------
__global__ void k_cvtQV(const float* __restrict__ X,
                        const float* __restrict__ yvf, const float* __restrict__ xvf,
                        const float* __restrict__ invdt, const float* __restrict__ notp,
                        float* __restrict__ POS,
                        unsigned short* __restrict__ QB, unsigned short* __restrict__ VBin) {
  long i = (long)blockIdx.x * 256 + threadIdx.x;
  if (i >= (long)NB * NPIX * CE) return;
  int c = (int)(i % CE);
  long row = i / CE;
  float p = (c < 192) ? yvf[row] : xvf[row];
  float v = p * invdt[c];
  int tt = (c < 192) ? c : c - 192;
  float r = (tt & 1) ? cosf(v) : sinf(v);
  POS[i] = r;
  float x = X[i];
  QB[i] = f2bf(x + r);
  VBin[i] = f2bf(x * notp[row]);
}

// ---------------- fused per-layer weight convert/transpose + concat bias ----------------
__global__ void k_cvtW_all(
    const float* __restrict__ Wv_l, const float* __restrict__ Woff_l,
    const float* __restrict__ Wa_l, const float* __restrict__ Wout_l,
    const float* __restrict__ Wf1_l, const float* __restrict__ Wf2_l,
    const float* __restrict__ boff_l, const float* __restrict__ ba_l,
    unsigned short* __restrict__ W0, unsigned short* __restrict__ W1,
    unsigned short* __restrict__ W3, unsigned short* __restrict__ W4,
    unsigned short* __restrict__ W5, float* __restrict__ biasCat) {
  int i = blockIdx.x * 256 + threadIdx.x;
  const int S = 147456, SF = 442368;
  if (i < S) {
    int n = i / 384, k = i % 384;
    W0[i] = f2bf(Wv_l[(long)k * 384 + n]);
  } else if (i < 2 * S) {
    int j = i - S; int n = j / 384, k = j % 384;
    float v = 0.f;
    if (n < 216) v = Woff_l[(long)k * 216 + n];
    else if (n < 324) v = Wa_l[(long)k * 108 + (n - 216)];
    W1[j] = f2bf(v);
  } else if (i < 3 * S) {
    int j = i - 2 * S; int n = j / 384, k = j % 384;
    W3[j] = f2bf(Wout_l[(long)k * 384 + n]);
  } else if (i < 3 * S + SF) {
    int j = i - 3 * S; int n = j / 384, k = j % 384;
    W4[j] = f2bf(Wf1_l[(long)k * 1152 + n]);
  } else if (i < 3 * S + 2 * SF) {
    int j = i - 3 * S - SF; int n = j / 1152, k = j % 1152;
    W5[j] = f2bf(Wf2_l[(long)k * 384 + n]);
  } else if (i < 3 * S + 2 * SF + 324) {
    int j = i - 3 * S - 2 * SF;
    biasCat[j] = (j < 216) ? boff_l[j] : ba_l[j - 216];
  }
}

// ---------------- bf16 MFMA GEMM: C = A @ Bt^T (+bias)(+relu) ----------------
// Staging via global_load_lds width=16. XCD-bijective remap (verified R9: FFN FETCH
// 56.7 -> 22.2/12.3 MB). LDS XOR-swizzle (verified R11: conflicts 1.77M -> 0).
// 2-phase double-buffered K-loop (verified R12: FFN 55 -> <43 µs, total -25 µs):
// prefetch next K-tile into the other buffer pair before computing the current one,
// ONE barrier per K-step; four statically distinct LDS arrays so the compiler can
// prove no aliasing between prefetch writes and current-tile ds_reads.
__global__ __launch_bounds__(256) void k_gemm_bf(
    const unsigned short* __restrict__ A, const unsigned short* __restrict__ Bt,
    const float* __restrict__ bias, float* __restrict__ Cf, unsigned short* __restrict__ Cb,
    int M, int K, int N, int relu) {
  __shared__ unsigned short As0[128 * 32];
  __shared__ unsigned short Bs0[128 * 32];
  __shared__ unsigned short As1[128 * 32];
  __shared__ unsigned short Bs1[128 * 32];
  int bx, by;
  {
    int gx = gridDim.x;
    int q = blockIdx.y * gx + blockIdx.x;
    if ((gridDim.y & 7) == 0) {
      int xcd = q & 7;
      int r = q >> 3;
      bx = r % gx;
      by = xcd + 8 * (r / gx);
    } else { bx = blockIdx.x; by = blockIdx.y; }
  }
  int m0 = by * 128, n0 = bx * 128;
  int t = threadIdx.x;
  int w = t >> 6, l = t & 63;
  int wm = w >> 1, wn = w & 1;
  int half = l >> 4, lr = l & 15;
  float4v acc[4][4] = {};

  auto STAGE = [&](unsigned short* AD, unsigned short* BD, int kk) {
    #pragma unroll
    for (int i = 0; i < 2; ++i) {
      int c = w * 64 + i * 256 + l;           // 0..511 = LDS slot index
      int r = c >> 2;
      int part = (c & 3) ^ ((r >> 1) & 3);    // swizzled global source chunk
      int ldsOff = (w * 64 + i * 256) * 8;    // shorts; lane adds l*16 bytes
      __builtin_amdgcn_global_load_lds(
          (const AS1 unsigned int*)(A + (size_t)(m0 + r) * K + kk + part * 8),
          (AS3 unsigned int*)(AD + ldsOff), 16, 0, 0);
      __builtin_amdgcn_global_load_lds(
          (const AS1 unsigned int*)(Bt + (size_t)(n0 + r) * K + kk + part * 8),
          (AS3 unsigned int*)(BD + ldsOff), 16, 0, 0);
    }
  };
  auto COMPUTE = [&](const unsigned short* AD, const unsigned short* BD) {
    short8 af[4], bfr[4];
    #pragma unroll
    for (int am = 0; am < 4; ++am) {
      int arow = wm * 64 + am * 16 + lr;
      af[am] = *(const short8*)(&AD[arow * 32 + (half ^ ((arow >> 1) & 3)) * 8]);
    }
    #pragma unroll
    for (int bn = 0; bn < 4; ++bn) {
      int brow = wn * 64 + bn * 16 + lr;
      bfr[bn] = *(const short8*)(&BD[brow * 32 + (half ^ ((brow >> 1) & 3)) * 8]);
    }
    #pragma unroll
    for (int am = 0; am < 4; ++am)
      #pragma unroll
      for (int bn = 0; bn < 4; ++bn)
        acc[am][bn] = __builtin_amdgcn_mfma_f32_16x16x32_bf16(af[am], bfr[bn], acc[am][bn], 0, 0, 0);
  };

  STAGE(As0, Bs0, 0);
  __syncthreads();
  for (int k0 = 0; k0 < K; k0 += 64) {
    // phase 0: prefetch k0+32 into buf1 while computing buf0
    STAGE(As1, Bs1, k0 + 32);               // k0+32 < K always (K % 64 == 0)
    COMPUTE(As0, Bs0);
    __syncthreads();
    // phase 1: prefetch k0+64 into buf0 (unless last) while computing buf1
    if (k0 + 64 < K) STAGE(As0, Bs0, k0 + 64);
    COMPUTE(As1, Bs1);
    __syncthreads();
  }
  #pragma unroll
  for (int am = 0; am < 4; ++am) {
    #pragma unroll
    for (int bn = 0; bn < 4; ++bn) {
      int gc = n0 + wn * 64 + bn * 16 + lr;
      if (gc < N) {
        float bv = bias ? bias[gc] : 0.f;
        int gr0 = m0 + wm * 64 + am * 16 + half * 4;
        #pragma unroll
        for (int r = 0; r < 4; ++r) {
          float v = acc[am][bn][r] + bv;
          if (relu) v = fmaxf(v, 0.f);
          size_t oi = (size_t)(gr0 + r) * N + gc;
          if (Cf) Cf[oi] = v;
          else Cb[oi] = f2bf(v);
        }
      }
    }
  }
}

// ---------------- coords+softmax: one thread per (row, head) ----------------
__global__ void k_coords(const unsigned short* __restrict__ OAB, float4* __restrict__ CRD) {
  int idx = blockIdx.x * 256 + threadIdx.x;
  if (idx >= NB * NPIX * NH) return;
  int row = idx / NH, h = idx % NH;
  int n = row & (NPIX - 1);
  int hh = n >> 6, ww = n & 63;
  float refx = ((float)ww + 0.5f) / (float)WDIM;
  float refy = ((float)hh + 0.5f) / (float)HDIM;
  const unsigned short* oab = OAB + (size_t)row * 324;
  float f[NPTS];
  #pragma unroll
  for (int j = 0; j < NPTS; ++j) f[j] = bf2f(oab[216 + h * 9 + j]);
  float m = f[0];
  #pragma unroll
  for (int j = 1; j < NPTS; ++j) m = fmaxf(m, f[j]);
  float s = 0.f;
  #pragma unroll
  for (int j = 0; j < NPTS; ++j) { f[j] = expf(f[j] - m); s += f[j]; }
  float inv = 1.f / s;
  float4* crd = CRD + (size_t)row * 108 + h * 9;
  #pragma unroll
  for (int p = 0; p < NPTS; ++p) {
    float ox = bf2f(oab[h * 18 + p * 2 + 0]);
    float oy = bf2f(oab[h * 18 + p * 2 + 1]);
    float lx = refx + ox / (float)WDIM;
    float ly = refy + oy / (float)HDIM;
    float xs = lx * (float)WDIM - 0.5f;
    float ys = ly * (float)HDIM - 0.5f;
    float x0f = floorf(xs), y0f = floorf(ys);
    int x0 = (int)x0f, y0 = (int)y0f;
    float4 o;
    o.x = xs - x0f;
    o.y = ys - y0f;
    o.z = f[p] * inv;
    o.w = __int_as_float((y0 << 16) | (x0 & 0xFFFF));
    crd[p] = o;
  }
}

// ---------------- gather: bf16 V, 8 channels/thread ----------------
// R12 post-mortem: gather was the top cost (43 µs x2) at VALU 50%, HBM 14.8%,
// ~900 MB semantic L1/L2 traffic (FETCH only 37 MB -> caches absorb 96%).
// R13: (1) V stored bf16 by the V-projection GEMM's existing bf16 epilogue ->
// L2 bytes halve. V feeds ONLY this gather, whose output T1b is already bf16;
// pre-rounding V adds ~6e-4 abs at the attention output (Wout scale 0.02) —
// far below the stable 0.03125 absmax. (2) 8 ch/thread (786K threads): per-point
// address/validity/weight work amortized 2x; bf16 unpack is 1 op/channel
// (shift or mask of the loaded dword). Validity folded into weights
// (w=0 * clamped-load == old zeroed-load semantics, exactly).
__global__ __launch_bounds__(256) void k_gather(
    const unsigned short* __restrict__ VB, const float4* __restrict__ CRD,
    uint4* __restrict__ ATTu) {
  int idx = blockIdx.x * 256 + threadIdx.x;
  if (idx >= NB * NPIX * (CE / 8)) return;
  int row = idx / (CE / 8), cq = idx % (CE / 8);
  int c = cq * 8;
  int h = c >> 5;
  int b = row >> 12;
  const unsigned short* vb = VB + (size_t)b * NPIX * CE;
  const float4* crd = CRD + (size_t)row * 108 + h * 9;
  float a[8];
  #pragma unroll
  for (int j = 0; j < 8; ++j) a[j] = 0.f;
  #pragma unroll
  for (int p = 0; p < NPTS; ++p) {
    float4 o = crd[p];
    int pk = __float_as_int(o.w);
    int x0 = (int)(short)(pk & 0xFFFF);
    int y0 = pk >> 16;
    float wx = o.x, wy = o.y, aw = o.z;
    int x1 = x0 + 1, y1 = y0 + 1;
    float vx0 = (x0 >= 0 && x0 < WDIM) ? 1.f : 0.f;
    float vx1 = (x1 >= 0 && x1 < WDIM) ? 1.f : 0.f;
    float vy0 = (y0 >= 0 && y0 < HDIM) ? 1.f : 0.f;
    float vy1 = (y1 >= 0 && y1 < HDIM) ? 1.f : 0.f;
    int x0c = min(max(x0, 0), WDIM - 1), x1c = min(max(x1, 0), WDIM - 1);
    int y0c = min(max(y0, 0), HDIM - 1), y1c = min(max(y1, 0), HDIM - 1);
    float w00 = (1.f - wx) * (1.f - wy) * aw * vx0 * vy0;
    float w01 = wx * (1.f - wy) * aw * vx1 * vy0;
    float w10 = (1.f - wx) * wy * aw * vx0 * vy1;
    float w11 = wx * wy * aw * vx1 * vy1;
    uint4 u00 = *(const uint4*)(vb + (size_t)(y0c * WDIM + x0c) * CE + c);
    uint4 u01 = *(const uint4*)(vb + (size_t)(y0c * WDIM + x1c) * CE + c);
    uint4 u10 = *(const uint4*)(vb + (size_t)(y1c * WDIM + x0c) * CE + c);
    uint4 u11 = *(const uint4*)(vb + (size_t)(y1c * WDIM + x1c) * CE + c);
    const unsigned* q00 = (const unsigned*)&u00;
    const unsigned* q01 = (const unsigned*)&u01;
    const unsigned* q10 = (const unsigned*)&u10;
    const unsigned* q11 = (const unsigned*)&u11;
    #pragma unroll
    for (int d = 0; d < 4; ++d) {
      float g00l = __uint_as_float(q00[d] << 16), g00h = __uint_as_float(q00[d] & 0xFFFF0000u);
      float g01l = __uint_as_float(q01[d] << 16), g01h = __uint_as_float(q01[d] & 0xFFFF0000u);
      float g10l = __uint_as_float(q10[d] << 16), g10h = __uint_as_float(q10[d] & 0xFFFF0000u);
      float g11l = __uint_as_float(q11[d] << 16), g11h = __uint_as_float(q11[d] & 0xFFFF0000u);
      a[2 * d]     += g00l * w00 + g01l * w01 + g10l * w10 + g11l * w11;
      a[2 * d + 1] += g00h * w00 + g01h * w01 + g10h * w10 + g11h * w11;
    }
  }
  uint4 pk4;
  pk4.x = (unsigned)f2bf(a[0]) | ((unsigned)f2bf(a[1]) << 16);
  pk4.y = (unsigned)f2bf(a[2]) | ((unsigned)f2bf(a[3]) << 16);
  pk4.z = (unsigned)f2bf(a[4]) | ((unsigned)f2bf(a[5]) << 16);
  pk4.w = (unsigned)f2bf(a[6]) | ((unsigned)f2bf(a[7]) << 16);
  ATTu[(size_t)row * (CE / 8) + cq] = pk4;
}

// ---------------- LayerNorm(X + T), 4 rows/block, fused epilogues ----------------
__global__ __launch_bounds__(256) void k_ln(
    float* __restrict__ X, const float* __restrict__ T,
    const float* __restrict__ g, const float* __restrict__ bb,
    unsigned short* __restrict__ xbOut,
    const float* __restrict__ posp, const float* __restrict__ notp,
    unsigned short* __restrict__ qb, unsigned short* __restrict__ vbin,
    float* __restrict__ outp) {
  int t = threadIdx.x;
  int row = blockIdx.x * 4 + (t >> 6);
  int lane = t & 63;
  float* xr = X + (long)row * CE;
  const float* tr = T + (long)row * CE;
  float v[6]; float s = 0.f;
  #pragma unroll
  for (int i = 0; i < 6; ++i) { v[i] = xr[lane + 64 * i] + tr[lane + 64 * i]; s += v[i]; }
  #pragma unroll
  for (int o = 32; o > 0; o >>= 1) s += __shfl_down(s, o, 64);
  s = __shfl(s, 0, 64);
  float m = s / (float)CE;
  float var = 0.f;
  #pragma unroll
  for (int i = 0; i < 6; ++i) { float d = v[i] - m; var += d * d; }
  #pragma unroll
  for (int o = 32; o > 0; o >>= 1) var += __shfl_down(var, o, 64);
  var = __shfl(var, 0, 64);
  float rst = rsqrtf(var / (float)CE + 1e-5f);
  float nprow = notp ? notp[row] : 0.f;
  int b = row >> 12, n = row & (NPIX - 1);
  #pragma unroll
  for (int i = 0; i < 6; ++i) {
    int c = lane + 64 * i;
    float xn = (v[i] - m) * rst * g[c] + bb[c];
    if (outp) outp[((long)b * NROW + n) * CE + c] = xn;
    else xr[c] = xn;
    if (xbOut) xbOut[(long)row * CE + c] = f2bf(xn);
    if (qb) {
      qb[(long)row * CE + c] = f2bf(xn + posp[(long)row * CE + c]);
      vbin[(long)row * CE + c] = f2bf(xn * nprow);
    }
  }
}

// ---------------- centers -> output ----------------
__global__ void k_out_cen(const float* __restrict__ fg, const float* __restrict__ bg,
                          float* __restrict__ out) {
  int i = blockIdx.x * 256 + threadIdx.x;
  const int tot = NB * (KFG + KBG) * CE;
  if (i >= tot) return;
  int c = i % CE;
  int r = i / CE;
  int rr = r % (KFG + KBG);
  int b = r / (KFG + KBG);
  float v;
  if (rr < KFG) v = fg[((long)b * KFG + rr) * CE + c];
  else v = bg[((long)b * KBG + (rr - KFG)) * CE + c];
  out[((long)b * NROW + NPIX + rr) * CE + c] = v;
}

extern "C" void kernel_launch(void* const* d_in, const int* in_sizes, int n_in,
                              void* d_out, int out_size, void* d_ws, size_t ws_size,
                              hipStream_t stream) {
  (void)in_sizes; (void)n_in; (void)out_size; (void)ws_size;
  const float* s_x  = (const float*)d_in[0];
  const float* s_pm = (const float*)d_in[1];
  const float* s_sm = (const float*)d_in[2];
  const float* Wv   = (const float*)d_in[3];
  const float* bv   = (const float*)d_in[4];
  const float* Woff = (const float*)d_in[5];
  const float* boff = (const float*)d_in[6];
  const float* Wa   = (const float*)d_in[7];
  const float* ba   = (const float*)d_in[8];
  const float* Wout = (const float*)d_in[9];
  const float* bout = (const float*)d_in[10];
  const float* ln1g = (const float*)d_in[11];
  const float* ln1b = (const float*)d_in[12];
  const float* Wf1  = (const float*)d_in[13];
  const float* Wf2  = (const float*)d_in[14];
  const float* ln2g = (const float*)d_in[15];
  const float* ln2b = (const float*)d_in[16];
  float* out = (float*)d_out;
  char* pb = (char*)d_ws;

  const long BN  = (long)NB * NPIX;      // 16384
  const long BNC = BN * CE;              // 6291456

  float* X    = (float*)pb; pb += BNC * 4;
  float* POS  = (float*)pb; pb += BNC * 4;
  float* V    = (float*)pb; pb += BNC * 4;   // holds bf16 V (12.6 MB used of 25.2)
  float* T2   = (float*)pb; pb += BNC * 4;
  unsigned short* VBh = (unsigned short*)V;  // bf16 view for V-GEMM + gather
  double* PC  = (double*)T2;  // 13.8 MB chunk partials alias T2 (dead during k-means;
                              // first written by layer-0 attn-out GEMM). Moved from V
                              // in R13 since V now holds live bf16 data of 12.6 MB.
  unsigned short* QB   = (unsigned short*)pb; pb += BNC * 2;
  unsigned short* VBin = (unsigned short*)pb; pb += BNC * 2;
  unsigned short* T1b  = (unsigned short*)pb; pb += BNC * 2;
  unsigned short* Zbf  = QB;   // FFN hidden aliases QB+VBin+T1b
  unsigned short* XB   = (unsigned short*)pb; pb += BNC * 2;
  unsigned short* OAB  = (unsigned short*)pb; pb += BN * 324 * 2;
  float4* CRD = (float4*)pb; pb += BN * 108 * 16;
  const int S_W = 147456, S_F = 442368;
  unsigned short* WT[NLAYERS][5];
  float* biasCat[NLAYERS];
  for (int l = 0; l < NLAYERS; ++l) {
    WT[l][0] = (unsigned short*)pb; pb += S_W * 2;
    WT[l][1] = (unsigned short*)pb; pb += S_W * 2;
    WT[l][2] = (unsigned short*)pb; pb += S_W * 2;
    WT[l][3] = (unsigned short*)pb; pb += S_F * 2;
    WT[l][4] = (unsigned short*)pb; pb += S_F * 2;
    biasCat[l] = (float*)pb; pb += 324 * 4;
  }
  float* padf = (float*)pb; pb += BN * 4;
  float* objf = (float*)pb; pb += BN * 4;
  float* notp = (float*)pb; pb += BN * 4;
  float* wfg  = (float*)pb; pb += BN * 4;
  float* wbg  = (float*)pb; pb += BN * 4;
  float* yvf  = (float*)pb; pb += BN * 4;
  float* xvf  = (float*)pb; pb += BN * 4;
  float* invdt = (float*)pb; pb += CE * 4;
  pb = (char*)(((size_t)pb + 7) & ~(size_t)7);
  double* xsq   = (double*)pb; pb += BN * 8;
  float* candD = (float*)pb; pb += BN * 7 * 4;            // per-chunk best distance (fp32)
  float* cFgA = (float*)pb; pb += (long)NB * KFG * CE * 4;  // fp32 centers
  float* cFgB = (float*)pb; pb += (long)NB * KFG * CE * 4;
  float* cBgA = (float*)pb; pb += (long)NB * KBG * CE * 4;
  float* cBgB = (float*)pb; pb += (long)NB * KBG * CE * 4;
  int* candI  = (int*)pb; pb += BN * 7 * 4;               // per-chunk best global-k
  int* cntAll = (int*)pb; pb += NB * (KFG + KBG) * 4;     // cluster counts (FG then BG)
  int* listF  = (int*)pb; pb += (long)NB * KFG * NPIX * 4;
  int* listB  = (int*)pb; pb += (long)NB * KBG * NPIX * 4;

  int bn = (int)BN;
  int cvtBlocks = (int)((BNC + 255) / 256);

  k_masks<<<(bn + 255) / 256, 256, 0, stream>>>(s_pm, s_sm, padf, objf, notp, wfg, wbg);
  k_transpose<<<dim3(NPIX / 64, CE / 64, NB), 256, 0, stream>>>(s_x, X);
  k_xsq<<<bn, 64, 0, stream>>>(X, xsq);
  k_cums<<<NB, 128, 0, stream>>>(padf, yvf, xvf, invdt);
  k_cvtQV<<<cvtBlocks, 256, 0, stream>>>(X, yvf, xvf, invdt, notp, POS, QB, VBin);

  const int CVTW_TOT = 3 * S_W + 2 * S_F + 324;
  for (int l = 0; l < NLAYERS; ++l) {
    k_cvtW_all<<<(CVTW_TOT + 255) / 256, 256, 0, stream>>>(
        Wv + (long)l * CE * CE, Woff + (long)l * CE * 216, Wa + (long)l * CE * 108,
        Wout + (long)l * CE * CE, Wf1 + (long)l * CE * 1152, Wf2 + (long)l * 1152 * CE,
        boff + l * 216, ba + l * 108,
        WT[l][0], WT[l][1], WT[l][2], WT[l][3], WT[l][4], biasCat[l]);
  }

  // ---- kmeans: dots(+chunk argmin) -> asn(bucket lists) -> cacc(chunk partials) -> cred ----
  float *srcF = cFgA, *dstF = cFgB, *srcB = cBgA, *dstB = cBgB;
  k_kinit<<<NB, 256, 0, stream>>>(X, wfg, srcF, KFG);
  k_kinit<<<NB, 256, 0, stream>>>(X, wbg, srcB, KBG);
  const int credBlocks = (NB * (KFG + KBG) * CE + 255) / 256;
  for (int it = 0; it < NITER; ++it) {
    k_dots<<<dim3(bn / 128, 7), 256, 0, stream>>>(X, xsq, srcF, srcB, candD, candI, cntAll);
    k_asn<<<(bn + 255) / 256, 256, 0, stream>>>(candD, candI, wfg, wbg, listF, listB, cntAll);
    k_cacc<<<dim3(3, KFG + KBG, NB * NCH), 128, 0, stream>>>(
        X, listF, listB, cntAll, PC);
    k_cred<<<credBlocks, 256, 0, stream>>>(PC, cntAll, srcF, dstF, srcB, dstB);
    float* tmp;
    tmp = srcF; srcF = dstF; dstF = tmp;
    tmp = srcB; srcB = dstB; dstB = tmp;
  }
  float* fgC = srcF; float* bgC = srcB;

  // ---- layers ----
  for (int l = 0; l < NLAYERS; ++l) {
    const float* bv_l   = bv   + l * CE;
    const float* bout_l = bout + l * CE;
    int last = (l == NLAYERS - 1);

    k_gemm_bf<<<dim3(3, 128), 256, 0, stream>>>(VBin, WT[l][0], bv_l, (float*)nullptr, VBh,
                                                bn, CE, 384, 0);
    k_gemm_bf<<<dim3(3, 128), 256, 0, stream>>>(QB, WT[l][1], biasCat[l], (float*)nullptr, OAB,
                                                bn, CE, 324, 0);
    k_coords<<<(bn * NH + 255) / 256, 256, 0, stream>>>(OAB, CRD);
    k_gather<<<(bn * (CE / 8) + 255) / 256, 256, 0, stream>>>(VBh, CRD, (uint4*)T1b);
    k_gemm_bf<<<dim3(3, 128), 256, 0, stream>>>(T1b, WT[l][2], bout_l, T2, (unsigned short*)nullptr,
                                                bn, CE, 384, 0);
    k_ln<<<bn / 4, 256, 0, stream>>>(X, T2, ln1g + l * CE, ln1b + l * CE,
                                     XB, (const float*)nullptr, (const float*)nullptr,
                                     (unsigned short*)nullptr, (unsigned short*)nullptr,
                                     (float*)nullptr);
    k_gemm_bf<<<dim3(9, 128), 256, 0, stream>>>(XB, WT[l][3], (const float*)nullptr,
                                                (float*)nullptr, Zbf, bn, CE, 1152, 1);
    k_gemm_bf<<<dim3(3, 128), 256, 0, stream>>>(Zbf, WT[l][4], (const float*)nullptr,
                                                T2, (unsigned short*)nullptr, bn, 1152, 384, 0);
    if (!last) {
      k_ln<<<bn / 4, 256, 0, stream>>>(X, T2, ln2g + l * CE, ln2b + l * CE,
                                       (unsigned short*)nullptr, POS, notp, QB, VBin,
                                       (float*)nullptr);
    } else {
      k_ln<<<bn / 4, 256, 0, stream>>>(X, T2, ln2g + l * CE, ln2b + l * CE,
                                       (unsigned short*)nullptr, (const float*)nullptr,
                                       (const float*)nullptr, (unsigned short*)nullptr,
                                       (unsigned short*)nullptr, out);
    }
  }

  k_out_cen<<<(NB * (KFG + KBG) * CE + 255) / 256, 256, 0, stream>>>(fgC, bgC, out);
}

// Round 14
// 1213.060 us; speedup vs baseline: 1.1977x; 1.0193x over previous
//
#include <hip/hip_runtime.h>
#include <hip/hip_bf16.h>
#include <math.h>

#define NB 4
#define CE 384
#define NH 12
#define DH 32
#define NPTS 9
#define NLAYERS 2
#define KFG 20
#define KBG 50
#define NITER 10
#define HDIM 64
#define WDIM 64
#define NPIX 4096
#define BNTOT (NB * NPIX)
#define NROW (NPIX + KFG + KBG)
#define NCH 16
#define TWO_PI 6.283185307179586f

#define AS1 __attribute__((address_space(1)))
#define AS3 __attribute__((address_space(3)))

typedef __attribute__((ext_vector_type(8))) short short8;
typedef __attribute__((ext_vector_type(4))) float float4v;

static __device__ __forceinline__ unsigned short f2bf(float f) {
  __hip_bfloat16 h = __float2bfloat16(f);
  return *reinterpret_cast<unsigned short*>(&h);
}
static __device__ __forceinline__ float bf2f(unsigned short u) {
  unsigned x = ((unsigned)u) << 16;
  return __uint_as_float(x);
}

// ---------------- masks ----------------
__global__ void k_masks(const float* __restrict__ pm, const float* __restrict__ sm,
                        float* padf, float* objf, float* notp, float* wfg, float* wbg) {
  int i = blockIdx.x * 256 + threadIdx.x;
  if (i >= NB * NPIX) return;
  float p  = (pm[i] == 255.0f) ? 1.f : 0.f;
  float o  = (sm[i] == 1.0f) ? 1.f : 0.f;
  float np_ = 1.f - p;
  padf[i] = p; objf[i] = o; notp[i] = np_;
  wfg[i] = o * np_;
  wbg[i] = (1.f - o) * np_;
}

// ---------------- LDS-tiled transpose s_x [B,C,N] -> X [B,N,C] ----------------
__global__ __launch_bounds__(256) void k_transpose(const float* __restrict__ sx,
                                                   float* __restrict__ X) {
  __shared__ float tile[64][65];
  int nb = blockIdx.x * 64, cb = blockIdx.y * 64, b = blockIdx.z;
  int t = threadIdx.x;
  for (int idx = t; idx < 64 * 64; idx += 256) {
    int cc = idx >> 6, nn = idx & 63;
    tile[cc][nn] = sx[((long)b * CE + cb + cc) * NPIX + nb + nn];
  }
  __syncthreads();
  for (int idx = t; idx < 64 * 64; idx += 256) {
    int nn = idx >> 6, cc = idx & 63;
    X[((long)b * NPIX + nb + nn) * CE + cb + cc] = tile[cc][nn];
  }
}

// ---------------- xsq (fp64) ----------------
__global__ void k_xsq(const float* __restrict__ X, double* __restrict__ xsq) {
  int row = blockIdx.x; int t = threadIdx.x;
  const float* xr = X + (long)row * CE;
  double s = 0.0;
  for (int i = t; i < CE; i += 64) { double v = (double)xr[i]; s += v * v; }
  #pragma unroll
  for (int o = 32; o > 0; o >>= 1) s += __shfl_down(s, o, 64);
  if (t == 0) xsq[row] = s;
}

// ---------------- pos cumsums + invdt table (LDS-staged; scans bit-identical) ----------------
__global__ __launch_bounds__(128) void k_cums(const float* __restrict__ padf,
                                              float* __restrict__ yvf,
                                              float* __restrict__ xvf,
                                              float* __restrict__ invdt) {
  __shared__ float pad_s[NPIX];
  int b = blockIdx.x; int t = threadIdx.x;
  for (int i = t; i < NPIX; i += 128) pad_s[i] = padf[b * NPIX + i];
  if (b == 0) {
    for (int c = t; c < CE; c += 128) {
      int tt = (c < 192) ? c : c - 192;
      invdt[c] = 1.0f / powf(10000.0f, (float)(2 * (tt / 2)) / 192.0f);
    }
  }
  __syncthreads();
  if (t < 64) {
    int w = t;
    float cum[64]; float tot = 0.f;
    for (int h = 0; h < 64; ++h) {
      float nm = 1.f - pad_s[h * WDIM + w];
      tot += nm; cum[h] = tot;
    }
    float sc = 1.f / (tot + 1e-6f);
    for (int h = 0; h < 64; ++h) yvf[b * NPIX + h * WDIM + w] = cum[h] * sc * TWO_PI;
  } else {
    int h = t - 64;
    float cum[64]; float tot = 0.f;
    for (int w = 0; w < 64; ++w) {
      float nm = 1.f - pad_s[h * WDIM + w];
      tot += nm; cum[w] = tot;
    }
    float sc = 1.f / (tot + 1e-6f);
    for (int w = 0; w < 64; ++w) xvf[b * NPIX + h * WDIM + w] = cum[w] * sc * TWO_PI;
  }
}

// ---------------- kmeans init (fp32 centers; X values are fp32 -> exact) ----------------
__global__ void k_kinit(const float* __restrict__ X, const float* __restrict__ wts,
                        float* __restrict__ cen, int K) {
  int b = blockIdx.x;
  __shared__ int idx[KBG];
  if (threadIdx.x == 0) {
    int cnt = 0;
    for (int n = 0; n < NPIX && cnt < K; ++n) if (wts[b * NPIX + n] > 0.f) idx[cnt++] = n;
    for (int n = 0; n < NPIX && cnt < K; ++n) if (!(wts[b * NPIX + n] > 0.f)) idx[cnt++] = n;
  }
  __syncthreads();
  for (int i = threadIdx.x; i < K * CE; i += blockDim.x) {
    int k = i / CE, c = i % CE;
    cen[((long)b * K + k) * CE + c] = X[((long)b * NPIX + idx[k]) * CE + c];
  }
}

// ---------------- kmeans distances: fp32 centers, 128 px/block, 2 px/thread ----------------
// Layout FROZEN at the R7 config (R10's relayout regressed 40->62; reverted).
// R14 (schedule-only, value-preserving): measured 40.6 µs vs floors VALU 5.6 µs
// (440M FMA / 1024 SIMDs) + LDS 16.8 µs (860K wave-b128 x 12cyc/256CU) -> ~18 µs
// of exposed load latency at the grid-capped 14 waves/CU (VALU 25%, HBM 5%).
// (1) X prefetch rotation: next iteration's 4 float4 loads issue BEFORE this
//     iteration's 160 FMAs (~320 cyc slack >= L2 latency). Same values, same FMA
//     order -> bit-identical. +16 VGPR (56 -> ~72, no occupancy change).
// (2) csq computed from the LDS tile (identical values, identical c-order ->
//     bit-identical sum) instead of re-reading centers from global: saves 13.4 MB
//     of L2 re-reads + a serial global-latency chain. Costs one extra barrier.
// Pre-commit: if k_dots lands 40.6 +/- 2 µs, compiler was already pipelining ->
// declare k_dots at structural plateau.
// grid (BN/128, 7), block 256 = 64 px-pairs x 4-way channel split (h = t&3, 96 ch).
// LDS padding: HSTR4=104 floats -> h-group bases at banks {0,8,16,24}; each wave
// b128 read touches 4 unique addrs (16-lane broadcast), conflict-free.
#define HSTR4 104
#define KSTR4 416

__global__ __launch_bounds__(256) void k_dots(
    const float* __restrict__ X, const double* __restrict__ xsq,
    const float* __restrict__ cenF, const float* __restrict__ cenB,
    float* __restrict__ candD, int* __restrict__ candI, int* __restrict__ cntAll) {
  __shared__ float ct[10 * KSTR4];
  __shared__ float csq_s[10];
  int z = blockIdx.y;
  int isBg = (z >= 2) ? 1 : 0;
  int k0 = isBg ? (z - 2) * 10 : z * 10;
  int t = threadIdx.x;
  int h = t & 3;
  int n = blockIdx.x * 128 + (t >> 2) * 2;   // first of this thread's 2 pixels
  int b = blockIdx.x >> 5;                   // 32 blocks per batch
  if (blockIdx.x == 0 && z == 0) {
    for (int i = t; i < NB * (KFG + KBG); i += 256) cntAll[i] = 0;
  }
  const float* cb = (isBg ? cenB + (long)b * KBG * CE
                          : cenF + (long)b * KFG * CE) + (long)k0 * CE;
  for (int i = t; i < 10 * CE; i += 256) {
    int k = i / CE, c = i % CE;
    ct[k * KSTR4 + (c / 96) * HSTR4 + (c % 96)] = cb[i];
  }
  __syncthreads();                           // ct visible before csq reads it
  {
    int w = t >> 6, lane = t & 63;           // 4 waves cover centers 0..9
    for (int kk = w; kk < 10; kk += 4) {
      double s = 0.0;
      for (int c = lane; c < CE; c += 64) {
        double v = (double)ct[kk * KSTR4 + (c / 96) * HSTR4 + (c % 96)];
        s += v * v;
      }
      #pragma unroll
      for (int o = 32; o > 0; o >>= 1) s += __shfl_down(s, o, 64);
      if (lane == 0) csq_s[kk] = (float)s;
    }
  }
  __syncthreads();
  const float* xr = X + (long)n * CE + h * 96;
  const float* cth = ct + h * HSTR4;
  float acc[10][2];
  #pragma unroll
  for (int k = 0; k < 10; ++k) { acc[k][0] = 0.f; acc[k][1] = 0.f; }
  float4 xa[2], xb[2];
  #pragma unroll
  for (int p = 0; p < 2; ++p) {
    xa[p] = *(const float4*)(xr + p * CE);
    xb[p] = *(const float4*)(xr + p * CE + 4);
  }
  for (int c0 = 0; c0 < 96; c0 += 8) {
    float4 nxa[2], nxb[2];
    if (c0 + 8 < 96) {
      #pragma unroll
      for (int p = 0; p < 2; ++p) {
        nxa[p] = *(const float4*)(xr + p * CE + c0 + 8);
        nxb[p] = *(const float4*)(xr + p * CE + c0 + 12);
      }
    }
    #pragma unroll
    for (int k = 0; k < 10; ++k) {
      float4 c1 = *(const float4*)(&cth[k * KSTR4 + c0]);       // 4 unique addrs/wave
      float4 c2 = *(const float4*)(&cth[k * KSTR4 + c0 + 4]);
      #pragma unroll
      for (int p = 0; p < 2; ++p) {
        float a = acc[k][p];
        a += xa[p].x * c1.x; a += xa[p].y * c1.y;
        a += xa[p].z * c1.z; a += xa[p].w * c1.w;
        a += xb[p].x * c2.x; a += xb[p].y * c2.y;
        a += xb[p].z * c2.z; a += xb[p].w * c2.w;
        acc[k][p] = a;
      }
    }
    if (c0 + 8 < 96) {
      #pragma unroll
      for (int p = 0; p < 2; ++p) { xa[p] = nxa[p]; xb[p] = nxb[p]; }
    }
  }
  // combine the 4 channel-quarter partials (lanes t, t^1, t^2 are same-wave)
  #pragma unroll
  for (int k = 0; k < 10; ++k)
    #pragma unroll
    for (int p = 0; p < 2; ++p) {
      float a = acc[k][p];
      a += __shfl_xor(a, 1, 64);
      a += __shfl_xor(a, 2, 64);
      acc[k][p] = a;
    }
  if (h == 0) {
    #pragma unroll
    for (int p = 0; p < 2; ++p) {
      float qn = (float)xsq[n + p];
      float best = 3.0e38f; int bi = 0;
      #pragma unroll
      for (int k = 0; k < 10; ++k) {
        float d = qn - 2.0f * acc[k][p] + csq_s[k];
        if (d < best) { best = d; bi = k0 + k; }
      }
      long gi = (long)z * BNTOT + n + p;
      candD[gi] = best;
      candI[gi] = bi;
    }
  }
}

// ---------------- final argmin over 7 chunk candidates + bucket scatter ----------------
// One thread per pixel. FG candidates are chunks z=0..1, BG z=2..6. Strict < in ascending
// z preserves the reference's earliest-index argmin. Pixels are scattered into per-cluster
// index lists; within-cluster order is nondeterministic (atomic slots) which only perturbs
// the fp64 summation order in k_cacc (~1 ulp, far below tolerance).
__global__ void k_asn(const float* __restrict__ candD, const int* __restrict__ candI,
                      const float* __restrict__ wfg, const float* __restrict__ wbg,
                      int* __restrict__ listF, int* __restrict__ listB,
                      int* __restrict__ cntAll) {
  int n = blockIdx.x * 256 + threadIdx.x;
  if (n >= BNTOT) return;
  int b = n >> 12;
  int nn = n & (NPIX - 1);
  float wf = wfg[n], wb = wbg[n];
  if (wf > 0.f) {
    float d0 = candD[n]; int i0 = candI[n];
    float d1 = candD[(long)BNTOT + n];
    if (d1 < d0) { d0 = d1; i0 = candI[(long)BNTOT + n]; }
    int slot = atomicAdd(&cntAll[b * KFG + i0], 1);
    listF[((long)b * KFG + i0) * NPIX + slot] = nn;
  } else if (wb > 0.f) {
    float d0 = candD[2L * BNTOT + n]; int i0 = candI[2L * BNTOT + n];
    #pragma unroll
    for (int z = 3; z < 7; ++z) {
      float dz = candD[(long)z * BNTOT + n];
      if (dz < d0) { d0 = dz; i0 = candI[(long)z * BNTOT + n]; }
    }
    int slot = atomicAdd(&cntAll[NB * KFG + b * KBG + i0], 1);
    listB[((long)b * KBG + i0) * NPIX + slot] = nn;
  }
}

// ---------------- chunk-parallel gather-accumulate per cluster ----------------
// R7 post-mortem: single-block-per-cluster k_cacc was a STRAGGLER kernel — 45.4 µs
// at 1.7% occupancy. Fix (R9, verified): split each cluster's list into NCH=16
// contiguous chunks; grid (3, 70, NB*NCH) = 13,440 blocks; fp64 partial per chunk;
// k_cred sums in fixed chunk order. PC aliases T2 (dead during k-means; first
// written by the layer-0 attention-out GEMM). R8 lesson: never grow the workspace.
__global__ __launch_bounds__(128) void k_cacc(
    const float* __restrict__ X,
    const int* __restrict__ listF, const int* __restrict__ listB,
    const int* __restrict__ cntAll,
    double* __restrict__ PC) {
  __shared__ int ls[256];    // cs = ceil(4096/16) = 256 max
  int slice = blockIdx.x;    // 0..2
  int kq = blockIdx.y;       // 0..KFG+KBG-1
  int zz = blockIdx.z;       // b*NCH + ch
  int b = zz / NCH, ch = zz % NCH;
  int t = threadIdx.x;
  int c = slice * 128 + t;
  const int* list; int cnt;
  if (kq < KFG) {
    cnt = cntAll[b * KFG + kq];
    list = listF + ((long)b * KFG + kq) * NPIX;
  } else {
    int k = kq - KFG;
    cnt = cntAll[NB * KFG + b * KBG + k];
    list = listB + ((long)b * KBG + k) * NPIX;
  }
  int cs = (cnt + NCH - 1) / NCH;
  int i0 = ch * cs;
  int i1 = min(i0 + cs, cnt);
  int m = i1 - i0;                       // may be <= 0 -> partial stays 0
  for (int i = t; i < m; i += 128) ls[i] = list[i0 + i];
  __syncthreads();
  const float* Xb = X + (long)b * NPIX * CE;
  double acc = 0.0;
  int i = 0;
  for (; i + 4 <= m; i += 4) {
    int n0 = ls[i], n1 = ls[i + 1], n2 = ls[i + 2], n3 = ls[i + 3];
    float v0 = Xb[(long)n0 * CE + c];
    float v1 = Xb[(long)n1 * CE + c];
    float v2 = Xb[(long)n2 * CE + c];
    float v3 = Xb[(long)n3 * CE + c];
    acc += (double)v0; acc += (double)v1; acc += (double)v2; acc += (double)v3;
  }
  for (; i < m; ++i) acc += (double)Xb[(long)ls[i] * CE + c];
  // PC layout: [ch][b*(KFG+KBG)+kq][c]
  PC[((long)ch * (NB * (KFG + KBG)) + (long)b * (KFG + KBG) + kq) * CE + c] = acc;
}

// ---------------- reduce chunk partials -> center update (deterministic) ----------------
__global__ void k_cred(const double* __restrict__ PC, const int* __restrict__ cntAll,
                       const float* __restrict__ srcF, float* __restrict__ dstF,
                       const float* __restrict__ srcB, float* __restrict__ dstB) {
  int i = blockIdx.x * 256 + threadIdx.x;
  const int tot = NB * (KFG + KBG) * CE;
  if (i >= tot) return;
  int c = i % CE;
  int r = i / CE;                        // b*(KFG+KBG)+kq
  int kq = r % (KFG + KBG);
  int b = r / (KFG + KBG);
  const long stride = (long)NB * (KFG + KBG) * CE;
  double s = 0.0;
  #pragma unroll
  for (int ch = 0; ch < NCH; ++ch) s += PC[(long)ch * stride + (long)r * CE + c];
  if (kq < KFG) {
    int cnt = cntAll[b * KFG + kq];
    long o = ((long)b * KFG + kq) * CE + c;
    dstF[o] = (cnt > 0) ? (float)(s / (double)cnt) : srcF[o];
  } else {
    int k = kq - KFG;
    int cnt = cntAll[NB * KFG + b * KBG + k];
    long o = ((long)b * KBG + k) * CE + c;
    dstB[o] = (cnt > 0) ? (float)(s / (double)cnt) : srcB[o];
  }
}

// ---------------- fused pos + bf16 staging ----------------
__global__ void k_cvtQV(const float* __restrict__ X,
                        const float* __restrict__ yvf, const float* __restrict__ xvf,
                        const float* __restrict__ invdt, const float* __restrict__ notp,
                        float* __restrict__ POS,
                        unsigned short* __restrict__ QB, unsigned short* __restrict__ VBin) {
  long i = (long)blockIdx.x * 256 + threadIdx.x;
  if (i >= (long)NB * NPIX * CE) return;
  int c = (int)(i % CE);
  long row = i / CE;
  float p = (c < 192) ? yvf[row] : xvf[row];
  float v = p * invdt[c];
  int tt = (c < 192) ? c : c - 192;
  float r = (tt & 1) ? cosf(v) : sinf(v);
  POS[i] = r;
  float x = X[i];
  QB[i] = f2bf(x + r);
  VBin[i] = f2bf(x * notp[row]);
}

// ---------------- fused per-layer weight convert/transpose + concat bias ----------------
__global__ void k_cvtW_all(
    const float* __restrict__ Wv_l, const float* __restrict__ Woff_l,
    const float* __restrict__ Wa_l, const float* __restrict__ Wout_l,
    const float* __restrict__ Wf1_l, const float* __restrict__ Wf2_l,
    const float* __restrict__ boff_l, const float* __restrict__ ba_l,
    unsigned short* __restrict__ W0, unsigned short* __restrict__ W1,
    unsigned short* __restrict__ W3, unsigned short* __restrict__ W4,
    unsigned short* __restrict__ W5, float* __restrict__ biasCat) {
  int i = blockIdx.x * 256 + threadIdx.x;
  const int S = 147456, SF = 442368;
  if (i < S) {
    int n = i / 384, k = i % 384;
    W0[i] = f2bf(Wv_l[(long)k * 384 + n]);
  } else if (i < 2 * S) {
    int j = i - S; int n = j / 384, k = j % 384;
    float v = 0.f;
    if (n < 216) v = Woff_l[(long)k * 216 + n];
    else if (n < 324) v = Wa_l[(long)k * 108 + (n - 216)];
    W1[j] = f2bf(v);
  } else if (i < 3 * S) {
    int j = i - 2 * S; int n = j / 384, k = j % 384;
    W3[j] = f2bf(Wout_l[(long)k * 384 + n]);
  } else if (i < 3 * S + SF) {
    int j = i - 3 * S; int n = j / 384, k = j % 384;
    W4[j] = f2bf(Wf1_l[(long)k * 1152 + n]);
  } else if (i < 3 * S + 2 * SF) {
    int j = i - 3 * S - SF; int n = j / 1152, k = j % 1152;
    W5[j] = f2bf(Wf2_l[(long)k * 384 + n]);
  } else if (i < 3 * S + 2 * SF + 324) {
    int j = i - 3 * S - 2 * SF;
    biasCat[j] = (j < 216) ? boff_l[j] : ba_l[j - 216];
  }
}

// ---------------- bf16 MFMA GEMM: C = A @ Bt^T (+bias)(+relu) ----------------
// Staging via global_load_lds width=16. XCD-bijective remap (verified R9: FFN FETCH
// 56.7 -> 22.2/12.3 MB). LDS XOR-swizzle (verified R11: conflicts 1.77M -> 0).
// 2-phase double-buffered K-loop (verified R12: FFN 55 -> <43 µs, total -25 µs):
// prefetch next K-tile into the other buffer pair before computing the current one,
// ONE barrier per K-step; four statically distinct LDS arrays so the compiler can
// prove no aliasing between prefetch writes and current-tile ds_reads.
__global__ __launch_bounds__(256) void k_gemm_bf(
    const unsigned short* __restrict__ A, const unsigned short* __restrict__ Bt,
    const float* __restrict__ bias, float* __restrict__ Cf, unsigned short* __restrict__ Cb,
    int M, int K, int N, int relu) {
  __shared__ unsigned short As0[128 * 32];
  __shared__ unsigned short Bs0[128 * 32];
  __shared__ unsigned short As1[128 * 32];
  __shared__ unsigned short Bs1[128 * 32];
  int bx, by;
  {
    int gx = gridDim.x;
    int q = blockIdx.y * gx + blockIdx.x;
    if ((gridDim.y & 7) == 0) {
      int xcd = q & 7;
      int r = q >> 3;
      bx = r % gx;
      by = xcd + 8 * (r / gx);
    } else { bx = blockIdx.x; by = blockIdx.y; }
  }
  int m0 = by * 128, n0 = bx * 128;
  int t = threadIdx.x;
  int w = t >> 6, l = t & 63;
  int wm = w >> 1, wn = w & 1;
  int half = l >> 4, lr = l & 15;
  float4v acc[4][4] = {};

  auto STAGE = [&](unsigned short* AD, unsigned short* BD, int kk) {
    #pragma unroll
    for (int i = 0; i < 2; ++i) {
      int c = w * 64 + i * 256 + l;           // 0..511 = LDS slot index
      int r = c >> 2;
      int part = (c & 3) ^ ((r >> 1) & 3);    // swizzled global source chunk
      int ldsOff = (w * 64 + i * 256) * 8;    // shorts; lane adds l*16 bytes
      __builtin_amdgcn_global_load_lds(
          (const AS1 unsigned int*)(A + (size_t)(m0 + r) * K + kk + part * 8),
          (AS3 unsigned int*)(AD + ldsOff), 16, 0, 0);
      __builtin_amdgcn_global_load_lds(
          (const AS1 unsigned int*)(Bt + (size_t)(n0 + r) * K + kk + part * 8),
          (AS3 unsigned int*)(BD + ldsOff), 16, 0, 0);
    }
  };
  auto COMPUTE = [&](const unsigned short* AD, const unsigned short* BD) {
    short8 af[4], bfr[4];
    #pragma unroll
    for (int am = 0; am < 4; ++am) {
      int arow = wm * 64 + am * 16 + lr;
      af[am] = *(const short8*)(&AD[arow * 32 + (half ^ ((arow >> 1) & 3)) * 8]);
    }
    #pragma unroll
    for (int bn = 0; bn < 4; ++bn) {
      int brow = wn * 64 + bn * 16 + lr;
      bfr[bn] = *(const short8*)(&BD[brow * 32 + (half ^ ((brow >> 1) & 3)) * 8]);
    }
    #pragma unroll
    for (int am = 0; am < 4; ++am)
      #pragma unroll
      for (int bn = 0; bn < 4; ++bn)
        acc[am][bn] = __builtin_amdgcn_mfma_f32_16x16x32_bf16(af[am], bfr[bn], acc[am][bn], 0, 0, 0);
  };

  STAGE(As0, Bs0, 0);
  __syncthreads();
  for (int k0 = 0; k0 < K; k0 += 64) {
    // phase 0: prefetch k0+32 into buf1 while computing buf0
    STAGE(As1, Bs1, k0 + 32);               // k0+32 < K always (K % 64 == 0)
    COMPUTE(As0, Bs0);
    __syncthreads();
    // phase 1: prefetch k0+64 into buf0 (unless last) while computing buf1
    if (k0 + 64 < K) STAGE(As0, Bs0, k0 + 64);
    COMPUTE(As1, Bs1);
    __syncthreads();
  }
  #pragma unroll
  for (int am = 0; am < 4; ++am) {
    #pragma unroll
    for (int bn = 0; bn < 4; ++bn) {
      int gc = n0 + wn * 64 + bn * 16 + lr;
      if (gc < N) {
        float bv = bias ? bias[gc] : 0.f;
        int gr0 = m0 + wm * 64 + am * 16 + half * 4;
        #pragma unroll
        for (int r = 0; r < 4; ++r) {
          float v = acc[am][bn][r] + bv;
          if (relu) v = fmaxf(v, 0.f);
          size_t oi = (size_t)(gr0 + r) * N + gc;
          if (Cf) Cf[oi] = v;
          else Cb[oi] = f2bf(v);
        }
      }
    }
  }
}

// ---------------- coords+softmax: one thread per (row, head) ----------------
__global__ void k_coords(const unsigned short* __restrict__ OAB, float4* __restrict__ CRD) {
  int idx = blockIdx.x * 256 + threadIdx.x;
  if (idx >= NB * NPIX * NH) return;
  int row = idx / NH, h = idx % NH;
  int n = row & (NPIX - 1);
  int hh = n >> 6, ww = n & 63;
  float refx = ((float)ww + 0.5f) / (float)WDIM;
  float refy = ((float)hh + 0.5f) / (float)HDIM;
  const unsigned short* oab = OAB + (size_t)row * 324;
  float f[NPTS];
  #pragma unroll
  for (int j = 0; j < NPTS; ++j) f[j] = bf2f(oab[216 + h * 9 + j]);
  float m = f[0];
  #pragma unroll
  for (int j = 1; j < NPTS; ++j) m = fmaxf(m, f[j]);
  float s = 0.f;
  #pragma unroll
  for (int j = 0; j < NPTS; ++j) { f[j] = expf(f[j] - m); s += f[j]; }
  float inv = 1.f / s;
  float4* crd = CRD + (size_t)row * 108 + h * 9;
  #pragma unroll
  for (int p = 0; p < NPTS; ++p) {
    float ox = bf2f(oab[h * 18 + p * 2 + 0]);
    float oy = bf2f(oab[h * 18 + p * 2 + 1]);
    float lx = refx + ox / (float)WDIM;
    float ly = refy + oy / (float)HDIM;
    float xs = lx * (float)WDIM - 0.5f;
    float ys = ly * (float)HDIM - 0.5f;
    float x0f = floorf(xs), y0f = floorf(ys);
    int x0 = (int)x0f, y0 = (int)y0f;
    float4 o;
    o.x = xs - x0f;
    o.y = ys - y0f;
    o.z = f[p] * inv;
    o.w = __int_as_float((y0 << 16) | (x0 & 0xFFFF));
    crd[p] = o;
  }
}

// ---------------- gather: bf16 V, 8 channels/thread ----------------
// R13 (verified): V stored bf16 by the V-GEMM's bf16 epilogue -> L2 bytes halve;
// 8 ch/thread amortizes address/weight work. Gather left the top-5 (<40 µs).
__global__ __launch_bounds__(256) void k_gather(
    const unsigned short* __restrict__ VB, const float4* __restrict__ CRD,
    uint4* __restrict__ ATTu) {
  int idx = blockIdx.x * 256 + threadIdx.x;
  if (idx >= NB * NPIX * (CE / 8)) return;
  int row = idx / (CE / 8), cq = idx % (CE / 8);
  int c = cq * 8;
  int h = c >> 5;
  int b = row >> 12;
  const unsigned short* vb = VB + (size_t)b * NPIX * CE;
  const float4* crd = CRD + (size_t)row * 108 + h * 9;
  float a[8];
  #pragma unroll
  for (int j = 0; j < 8; ++j) a[j] = 0.f;
  #pragma unroll
  for (int p = 0; p < NPTS; ++p) {
    float4 o = crd[p];
    int pk = __float_as_int(o.w);
    int x0 = (int)(short)(pk & 0xFFFF);
    int y0 = pk >> 16;
    float wx = o.x, wy = o.y, aw = o.z;
    int x1 = x0 + 1, y1 = y0 + 1;
    float vx0 = (x0 >= 0 && x0 < WDIM) ? 1.f : 0.f;
    float vx1 = (x1 >= 0 && x1 < WDIM) ? 1.f : 0.f;
    float vy0 = (y0 >= 0 && y0 < HDIM) ? 1.f : 0.f;
    float vy1 = (y1 >= 0 && y1 < HDIM) ? 1.f : 0.f;
    int x0c = min(max(x0, 0), WDIM - 1), x1c = min(max(x1, 0), WDIM - 1);
    int y0c = min(max(y0, 0), HDIM - 1), y1c = min(max(y1, 0), HDIM - 1);
    float w00 = (1.f - wx) * (1.f - wy) * aw * vx0 * vy0;
    float w01 = wx * (1.f - wy) * aw * vx1 * vy0;
    float w10 = (1.f - wx) * wy * aw * vx0 * vy1;
    float w11 = wx * wy * aw * vx1 * vy1;
    uint4 u00 = *(const uint4*)(vb + (size_t)(y0c * WDIM + x0c) * CE + c);
    uint4 u01 = *(const uint4*)(vb + (size_t)(y0c * WDIM + x1c) * CE + c);
    uint4 u10 = *(const uint4*)(vb + (size_t)(y1c * WDIM + x0c) * CE + c);
    uint4 u11 = *(const uint4*)(vb + (size_t)(y1c * WDIM + x1c) * CE + c);
    const unsigned* q00 = (const unsigned*)&u00;
    const unsigned* q01 = (const unsigned*)&u01;
    const unsigned* q10 = (const unsigned*)&u10;
    const unsigned* q11 = (const unsigned*)&u11;
    #pragma unroll
    for (int d = 0; d < 4; ++d) {
      float g00l = __uint_as_float(q00[d] << 16), g00h = __uint_as_float(q00[d] & 0xFFFF0000u);
      float g01l = __uint_as_float(q01[d] << 16), g01h = __uint_as_float(q01[d] & 0xFFFF0000u);
      float g10l = __uint_as_float(q10[d] << 16), g10h = __uint_as_float(q10[d] & 0xFFFF0000u);
      float g11l = __uint_as_float(q11[d] << 16), g11h = __uint_as_float(q11[d] & 0xFFFF0000u);
      a[2 * d]     += g00l * w00 + g01l * w01 + g10l * w10 + g11l * w11;
      a[2 * d + 1] += g00h * w00 + g01h * w01 + g10h * w10 + g11h * w11;
    }
  }
  uint4 pk4;
  pk4.x = (unsigned)f2bf(a[0]) | ((unsigned)f2bf(a[1]) << 16);
  pk4.y = (unsigned)f2bf(a[2]) | ((unsigned)f2bf(a[3]) << 16);
  pk4.z = (unsigned)f2bf(a[4]) | ((unsigned)f2bf(a[5]) << 16);
  pk4.w = (unsigned)f2bf(a[6]) | ((unsigned)f2bf(a[7]) << 16);
  ATTu[(size_t)row * (CE / 8) + cq] = pk4;
}

// ---------------- LayerNorm(X + T), 4 rows/block, fused epilogues ----------------
__global__ __launch_bounds__(256) void k_ln(
    float* __restrict__ X, const float* __restrict__ T,
    const float* __restrict__ g, const float* __restrict__ bb,
    unsigned short* __restrict__ xbOut,
    const float* __restrict__ posp, const float* __restrict__ notp,
    unsigned short* __restrict__ qb, unsigned short* __restrict__ vbin,
    float* __restrict__ outp) {
  int t = threadIdx.x;
  int row = blockIdx.x * 4 + (t >> 6);
  int lane = t & 63;
  float* xr = X + (long)row * CE;
  const float* tr = T + (long)row * CE;
  float v[6]; float s = 0.f;
  #pragma unroll
  for (int i = 0; i < 6; ++i) { v[i] = xr[lane + 64 * i] + tr[lane + 64 * i]; s += v[i]; }
  #pragma unroll
  for (int o = 32; o > 0; o >>= 1) s += __shfl_down(s, o, 64);
  s = __shfl(s, 0, 64);
  float m = s / (float)CE;
  float var = 0.f;
  #pragma unroll
  for (int i = 0; i < 6; ++i) { float d = v[i] - m; var += d * d; }
  #pragma unroll
  for (int o = 32; o > 0; o >>= 1) var += __shfl_down(var, o, 64);
  var = __shfl(var, 0, 64);
  float rst = rsqrtf(var / (float)CE + 1e-5f);
  float nprow = notp ? notp[row] : 0.f;
  int b = row >> 12, n = row & (NPIX - 1);
  #pragma unroll
  for (int i = 0; i < 6; ++i) {
    int c = lane + 64 * i;
    float xn = (v[i] - m) * rst * g[c] + bb[c];
    if (outp) outp[((long)b * NROW + n) * CE + c] = xn;
    else xr[c] = xn;
    if (xbOut) xbOut[(long)row * CE + c] = f2bf(xn);
    if (qb) {
      qb[(long)row * CE + c] = f2bf(xn + posp[(long)row * CE + c]);
      vbin[(long)row * CE + c] = f2bf(xn * nprow);
    }
  }
}

// ---------------- centers -> output ----------------
__global__ void k_out_cen(const float* __restrict__ fg, const float* __restrict__ bg,
                          float* __restrict__ out) {
  int i = blockIdx.x * 256 + threadIdx.x;
  const int tot = NB * (KFG + KBG) * CE;
  if (i >= tot) return;
  int c = i % CE;
  int r = i / CE;
  int rr = r % (KFG + KBG);
  int b = r / (KFG + KBG);
  float v;
  if (rr < KFG) v = fg[((long)b * KFG + rr) * CE + c];
  else v = bg[((long)b * KBG + (rr - KFG)) * CE + c];
  out[((long)b * NROW + NPIX + rr) * CE + c] = v;
}

extern "C" void kernel_launch(void* const* d_in, const int* in_sizes, int n_in,
                              void* d_out, int out_size, void* d_ws, size_t ws_size,
                              hipStream_t stream) {
  (void)in_sizes; (void)n_in; (void)out_size; (void)ws_size;
  const float* s_x  = (const float*)d_in[0];
  const float* s_pm = (const float*)d_in[1];
  const float* s_sm = (const float*)d_in[2];
  const float* Wv   = (const float*)d_in[3];
  const float* bv   = (const float*)d_in[4];
  const float* Woff = (const float*)d_in[5];
  const float* boff = (const float*)d_in[6];
  const float* Wa   = (const float*)d_in[7];
  const float* ba   = (const float*)d_in[8];
  const float* Wout = (const float*)d_in[9];
  const float* bout = (const float*)d_in[10];
  const float* ln1g = (const float*)d_in[11];
  const float* ln1b = (const float*)d_in[12];
  const float* Wf1  = (const float*)d_in[13];
  const float* Wf2  = (const float*)d_in[14];
  const float* ln2g = (const float*)d_in[15];
  const float* ln2b = (const float*)d_in[16];
  float* out = (float*)d_out;
  char* pb = (char*)d_ws;

  const long BN  = (long)NB * NPIX;      // 16384
  const long BNC = BN * CE;              // 6291456

  float* X    = (float*)pb; pb += BNC * 4;
  float* POS  = (float*)pb; pb += BNC * 4;
  float* V    = (float*)pb; pb += BNC * 4;   // holds bf16 V (12.6 MB used of 25.2)
  float* T2   = (float*)pb; pb += BNC * 4;
  unsigned short* VBh = (unsigned short*)V;  // bf16 view for V-GEMM + gather
  double* PC  = (double*)T2;  // 13.8 MB chunk partials alias T2 (dead during k-means;
                              // first written by layer-0 attn-out GEMM).
  unsigned short* QB   = (unsigned short*)pb; pb += BNC * 2;
  unsigned short* VBin = (unsigned short*)pb; pb += BNC * 2;
  unsigned short* T1b  = (unsigned short*)pb; pb += BNC * 2;
  unsigned short* Zbf  = QB;   // FFN hidden aliases QB+VBin+T1b
  unsigned short* XB   = (unsigned short*)pb; pb += BNC * 2;
  unsigned short* OAB  = (unsigned short*)pb; pb += BN * 324 * 2;
  float4* CRD = (float4*)pb; pb += BN * 108 * 16;
  const int S_W = 147456, S_F = 442368;
  unsigned short* WT[NLAYERS][5];
  float* biasCat[NLAYERS];
  for (int l = 0; l < NLAYERS; ++l) {
    WT[l][0] = (unsigned short*)pb; pb += S_W * 2;
    WT[l][1] = (unsigned short*)pb; pb += S_W * 2;
    WT[l][2] = (unsigned short*)pb; pb += S_W * 2;
    WT[l][3] = (unsigned short*)pb; pb += S_F * 2;
    WT[l][4] = (unsigned short*)pb; pb += S_F * 2;
    biasCat[l] = (float*)pb; pb += 324 * 4;
  }
  float* padf = (float*)pb; pb += BN * 4;
  float* objf = (float*)pb; pb += BN * 4;
  float* notp = (float*)pb; pb += BN * 4;
  float* wfg  = (float*)pb; pb += BN * 4;
  float* wbg  = (float*)pb; pb += BN * 4;
  float* yvf  = (float*)pb; pb += BN * 4;
  float* xvf  = (float*)pb; pb += BN * 4;
  float* invdt = (float*)pb; pb += CE * 4;
  pb = (char*)(((size_t)pb + 7) & ~(size_t)7);
  double* xsq   = (double*)pb; pb += BN * 8;
  float* candD = (float*)pb; pb += BN * 7 * 4;            // per-chunk best distance (fp32)
  float* cFgA = (float*)pb; pb += (long)NB * KFG * CE * 4;  // fp32 centers
  float* cFgB = (float*)pb; pb += (long)NB * KFG * CE * 4;
  float* cBgA = (float*)pb; pb += (long)NB * KBG * CE * 4;
  float* cBgB = (float*)pb; pb += (long)NB * KBG * CE * 4;
  int* candI  = (int*)pb; pb += BN * 7 * 4;               // per-chunk best global-k
  int* cntAll = (int*)pb; pb += NB * (KFG + KBG) * 4;     // cluster counts (FG then BG)
  int* listF  = (int*)pb; pb += (long)NB * KFG * NPIX * 4;
  int* listB  = (int*)pb; pb += (long)NB * KBG * NPIX * 4;

  int bn = (int)BN;
  int cvtBlocks = (int)((BNC + 255) / 256);

  k_masks<<<(bn + 255) / 256, 256, 0, stream>>>(s_pm, s_sm, padf, objf, notp, wfg, wbg);
  k_transpose<<<dim3(NPIX / 64, CE / 64, NB), 256, 0, stream>>>(s_x, X);
  k_xsq<<<bn, 64, 0, stream>>>(X, xsq);
  k_cums<<<NB, 128, 0, stream>>>(padf, yvf, xvf, invdt);
  k_cvtQV<<<cvtBlocks, 256, 0, stream>>>(X, yvf, xvf, invdt, notp, POS, QB, VBin);

  const int CVTW_TOT = 3 * S_W + 2 * S_F + 324;
  for (int l = 0; l < NLAYERS; ++l) {
    k_cvtW_all<<<(CVTW_TOT + 255) / 256, 256, 0, stream>>>(
        Wv + (long)l * CE * CE, Woff + (long)l * CE * 216, Wa + (long)l * CE * 108,
        Wout + (long)l * CE * CE, Wf1 + (long)l * CE * 1152, Wf2 + (long)l * 1152 * CE,
        boff + l * 216, ba + l * 108,
        WT[l][0], WT[l][1], WT[l][2], WT[l][3], WT[l][4], biasCat[l]);
  }

  // ---- kmeans: dots(+chunk argmin) -> asn(bucket lists) -> cacc(chunk partials) -> cred ----
  float *srcF = cFgA, *dstF = cFgB, *srcB = cBgA, *dstB = cBgB;
  k_kinit<<<NB, 256, 0, stream>>>(X, wfg, srcF, KFG);
  k_kinit<<<NB, 256, 0, stream>>>(X, wbg, srcB, KBG);
  const int credBlocks = (NB * (KFG + KBG) * CE + 255) / 256;
  for (int it = 0; it < NITER; ++it) {
    k_dots<<<dim3(bn / 128, 7), 256, 0, stream>>>(X, xsq, srcF, srcB, candD, candI, cntAll);
    k_asn<<<(bn + 255) / 256, 256, 0, stream>>>(candD, candI, wfg, wbg, listF, listB, cntAll);
    k_cacc<<<dim3(3, KFG + KBG, NB * NCH), 128, 0, stream>>>(
        X, listF, listB, cntAll, PC);
    k_cred<<<credBlocks, 256, 0, stream>>>(PC, cntAll, srcF, dstF, srcB, dstB);
    float* tmp;
    tmp = srcF; srcF = dstF; dstF = tmp;
    tmp = srcB; srcB = dstB; dstB = tmp;
  }
  float* fgC = srcF; float* bgC = srcB;

  // ---- layers ----
  for (int l = 0; l < NLAYERS; ++l) {
    const float* bv_l   = bv   + l * CE;
    const float* bout_l = bout + l * CE;
    int last = (l == NLAYERS - 1);

    k_gemm_bf<<<dim3(3, 128), 256, 0, stream>>>(VBin, WT[l][0], bv_l, (float*)nullptr, VBh,
                                                bn, CE, 384, 0);
    k_gemm_bf<<<dim3(3, 128), 256, 0, stream>>>(QB, WT[l][1], biasCat[l], (float*)nullptr, OAB,
                                                bn, CE, 324, 0);
    k_coords<<<(bn * NH + 255) / 256, 256, 0, stream>>>(OAB, CRD);
    k_gather<<<(bn * (CE / 8) + 255) / 256, 256, 0, stream>>>(VBh, CRD, (uint4*)T1b);
    k_gemm_bf<<<dim3(3, 128), 256, 0, stream>>>(T1b, WT[l][2], bout_l, T2, (unsigned short*)nullptr,
                                                bn, CE, 384, 0);
    k_ln<<<bn / 4, 256, 0, stream>>>(X, T2, ln1g + l * CE, ln1b + l * CE,
                                     XB, (const float*)nullptr, (const float*)nullptr,
                                     (unsigned short*)nullptr, (unsigned short*)nullptr,
                                     (float*)nullptr);
    k_gemm_bf<<<dim3(9, 128), 256, 0, stream>>>(XB, WT[l][3], (const float*)nullptr,
                                                (float*)nullptr, Zbf, bn, CE, 1152, 1);
    k_gemm_bf<<<dim3(3, 128), 256, 0, stream>>>(Zbf, WT[l][4], (const float*)nullptr,
                                                T2, (unsigned short*)nullptr, bn, 1152, 384, 0);
    if (!last) {
      k_ln<<<bn / 4, 256, 0, stream>>>(X, T2, ln2g + l * CE, ln2b + l * CE,
                                       (unsigned short*)nullptr, POS, notp, QB, VBin,
                                       (float*)nullptr);
    } else {
      k_ln<<<bn / 4, 256, 0, stream>>>(X, T2, ln2g + l * CE, ln2b + l * CE,
                                       (unsigned short*)nullptr, (const float*)nullptr,
                                       (const float*)nullptr, (unsigned short*)nullptr,
                                       (unsigned short*)nullptr, out);
    }
  }

  k_out_cen<<<(NB * (KFG + KBG) * CE + 255) / 256, 256, 0, stream>>>(fgC, bgC, out);
}